// Round 5
// baseline (358.696 us; speedup 1.0000x reference)
//
#include <hip/hip_runtime.h>

static constexpr int NB = 2048;
static constexpr float SENT = -1e30f;

typedef __attribute__((ext_vector_type(8))) short bf16x8;
typedef __attribute__((ext_vector_type(4))) float f32x4;

// Stats arena: layer slot = 8192 floats. Line-padded atomics:
//   addr(ch, kind, copy) = base + (ch*4 + copy)*32 + kind*8   (kind 0=sum, 1=sumsq; copy 0..3)
// Every (ch,copy) owns a 128B cache line -> ~1024 same-line atomics instead of 65536.
#define ST_ADDR(base, ch, kind, copy) ((base) + (((ch)*4 + (copy))*32 + (kind)*8))

// rotated-3x3 tap permutation: weight tap k of rotation r lands at patch position DST[r][k]
static constexpr int DST[8][9] = {
  {8,7,6,5,4,3,2,1,0},
  {5,8,7,2,4,6,1,0,3},
  {2,5,8,1,4,7,0,3,6},
  {1,2,5,0,4,8,3,6,7},
  {0,1,2,3,4,5,6,7,8},
  {3,0,1,6,4,2,7,8,5},
  {6,3,0,7,4,1,8,5,2},
  {7,6,3,8,4,0,5,2,1},
};

__device__ __forceinline__ unsigned short f2bf(float f){
  unsigned int u = __float_as_uint(f);
  u += 0x7fffu + ((u>>16)&1u);          // RNE
  return (unsigned short)(u>>16);
}

__device__ __forceinline__ float st_read(const float* base, int ch, int kind){
  return base[((ch*4+0)*32 + kind*8)] + base[((ch*4+1)*32 + kind*8)]
       + base[((ch*4+2)*32 + kind*8)] + base[((ch*4+3)*32 + kind*8)];
}

// border cell index (16x16 plane) for border id t<60
__device__ __forceinline__ int border_cell(int t){
  if (t<16) return t;
  if (t<32) return 240 + (t-16);
  if (t<46) return (t-31)*16;
  return (t-45)*16 + 15;
}

// ---------------- pre: weight packs (blocks 0..282) + conv7 B (283..1306) + bn1 stats (1307..1818) ----------------
__global__ __launch_bounds__(256) void k_pre(const float* __restrict__ x, const float* __restrict__ w1,
                                             const float* __restrict__ w2, const float* __restrict__ w3,
                                             const float* __restrict__ w4,
                                             const float* __restrict__ w5, const float* __restrict__ w6,
                                             const float* __restrict__ w7,
                                             unsigned short* __restrict__ B2,
                                             unsigned short* __restrict__ B3,
                                             unsigned short* __restrict__ wb4,
                                             unsigned short* __restrict__ wb5, unsigned short* __restrict__ wb6,
                                             unsigned short* __restrict__ Bl,
                                             float* __restrict__ st){
  int blk = blockIdx.x;
  if (blk < 283){
    int i = blk*256 + threadIdx.x;
    if (i < 18432){                                  // 9*64*32
      int tap = i/2048, rem = i%2048, oc = rem/32, ci = rem%32;
      wb5[i] = f2bf(w5[(oc*32+ci)*9 + tap]);
    } else if (i < 55296){                           // + 9*64*64
      int j = i - 18432;
      int tap = j/4096, rem = j%4096, oc = rem/64, ci = rem%64;
      wb6[j] = f2bf(w6[(oc*64+ci)*9 + tap]);
    } else if (i < 64512){                           // + 9*32*32
      int j = i - 55296;
      int tap = j/1024, rem = j%1024, oc = rem/32, ci = rem%32;
      wb4[j] = f2bf(w4[(oc*32+ci)*9 + tap]);
    } else if (i < 67072){                           // + conv2 tap-pair pack [5][16][32]
      int j = i - 64512;
      int c = j >> 9;
      int rem = j & 511;
      int o = rem >> 5, k = rem & 31;
      int tap = c*2 + (k>>4);
      int ci = k & 15;
      unsigned short v = 0;
      if (tap <= 8){
        int rot = o>>1, u = o&1;
        int bb = ci>>1, ui = ci&1;
        int wc = (((bb - rot) & 7)<<1) | ui;
        int kk = 0;
        #pragma unroll
        for (int q=0;q<9;q++) if (DST[rot][q]==tap) kk=q;
        v = f2bf(w2[(u*16+wc)*9 + kk]);
      }
      B2[j] = v;
    } else if (i < 72192){                           // + conv3 tap-pair pack [5][32][32]
      int j = i - 67072;
      int c = j >> 10;
      int rem = j & 1023;
      int o = rem >> 5, k = rem & 31;
      int tap = c*2 + (k>>4);
      int ci = k & 15;
      unsigned short v = 0;
      if (tap <= 8){
        int rot = o>>2, uh = (o>>1)&1, ul = o&1;
        int bb = ci>>1, ui = ci&1;
        int wc = (((bb - rot) & 7)<<1) | ui;
        int kk = 0;
        #pragma unroll
        for (int q=0;q<9;q++) if (DST[rot][q]==tap) kk=q;
        v = f2bf(w3[uh*288 + (ul*16+wc)*9 + kk]);
      }
      B3[j] = v;
    }
    return;
  }
  if (blk < 1307){
    int i = (blk-283)*256 + threadIdx.x;             // 262144 exact
    int n = i>>10, k = i&1023;
    int pos16 = k>>6, ci = k&63;
    int r = pos16>>2, c = pos16&3;
    unsigned short v = 0;
    if (n < 250){
      int pos = n/10, o = n - 10*(n/10);
      int py = pos/5, px = pos - 5*(pos/5);
      int ky = r - py + 2, kx = c - px + 2;
      if (ky>=0 && ky<4 && kx>=0 && kx<4) v = f2bf(w7[(o*64+ci)*16 + ky*4 + kx]);
    }
    Bl[i] = v;
    return;
  }
  // ---- bn1 stats over y1 = rotconv1(x); w1 (18 floats) held in registers, rotation = compile-time tap permutation ----
  __shared__ float red[4][32];
  float wa[18];
  #pragma unroll
  for (int i=0;i<18;i++) wa[i] = w1[i];
  float s[16], s2[16];
  #pragma unroll
  for (int o=0;o<16;o++){ s[o]=0.f; s2[o]=0.f; }
  for (int idx = (blk-1307)*256 + threadIdx.x; idx < NB*784; idx += 512*256){
    int b = idx/784, pix = idx-b*784;
    int py = pix/28, px = pix-py*28;
    const float* xb = x + (size_t)b*784;
    float tap[9];
    #pragma unroll
    for (int d=0; d<9; d++){
      int dy = d/3-1, dx = d%3-1;
      int yy = py+dy, xx = px+dx;
      tap[d] = (yy>=0 && yy<28 && xx>=0 && xx<28) ? xb[yy*28+xx] : 0.f;
    }
    #pragma unroll
    for (int rot=0; rot<8; rot++){
      #pragma unroll
      for (int u=0; u<2; u++){
        float y = 0.f;
        #pragma unroll
        for (int k=0; k<9; k++) y += wa[u*9+k]*tap[DST[rot][k]];
        int ci = rot*2+u;
        s[ci] += y; s2[ci] += y*y;
      }
    }
  }
  int wid = threadIdx.x>>6;
  #pragma unroll
  for (int o=0;o<16;o++){
    float a = s[o], b2 = s2[o];
    #pragma unroll
    for (int off=32; off; off>>=1){ a += __shfl_down(a,off); b2 += __shfl_down(b2,off); }
    if ((threadIdx.x&63)==0){ red[wid][o] = a; red[wid][16+o] = b2; }
  }
  __syncthreads();
  if (threadIdx.x < 32){
    float v = red[0][threadIdx.x]+red[1][threadIdx.x]+red[2][threadIdx.x]+red[3][threadIdx.x];
    int ch = threadIdx.x & 15, kind = threadIdx.x >> 4;
    atomicAdd(ST_ADDR(st, ch, kind, blk & 3), v);
  }
}

// ---------------- conv2 MFMA: recompute y1 from x in-block (register weights); bn1 coef in-block ----------------
// NOTE: __launch_bounds__(256,2) — (256,4) forced a 128-TOTAL reg budget on a ~160-reg kernel -> mass spill.
__global__ __launch_bounds__(256, 2) void k_conv2m(const float* __restrict__ x,
                                                   const float* __restrict__ w1,
                                                   const unsigned short* __restrict__ B2,  // [5][16][32] bf16
                                                   const float* __restrict__ stin,   // bn1 sums (layer0)
                                                   const float* __restrict__ g1, const float* __restrict__ b1,
                                                   float* __restrict__ p2p,
                                                   float* __restrict__ stout){
  __shared__ float smemf[8640];
  __shared__ float cab[32];                      // ca[0:16], cb[16:32]
  __shared__ float red[4][32];
  unsigned short* Ls = (unsigned short*)smemf;
  float* xs = smemf + 7680;
  float* out2 = smemf;
  int t = threadIdx.x;
  int wid = t>>6, lane = t&63;
  int quad = lane>>4, m = lane&15;
  float wa[18];
  #pragma unroll
  for (int i=0;i<18;i++) wa[i] = w1[i];
  if (t < 16){
    const float invN = 1.f/1605632.f;
    float mu = st_read(stin, t, 0)*invN;
    float var = st_read(stin, t, 1)*invN - mu*mu;
    float a = g1[t&1]*rsqrtf(var + 1e-5f);
    cab[t] = a; cab[16+t] = b1[t&1] - mu*a;
  }
  int b = blockIdx.x;
  for (int i=t; i<960; i+=256){
    int r = i>>5, c = i&31;
    int iy = r-1, ix = c-1;
    xs[i] = (iy>=0 && iy<28 && ix>=0 && ix<28) ? x[(size_t)b*784 + iy*28 + ix] : 0.f;
  }
  for (int i=t; i<3840; i+=256) ((unsigned long long*)Ls)[i] = 0ULL;
  __syncthreads();
  for (int i=t; i<784; i+=256){
    int py = i/28, px = i - 28*(i/28);
    float tap[9];
    #pragma unroll
    for (int d=0; d<9; d++) tap[d] = xs[(py + d/3)*32 + px + d%3];
    float y[16];
    #pragma unroll
    for (int rot=0; rot<8; rot++){
      #pragma unroll
      for (int u=0; u<2; u++){
        float acc1 = 0.f;
        #pragma unroll
        for (int k=0; k<9; k++) acc1 += wa[u*9+k]*tap[DST[rot][k]];
        y[rot*2+u] = acc1;
      }
    }
    unsigned long long pk[4];
    #pragma unroll
    for (int q=0; q<4; q++){
      float4 A = *(const float4*)(cab + q*4);
      float4 Bv = *(const float4*)(cab + 16 + q*4);
      float r0 = fmaxf(y[q*4+0]*A.x + Bv.x, 0.f);
      float r1 = fmaxf(y[q*4+1]*A.y + Bv.y, 0.f);
      float r2 = fmaxf(y[q*4+2]*A.z + Bv.z, 0.f);
      float r3 = fmaxf(y[q*4+3]*A.w + Bv.w, 0.f);
      pk[q] = (unsigned long long)f2bf(r0)
            | ((unsigned long long)f2bf(r1)<<16)
            | ((unsigned long long)f2bf(r2)<<32)
            | ((unsigned long long)f2bf(r3)<<48);
    }
    int cell = (py+1)*32 + px + 1;
    unsigned long long* dstp = (unsigned long long*)(Ls + cell*16);
    dstp[0]=pk[0]; dstp[1]=pk[1]; dstp[2]=pk[2]; dstp[3]=pk[3];
  }
  __syncthreads();
  f32x4 acc[13];
  #pragma unroll
  for (int j=0;j<13;j++) acc[j] = (f32x4){0.f,0.f,0.f,0.f};
  #pragma unroll
  for (int c=0;c<5;c++){
    int tapA = 2*c, tapB = (2*c+1 < 9) ? 2*c+1 : 8;
    int dyA = tapA/3, dxA = tapA - 3*(tapA/3);
    int dyB = tapB/3, dxB = tapB - 3*(tapB/3);
    bf16x8 Bf = *(const bf16x8*)(B2 + (c*16 + m)*32 + quad*8);
    #pragma unroll
    for (int j=0;j<13;j++){
      int mt = wid + 4*j;
      if (mt >= 49) continue;
      int pos = mt*16 + m;
      int py = pos/28, px = pos - py*28;
      int pix = (quad < 2) ? ((py+dyA)*32 + px+dxA) : ((py+dyB)*32 + px+dxB);
      bf16x8 Af = *(const bf16x8*)(Ls + pix*16 + (quad&1)*8);
      acc[j] = __builtin_amdgcn_mfma_f32_16x16x32_bf16(Af, Bf, acc[j], 0, 0, 0);
    }
  }
  __syncthreads();   // done reading Ls; reuse as out2
  float s = 0.f, sq = 0.f;
  #pragma unroll
  for (int j=0;j<13;j++){
    int mt = wid + 4*j;
    if (mt >= 49) continue;
    #pragma unroll
    for (int p=0;p<2;p++){
      // pos0 = mt*16 + quad*4 + 2p is even and never wraps a row: (r0,r1) horizontal pool pair
      int pos0 = mt*16 + quad*4 + p*2;
      float v0 = acc[j][2*p], v1 = acc[j][2*p+1];
      s += v0 + v1; sq += v0*v0 + v1*v1;
      float hm = fmaxf(v0, v1);
      int py = pos0/28, px2 = (pos0 - py*28)>>1;
      out2[(py*14+px2)*17 + m] = hm;
    }
  }
  s += __shfl_down(s,32);  s += __shfl_down(s,16);
  sq += __shfl_down(sq,32); sq += __shfl_down(sq,16);
  if (lane < 16){ red[wid][m] = s; red[wid][16+m] = sq; }
  __syncthreads();
  if (t < 32){
    float v = red[0][t]+red[1][t]+red[2][t]+red[3][t];
    int ch = t & 15, kind = t >> 4;
    atomicAdd(ST_ADDR(stout, ch, kind, b & 3), v);
  }
  for (int i=t; i<3136; i+=256){
    int cell = i>>4, oc = i&15;
    int yo = cell/14, xo = cell - yo*14;
    float mx = fmaxf(out2[((2*yo)*14+xo)*17 + oc], out2[((2*yo+1)*14+xo)*17 + oc]);
    p2p[((size_t)b*256 + (yo+1)*16 + xo + 1)*16 + oc] = mx;
  }
  for (int i=t; i<960; i+=256){
    int bc = border_cell(i>>4), oc = i&15;
    p2p[((size_t)b*256 + bc)*16 + oc] = SENT;
  }
}

// ---------------- conv3 MFMA: 16->32 rotated over 14x14, bn2 coef in-block, stats, padded y3 out ----------------
__global__ __launch_bounds__(256, 2) void k_conv3m(const float* __restrict__ p2p,
                                                   const unsigned short* __restrict__ B3,  // [5][32][32] bf16
                                                   const float* __restrict__ stin,
                                                   const float* __restrict__ g2, const float* __restrict__ b2,
                                                   float* __restrict__ y3p,
                                                   float* __restrict__ stout){
  __shared__ unsigned short Ls[256*16];
  __shared__ float ca[16], cb[16];
  __shared__ float red[4][64];
  int t = threadIdx.x;
  int wid = t>>6, lane = t&63;
  int quad = lane>>4, m = lane&15;
  if (t < 16){
    const float invN = 1.f/1605632.f;
    float mu = st_read(stin, t, 0)*invN;
    float var = st_read(stin, t, 1)*invN - mu*mu;
    float a = g2[t&1]*rsqrtf(var + 1e-5f);
    ca[t] = a; cb[t] = b2[t&1] - mu*a;
  }
  __syncthreads();
  int b = blockIdx.x;
  const float* sb = p2p + (size_t)b*4096;
  #pragma unroll
  for (int it=0; it<4; it++){
    float4 v = *(const float4*)(sb + (size_t)t*16 + it*4);
    int c0 = it*4;
    float r0 = fmaxf(v.x*ca[c0]  +cb[c0],   0.f);
    float r1 = fmaxf(v.y*ca[c0+1]+cb[c0+1], 0.f);
    float r2 = fmaxf(v.z*ca[c0+2]+cb[c0+2], 0.f);
    float r3 = fmaxf(v.w*ca[c0+3]+cb[c0+3], 0.f);
    unsigned long long pk = (unsigned long long)f2bf(r0)
                          | ((unsigned long long)f2bf(r1)<<16)
                          | ((unsigned long long)f2bf(r2)<<32)
                          | ((unsigned long long)f2bf(r3)<<48);
    *(unsigned long long*)(Ls + t*16 + it*4) = pk;
  }
  __syncthreads();
  int py[4], px[4]; bool vt[4];
  #pragma unroll
  for (int j=0;j<4;j++){
    int mt = wid + 4*j;
    int pos = mt*16 + m;
    vt[j] = (mt <= 12);
    if (pos >= 196) pos = 0;
    py[j] = pos/14; px[j] = pos%14;
  }
  float* yb = y3p + (size_t)b*8192;
  float sa[2], sqa[2];
  #pragma unroll
  for (int nt=0; nt<2; nt++){
    f32x4 acc[4];
    #pragma unroll
    for (int j=0;j<4;j++) acc[j] = (f32x4){0.f,0.f,0.f,0.f};
    #pragma unroll
    for (int c=0;c<5;c++){
      int tapA = 2*c, tapB = (2*c+1 < 9) ? 2*c+1 : 8;
      int dyA = tapA/3, dxA = tapA - 3*(tapA/3);
      int dyB = tapB/3, dxB = tapB - 3*(tapB/3);
      bf16x8 Bf = *(const bf16x8*)(B3 + (c*32 + nt*16 + m)*32 + quad*8);
      #pragma unroll
      for (int j=0;j<4;j++){
        if (!vt[j]) continue;
        int pix = (quad < 2) ? ((py[j]+dyA)*16 + px[j]+dxA) : ((py[j]+dyB)*16 + px[j]+dxB);
        bf16x8 Af = *(const bf16x8*)(Ls + pix*16 + (quad&1)*8);
        acc[j] = __builtin_amdgcn_mfma_f32_16x16x32_bf16(Af, Bf, acc[j], 0, 0, 0);
      }
    }
    float s = 0.f, sq = 0.f;
    #pragma unroll
    for (int j=0;j<4;j++){
      if (!vt[j]) continue;
      int mt = wid + 4*j;
      #pragma unroll
      for (int r=0;r<4;r++){
        int pos = mt*16 + quad*4 + r;
        if (pos < 196){
          float v = acc[j][r];
          int py2 = pos/14, px2 = pos - py2*14;
          yb[(size_t)((py2+1)*16 + px2 + 1)*32 + nt*16 + m] = v;
          s += v; sq += v*v;
        }
      }
    }
    s += __shfl_down(s,32);  s += __shfl_down(s,16);
    sq += __shfl_down(sq,32); sq += __shfl_down(sq,16);
    sa[nt] = s; sqa[nt] = sq;
  }
  if (lane < 16){
    red[wid][m]      = sa[0];  red[wid][32+m]      = sqa[0];
    red[wid][16+m]   = sa[1];  red[wid][32+16+m]   = sqa[1];
  }
  __syncthreads();
  if (t < 64){
    float v = red[0][t]+red[1][t]+red[2][t]+red[3][t];
    int ch = t & 31, kind = t >> 5;
    atomicAdd(ST_ADDR(stout, ch, kind, b & 3), v);
  }
  for (int i=t; i<1920; i+=256){
    int bc = border_cell(i>>5), oc = i&31;
    yb[(size_t)bc*32 + oc] = SENT;
  }
}

// ---------------- conv4 MFMA: 32->32 over 14x14, bn3 coef in-block, FUSED NMS, stats + raw pool -> p4 ----------------
__global__ __launch_bounds__(256, 2) void k_conv4m(const float* __restrict__ y3p,
                                                   const unsigned short* __restrict__ wb4, // [9][32][32] bf16
                                                   const float* __restrict__ stin,
                                                   const float* __restrict__ g3, const float* __restrict__ b3,
                                                   float* __restrict__ p4,
                                                   float* __restrict__ stout,
                                                   float* __restrict__ nmsa){
  __shared__ unsigned short L[256*40];   // 20480 B
  __shared__ float hp[98*33];            // 12936 B, horizontal pool staging
  __shared__ float ca[32], cb[32];
  __shared__ float red[4][64];
  __shared__ float nred[4];
  int t = threadIdx.x;
  int wid = t>>6, lane = t&63;
  int quad = lane>>4, m = lane&15;
  if (t < 32){
    const float invN = 1.f/401408.f;
    float mu = st_read(stin, t, 0)*invN;
    float var = st_read(stin, t, 1)*invN - mu*mu;
    float a = g3[t&3]*rsqrtf(var + 1e-5f);
    ca[t] = a; cb[t] = b3[t&3] - mu*a;
  }
  __syncthreads();
  int b = blockIdx.x;
  const float* sb = y3p + (size_t)b*8192;
  #pragma unroll
  for (int it=0; it<8; it++){
    float4 v = *(const float4*)(sb + (size_t)t*32 + it*4);
    int c0 = it*4;
    float r0 = fmaxf(v.x*ca[c0]  +cb[c0],   0.f);
    float r1 = fmaxf(v.y*ca[c0+1]+cb[c0+1], 0.f);
    float r2 = fmaxf(v.z*ca[c0+2]+cb[c0+2], 0.f);
    float r3 = fmaxf(v.w*ca[c0+3]+cb[c0+3], 0.f);
    unsigned long long pk = (unsigned long long)f2bf(r0)
                          | ((unsigned long long)f2bf(r1)<<16)
                          | ((unsigned long long)f2bf(r2)<<32)
                          | ((unsigned long long)f2bf(r3)<<48);
    *(unsigned long long*)(L + t*40 + it*4) = pk;
  }
  __syncthreads();
  float nloc = 0.f;
  for (int i=t; i<784; i+=256){
    int hw = i>>2, c4 = i&3;
    int cell = (hw/14 + 1)*16 + hw%14 + 1;
    const unsigned long long* g64 = (const unsigned long long*)(L + cell*40 + c4*8);
    unsigned long long w0 = g64[0], w1 = g64[1];
    float v[8]; float vmax = -1e30f;
    #pragma unroll
    for (int r=0;r<4;r++){
      v[r]   = __uint_as_float((unsigned int)((w0 >> (16*r)) & 0xFFFFu) << 16);
      v[4+r] = __uint_as_float((unsigned int)((w1 >> (16*r)) & 0xFFFFu) << 16);
    }
    #pragma unroll
    for (int r=0;r<8;r++) vmax = fmaxf(vmax, v[r]);
    #pragma unroll
    for (int r=0;r<8;r++) nloc += (v[r] != vmax) ? v[r] : 0.f;
  }
  #pragma unroll
  for (int off=32; off; off>>=1) nloc += __shfl_down(nloc, off);
  if (lane == 0) nred[wid] = nloc;
  int py[4], px[4]; bool vt[4];
  #pragma unroll
  for (int j=0;j<4;j++){
    int mt = wid + 4*j;
    int pos = mt*16 + m;
    vt[j] = (mt <= 12);
    if (pos >= 196) pos = 0;
    py[j] = pos/14; px[j] = pos%14;
  }
  float sa[2], sqa[2];
  #pragma unroll
  for (int nt=0; nt<2; nt++){
    f32x4 acc[4];
    #pragma unroll
    for (int j=0;j<4;j++) acc[j] = (f32x4){0.f,0.f,0.f,0.f};
    for (int tap=0; tap<9; tap++){
      int dy = tap/3, dx = tap - dy*3;
      bf16x8 Bf = *(const bf16x8*)(wb4 + (tap*32 + nt*16 + m)*32 + quad*8);
      bf16x8 Af[4];
      #pragma unroll
      for (int j=0;j<4;j++)
        Af[j] = *(const bf16x8*)(L + ((py[j]+dy)*16 + px[j]+dx)*40 + quad*8);
      #pragma unroll
      for (int j=0;j<4;j++){
        if (!vt[j]) continue;
        acc[j] = __builtin_amdgcn_mfma_f32_16x16x32_bf16(Af[j], Bf, acc[j], 0, 0, 0);
      }
    }
    float s = 0.f, sq = 0.f;
    #pragma unroll
    for (int j=0;j<4;j++){
      if (!vt[j]) continue;
      int mt = wid + 4*j;
      #pragma unroll
      for (int p=0;p<2;p++){
        // pos0 even -> px even -> (v0,v1) is a horizontal 2x2-pool pair
        int pos0 = mt*16 + quad*4 + 2*p;
        if (pos0 + 1 < 196){
          float v0 = acc[j][2*p], v1 = acc[j][2*p+1];
          s += v0 + v1; sq += v0*v0 + v1*v1;
          float hm = fmaxf(v0, v1);
          int py0 = pos0/14, pxh = (pos0 - py0*14)>>1;
          hp[(py0*7 + pxh)*33 + nt*16 + m] = hm;
        }
      }
    }
    s += __shfl_down(s,32);  s += __shfl_down(s,16);
    sq += __shfl_down(sq,32); sq += __shfl_down(sq,16);
    sa[nt] = s; sqa[nt] = sq;
  }
  if (lane < 16){
    red[wid][m]      = sa[0];  red[wid][32+m]      = sqa[0];
    red[wid][16+m]   = sa[1];  red[wid][32+16+m]   = sqa[1];
  }
  __syncthreads();
  if (t == 0) atomicAdd(&nmsa[(b & 7)*32], nred[0]+nred[1]+nred[2]+nred[3]);
  if (t < 64){
    float v = red[0][t]+red[1][t]+red[2][t]+red[3][t];
    int ch = t & 31, kind = t >> 5;
    atomicAdd(ST_ADDR(stout, ch, kind, b & 3), v);
  }
  for (int i=t; i<1568; i+=256){
    int cell = i>>5, oc = i&31;
    int yo = cell/7, xo = cell - yo*7;
    float mx = fmaxf(hp[((2*yo)*7 + xo)*33 + oc], hp[((2*yo+1)*7 + xo)*33 + oc]);
    p4[((size_t)b*49 + cell)*32 + oc] = mx;
  }
}

// ---------------- conv5/conv6 MFMA: CI->64, per-wave batch, bn coef in-block, shift-GEMM over 9 taps ----------------
template<int CI>
__global__ __launch_bounds__(256, 2) void k_conv56m(const float* __restrict__ src,
                                                    const unsigned short* __restrict__ wb,  // [9][64][CI] bf16
                                                    const float* __restrict__ stin,
                                                    const float* __restrict__ g, const float* __restrict__ be,
                                                    float invN,
                                                    float* __restrict__ dst,
                                                    float* __restrict__ stout){
  constexpr int CIP = CI + 8;
  constexpr int KC = CI/32;
  __shared__ unsigned short lin[4][81*CIP];
  __shared__ float red[4][256];
  __shared__ float ca[CI], cb[CI];
  int wid = threadIdx.x>>6, lane = threadIdx.x&63;
  int quad = lane>>4, m = lane&15;
  unsigned short* L = lin[wid];
  if (threadIdx.x < CI){
    int i = threadIdx.x;
    float mu = st_read(stin, i, 0)*invN;
    float var = st_read(stin, i, 1)*invN - mu*mu;
    float a = g[i]*rsqrtf(var + 1e-5f);
    ca[i] = a; cb[i] = be[i] - mu*a;
  }
  for (int i = lane; i < 81*CIP/4; i += 64) ((unsigned long long*)L)[i] = 0ULL;
  __syncthreads();
  int b = blockIdx.x*4 + wid;
  const float* sb = src + (size_t)b*49*CI;
  for (int i = lane; i < 49*CI/4; i += 64){
    int pos = i/(CI/4), cig = i - pos*(CI/4);
    float4 v = *(const float4*)(sb + pos*CI + cig*4);
    float r0 = fmaxf(v.x*ca[cig*4]  +cb[cig*4],   0.f);
    float r1 = fmaxf(v.y*ca[cig*4+1]+cb[cig*4+1], 0.f);
    float r2 = fmaxf(v.z*ca[cig*4+2]+cb[cig*4+2], 0.f);
    float r3 = fmaxf(v.w*ca[cig*4+3]+cb[cig*4+3], 0.f);
    int pos9 = (pos/7 + 1)*9 + pos%7 + 1;
    unsigned long long pk = (unsigned long long)f2bf(r0)
                          | ((unsigned long long)f2bf(r1)<<16)
                          | ((unsigned long long)f2bf(r2)<<32)
                          | ((unsigned long long)f2bf(r3)<<48);
    *(unsigned long long*)(L + pos9*CIP + cig*4) = pk;
  }
  __syncthreads();
  int py[4], px[4];
  #pragma unroll
  for (int mt=0; mt<4; mt++){
    int pos = mt*16 + m;
    if (pos < 49){ py[mt] = pos/7; px[mt] = pos%7; }
    else { py[mt] = 0; px[mt] = 0; }
  }
  f32x4 acc[4][4];
  #pragma unroll
  for (int nt=0; nt<4; nt++)
    #pragma unroll
    for (int mt=0; mt<4; mt++) acc[nt][mt] = (f32x4){0.f,0.f,0.f,0.f};

  for (int tap=0; tap<9; tap++){
    int dy = tap/3, dx = tap - dy*3;
    int o9[4];
    #pragma unroll
    for (int mt=0; mt<4; mt++) o9[mt] = ((py[mt]+dy)*9 + px[mt]+dx)*CIP;
    #pragma unroll
    for (int kc=0; kc<KC; kc++){
      int ko = kc*32 + quad*8;
      bf16x8 Bf[4], Af[4];
      #pragma unroll
      for (int nt=0; nt<4; nt++)
        Bf[nt] = *(const bf16x8*)(wb + (tap*64 + nt*16 + m)*CI + ko);
      #pragma unroll
      for (int mt=0; mt<4; mt++)
        Af[mt] = *(const bf16x8*)(L + o9[mt] + ko);
      #pragma unroll
      for (int nt=0; nt<4; nt++)
        #pragma unroll
        for (int mt=0; mt<4; mt++)
          acc[nt][mt] = __builtin_amdgcn_mfma_f32_16x16x32_bf16(Af[mt], Bf[nt], acc[nt][mt], 0, 0, 0);
    }
  }
  float* db = dst + (size_t)b*49*64;
  float snt[4], sqnt[4];
  #pragma unroll
  for (int nt=0; nt<4; nt++){
    float s = 0.f, sq = 0.f;
    #pragma unroll
    for (int mt=0; mt<4; mt++){
      #pragma unroll
      for (int r=0; r<4; r++){
        int pos = mt*16 + quad*4 + r;
        if (pos < 49){
          float v = acc[nt][mt][r];
          db[pos*64 + nt*16 + m] = v;
          s += v; sq += v*v;
        }
      }
    }
    s += __shfl_down(s, 32);  s += __shfl_down(s, 16);
    sq += __shfl_down(sq, 32); sq += __shfl_down(sq, 16);
    snt[nt] = s; sqnt[nt] = sq;
  }
  if (lane < 16){
    #pragma unroll
    for (int nt=0; nt<4; nt++){
      red[wid][nt*16 + lane] = snt[nt];
      red[wid][128 + nt*16 + lane] = sqnt[nt];
    }
  }
  __syncthreads();
  if (threadIdx.x < 128){
    int c = threadIdx.x & 63;
    int off = (threadIdx.x < 64) ? threadIdx.x : (128 + c);
    float v = red[0][off]+red[1][off]+red[2][off]+red[3][off];
    int kind = (threadIdx.x < 64) ? 0 : 1;
    atomicAdd(ST_ADDR(stout, c, kind, blockIdx.x & 3), v);
  }
}

// ---------------- bn6+relu + 2x2 pool pad 1 (7 -> 4); bn6 coef per-thread; y6 -> p6b bf16 ----------------
__global__ __launch_bounds__(256) void k_pool6(const float* __restrict__ y,
                                               const float* __restrict__ stin,
                                               const float* __restrict__ g6, const float* __restrict__ b6,
                                               unsigned short* __restrict__ p6b){
  int idx = blockIdx.x*256 + threadIdx.x;       // NB*16*64 exact
  int oc = idx & 63; int t2 = idx >> 6;
  int xo = t2 & 3;  int yo = (t2>>2) & 3;  int b = t2 >> 4;
  const float invN = 1.f/100352.f;
  float mu = st_read(stin, oc, 0)*invN;
  float var = st_read(stin, oc, 1)*invN - mu*mu;
  float a = g6[oc]*rsqrtf(var + 1e-5f);
  float bo = b6[oc] - mu*a;
  const float* src = y + (size_t)b*3136;
  float mx = -1e30f;
  #pragma unroll
  for (int dy=0;dy<2;dy++){
    int iy = yo*2 - 1 + dy;
    if (iy < 0 || iy >= 7) continue;
    #pragma unroll
    for (int dx=0;dx<2;dx++){
      int ix = xo*2 - 1 + dx;
      if (ix < 0 || ix >= 7) continue;
      mx = fmaxf(mx, src[(iy*7+ix)*64 + oc]*a + bo);
    }
  }
  p6b[(size_t)b*1024 + (yo*4 + xo)*64 + oc] = f2bf(fmaxf(mx, 0.f));
}

// ---------------- conv7 as GEMM: M=2048 (batch), N=256 (pos25*10+o), K=1024; partial max per N-block ----------------
__global__ __launch_bounds__(256) void k_gemm7(const unsigned short* __restrict__ A,   // [2048][1024] bf16
                                               const unsigned short* __restrict__ Bl,  // [256][1024] bf16
                                               float* __restrict__ part){              // [2048][4][10]
  __shared__ float Lw[4][16*65];
  int wid = threadIdx.x>>6, lane = threadIdx.x&63;
  int quad = lane>>4, m = lane&15;
  int blkm = blockIdx.x >> 2, blkn = blockIdx.x & 3;   // grid 128
  int rowb = blkm*64 + wid*16 + m;
  const unsigned short* Arow = A + (size_t)rowb*1024;
  f32x4 acc[4];
  #pragma unroll
  for (int nt=0; nt<4; nt++) acc[nt] = (f32x4){0.f,0.f,0.f,0.f};
  for (int kc=0; kc<32; kc++){
    bf16x8 Af = *(const bf16x8*)(Arow + kc*32 + quad*8);
    #pragma unroll
    for (int nt=0; nt<4; nt++){
      bf16x8 Bf = *(const bf16x8*)(Bl + (size_t)(blkn*64 + nt*16 + m)*1024 + kc*32 + quad*8);
      acc[nt] = __builtin_amdgcn_mfma_f32_16x16x32_bf16(Af, Bf, acc[nt], 0, 0, 0);
    }
  }
  float* Lp = &Lw[wid][0];
  #pragma unroll
  for (int nt=0; nt<4; nt++)
    #pragma unroll
    for (int r=0; r<4; r++)
      Lp[(quad*4+r)*65 + nt*16 + m] = acc[nt][r];
  __syncthreads();
  for (int i=lane; i<160; i+=64){
    int br = i/10, o = i - 10*(i/10);
    int c0 = ((o - blkn*64) % 10 + 10) % 10;
    float mx = -1e30f;
    for (int c=c0; c<64; c+=10){
      if (blkn*64 + c < 250) mx = fmaxf(mx, Lp[br*65 + c]);
    }
    part[((size_t)(blkm*64 + wid*16 + br)*4 + blkn)*10 + o] = mx;
  }
}

// ---------------- logits: max over 4 N-block partials + bias; nms write ----------------
__global__ __launch_bounds__(256) void k_logits(const float* __restrict__ part,
                                                const float* __restrict__ bias,
                                                const float* __restrict__ nmsa,
                                                float* __restrict__ out){
  int idx = blockIdx.x*256 + threadIdx.x;       // 20480 exact (80 blocks)
  int b = idx/10, o = idx - 10*(idx/10);
  const float* p = part + (size_t)b*40 + o;
  float mx = fmaxf(fmaxf(p[0], p[10]), fmaxf(p[20], p[30]));
  out[idx] = mx + bias[o];
  if (blockIdx.x == 0 && threadIdx.x == 0){
    float nm = 0.f;
    #pragma unroll
    for (int cp=0; cp<8; cp++) nm += nmsa[cp*32];
    out[20480] = nm * (1.f/12845056.f);
  }
}

extern "C" void kernel_launch(void* const* d_in, const int* in_sizes, int n_in,
                              void* d_out, int out_size, void* d_ws, size_t ws_size,
                              hipStream_t stream){
  const float* x  = (const float*)d_in[0];
  const float* w1 = (const float*)d_in[1];
  const float* w2 = (const float*)d_in[2];
  const float* w3 = (const float*)d_in[3];
  const float* w4 = (const float*)d_in[4];
  const float* w5 = (const float*)d_in[5];
  const float* w6 = (const float*)d_in[6];
  const float* w7 = (const float*)d_in[7];
  const float* g1 = (const float*)d_in[8];
  const float* b1 = (const float*)d_in[9];
  const float* g2 = (const float*)d_in[10];
  const float* b2 = (const float*)d_in[11];
  const float* g3 = (const float*)d_in[12];
  const float* b3 = (const float*)d_in[13];
  const float* g4 = (const float*)d_in[14];
  const float* b4 = (const float*)d_in[15];
  const float* g5 = (const float*)d_in[16];
  const float* b5 = (const float*)d_in[17];
  const float* g6 = (const float*)d_in[18];
  const float* b6 = (const float*)d_in[19];
  const float* b7 = (const float*)d_in[20];
  float* out = (float*)d_out;
  float* W = (float*)d_ws;

  // arena (float units)
  float* p2p  = W + 15728640;          //  8,388,608  (2048*256*16, cell-major)
  float* y3p  = W + 24117248;          // 16,777,216  (2048*256*32, cell-major)
  float* p4   = W + 0;                 //  3,211,264  (2048*49*32) -> ends 3,211,264
  // line-padded stats arena lives in the verified-free gap [3211264, 3407872):
  //   6 layers x 8192 floats + 8-copy nms (256) = 49,408 floats -> ends 3,260,672 < 3,407,872. No overlap.
  float* st   = W + 3211264;
  float* nmsa = st + 6*8192;
  float* y5   = W + 3407872;           //  6,422,528  (2048*49*64)
  float* y6   = W + 10223616;          //  6,422,528
  unsigned short* p6b = (unsigned short*)(W + 16646144); // 2048*1024 bf16
  unsigned short* wb5 = (unsigned short*)(W + 40894464);  // 9*64*32 bf16
  unsigned short* wb6 = (unsigned short*)(W + 40912896);  // 9*64*64 bf16
  unsigned short* wb4 = (unsigned short*)(W + 40931328);  // 9*32*32 bf16
  unsigned short* Bl = (unsigned short*)(W + 40951808);   // 256*1024 bf16
  float* part = W + 41082880;          //  81,920 (2048*4*10)
  unsigned short* B2 = (unsigned short*)(W + 41164800);   // 5*16*32 bf16 (1280 floats)
  unsigned short* B3 = (unsigned short*)(W + 41166080);   // 5*32*32 bf16 (2560 floats)

  hipMemsetAsync(st, 0, 49408*sizeof(float), stream);

  k_pre<<<1819,256,0,stream>>>(x, w1, w2, w3, w4, w5, w6, w7,
                               B2, B3, wb4, wb5, wb6, Bl, st + 0*8192);

  k_conv2m<<<2048,256,0,stream>>>(x, w1, B2, st + 0*8192, g1, b1, p2p, st + 1*8192);

  k_conv3m<<<2048,256,0,stream>>>(p2p, B3, st + 1*8192, g2, b2, y3p, st + 2*8192);

  k_conv4m<<<2048,256,0,stream>>>(y3p, wb4, st + 2*8192, g3, b3, p4, st + 3*8192, nmsa);

  k_conv56m<32><<<512,256,0,stream>>>(p4, wb5, st + 3*8192, g4, b4, 1.f/401408.f, y5, st + 4*8192);

  k_conv56m<64><<<512,256,0,stream>>>(y5, wb6, st + 4*8192, g5, b5, 1.f/100352.f, y6, st + 5*8192);

  k_pool6<<<8192,256,0,stream>>>(y6, st + 5*8192, g6, b6, p6b);

  k_gemm7<<<128,256,0,stream>>>(p6b, Bl, part);
  k_logits<<<80,256,0,stream>>>(part, b7, nmsa, out);
}

// Round 6
// 351.833 us; speedup vs baseline: 1.0195x; 1.0195x over previous
//
#include <hip/hip_runtime.h>

static constexpr int NB = 2048;
static constexpr float SENT = -1e30f;

typedef __attribute__((ext_vector_type(8))) short bf16x8;
typedef __attribute__((ext_vector_type(8))) unsigned short u16x8;
typedef __attribute__((ext_vector_type(4))) float f32x4;

// Stats arena: layer slot = 8192 floats. Line-padded atomics:
//   addr(ch, kind, copy) = base + (ch*4 + copy)*32 + kind*8   (kind 0=sum, 1=sumsq; copy 0..3)
#define ST_ADDR(base, ch, kind, copy) ((base) + (((ch)*4 + (copy))*32 + (kind)*8))

// rotated-3x3 tap permutation: weight tap k of rotation r lands at patch position DST[r][k]
static constexpr int DST[8][9] = {
  {8,7,6,5,4,3,2,1,0},
  {5,8,7,2,4,6,1,0,3},
  {2,5,8,1,4,7,0,3,6},
  {1,2,5,0,4,8,3,6,7},
  {0,1,2,3,4,5,6,7,8},
  {3,0,1,6,4,2,7,8,5},
  {6,3,0,7,4,1,8,5,2},
  {7,6,3,8,4,0,5,2,1},
};

__device__ __forceinline__ unsigned short f2bf(float f){
  unsigned int u = __float_as_uint(f);
  u += 0x7fffu + ((u>>16)&1u);          // RNE
  return (unsigned short)(u>>16);
}

__device__ __forceinline__ float bf2f(unsigned short h){
  return __uint_as_float((unsigned int)h << 16);
}

__device__ __forceinline__ float st_read(const float* base, int ch, int kind){
  return base[((ch*4+0)*32 + kind*8)] + base[((ch*4+1)*32 + kind*8)]
       + base[((ch*4+2)*32 + kind*8)] + base[((ch*4+3)*32 + kind*8)];
}

// border cell index (16x16 plane) for border id t<60
__device__ __forceinline__ int border_cell(int t){
  if (t<16) return t;
  if (t<32) return 240 + (t-16);
  if (t<46) return (t-31)*16;
  return (t-45)*16 + 15;
}

// ---------------- pre: weight packs (blocks 0..282) + conv7 B (283..1306) + bn1 stats (1307..1818) ----------------
__global__ __launch_bounds__(256) void k_pre(const float* __restrict__ x, const float* __restrict__ w1,
                                             const float* __restrict__ w2, const float* __restrict__ w3,
                                             const float* __restrict__ w4,
                                             const float* __restrict__ w5, const float* __restrict__ w6,
                                             const float* __restrict__ w7,
                                             unsigned short* __restrict__ B2,
                                             unsigned short* __restrict__ B3,
                                             unsigned short* __restrict__ wb4,
                                             unsigned short* __restrict__ wb5, unsigned short* __restrict__ wb6,
                                             unsigned short* __restrict__ Bl,
                                             float* __restrict__ st){
  int blk = blockIdx.x;
  if (blk < 283){
    int i = blk*256 + threadIdx.x;
    if (i < 18432){                                  // 9*64*32
      int tap = i/2048, rem = i%2048, oc = rem/32, ci = rem%32;
      wb5[i] = f2bf(w5[(oc*32+ci)*9 + tap]);
    } else if (i < 55296){                           // + 9*64*64
      int j = i - 18432;
      int tap = j/4096, rem = j%4096, oc = rem/64, ci = rem%64;
      wb6[j] = f2bf(w6[(oc*64+ci)*9 + tap]);
    } else if (i < 64512){                           // + 9*32*32
      int j = i - 55296;
      int tap = j/1024, rem = j%1024, oc = rem/32, ci = rem%32;
      wb4[j] = f2bf(w4[(oc*32+ci)*9 + tap]);
    } else if (i < 67072){                           // + conv2 tap-pair pack [5][16][32]
      int j = i - 64512;
      int c = j >> 9;
      int rem = j & 511;
      int o = rem >> 5, k = rem & 31;
      int tap = c*2 + (k>>4);
      int ci = k & 15;
      unsigned short v = 0;
      if (tap <= 8){
        int rot = o>>1, u = o&1;
        int bb = ci>>1, ui = ci&1;
        int wc = (((bb - rot) & 7)<<1) | ui;
        int kk = 0;
        #pragma unroll
        for (int q=0;q<9;q++) if (DST[rot][q]==tap) kk=q;
        v = f2bf(w2[(u*16+wc)*9 + kk]);
      }
      B2[j] = v;
    } else if (i < 72192){                           // + conv3 tap-pair pack [5][32][32]
      int j = i - 67072;
      int c = j >> 10;
      int rem = j & 1023;
      int o = rem >> 5, k = rem & 31;
      int tap = c*2 + (k>>4);
      int ci = k & 15;
      unsigned short v = 0;
      if (tap <= 8){
        int rot = o>>2, uh = (o>>1)&1, ul = o&1;
        int bb = ci>>1, ui = ci&1;
        int wc = (((bb - rot) & 7)<<1) | ui;
        int kk = 0;
        #pragma unroll
        for (int q=0;q<9;q++) if (DST[rot][q]==tap) kk=q;
        v = f2bf(w3[uh*288 + (ul*16+wc)*9 + kk]);
      }
      B3[j] = v;
    }
    return;
  }
  if (blk < 1307){
    int i = (blk-283)*256 + threadIdx.x;             // 262144 exact
    int n = i>>10, k = i&1023;
    int pos16 = k>>6, ci = k&63;
    int r = pos16>>2, c = pos16&3;
    unsigned short v = 0;
    if (n < 250){
      int pos = n/10, o = n - 10*(n/10);
      int py = pos/5, px = pos - 5*(pos/5);
      int ky = r - py + 2, kx = c - px + 2;
      if (ky>=0 && ky<4 && kx>=0 && kx<4) v = f2bf(w7[(o*64+ci)*16 + ky*4 + kx]);
    }
    Bl[i] = v;
    return;
  }
  // ---- bn1 stats over y1 = rotconv1(x); w1 (18 floats) in registers, rotation = compile-time tap permutation ----
  __shared__ float red[4][32];
  float wa[18];
  #pragma unroll
  for (int i=0;i<18;i++) wa[i] = w1[i];
  float s[16], s2[16];
  #pragma unroll
  for (int o=0;o<16;o++){ s[o]=0.f; s2[o]=0.f; }
  for (int idx = (blk-1307)*256 + threadIdx.x; idx < NB*784; idx += 512*256){
    int b = idx/784, pix = idx-b*784;
    int py = pix/28, px = pix-py*28;
    const float* xb = x + (size_t)b*784;
    float tap[9];
    #pragma unroll
    for (int d=0; d<9; d++){
      int dy = d/3-1, dx = d%3-1;
      int yy = py+dy, xx = px+dx;
      tap[d] = (yy>=0 && yy<28 && xx>=0 && xx<28) ? xb[yy*28+xx] : 0.f;
    }
    #pragma unroll
    for (int rot=0; rot<8; rot++){
      #pragma unroll
      for (int u=0; u<2; u++){
        float y = 0.f;
        #pragma unroll
        for (int k=0; k<9; k++) y += wa[u*9+k]*tap[DST[rot][k]];
        int ci = rot*2+u;
        s[ci] += y; s2[ci] += y*y;
      }
    }
  }
  int wid = threadIdx.x>>6;
  #pragma unroll
  for (int o=0;o<16;o++){
    float a = s[o], b2 = s2[o];
    #pragma unroll
    for (int off=32; off; off>>=1){ a += __shfl_down(a,off); b2 += __shfl_down(b2,off); }
    if ((threadIdx.x&63)==0){ red[wid][o] = a; red[wid][16+o] = b2; }
  }
  __syncthreads();
  if (threadIdx.x < 32){
    float v = red[0][threadIdx.x]+red[1][threadIdx.x]+red[2][threadIdx.x]+red[3][threadIdx.x];
    int ch = threadIdx.x & 15, kind = threadIdx.x >> 4;
    atomicAdd(ST_ADDR(st, ch, kind, blk & 3), v);
  }
}

// ---------------- conv2 MFMA: recompute y1 from x in-block; bn1 coef in-block; p2 OUTPUT AS BF16 ----------------
__global__ __launch_bounds__(256, 2) void k_conv2m(const float* __restrict__ x,
                                                   const float* __restrict__ w1,
                                                   const unsigned short* __restrict__ B2,  // [5][16][32] bf16
                                                   const float* __restrict__ stin,   // bn1 sums (layer0)
                                                   const float* __restrict__ g1, const float* __restrict__ b1,
                                                   unsigned short* __restrict__ p2b,
                                                   float* __restrict__ stout){
  __shared__ float smemf[8640];
  __shared__ float cab[32];                      // ca[0:16], cb[16:32]
  __shared__ float red[4][32];
  unsigned short* Ls = (unsigned short*)smemf;
  float* xs = smemf + 7680;
  float* out2 = smemf;
  int t = threadIdx.x;
  int wid = t>>6, lane = t&63;
  int quad = lane>>4, m = lane&15;
  float wa[18];
  #pragma unroll
  for (int i=0;i<18;i++) wa[i] = w1[i];
  if (t < 16){
    const float invN = 1.f/1605632.f;
    float mu = st_read(stin, t, 0)*invN;
    float var = st_read(stin, t, 1)*invN - mu*mu;
    float a = g1[t&1]*rsqrtf(var + 1e-5f);
    cab[t] = a; cab[16+t] = b1[t&1] - mu*a;
  }
  int b = blockIdx.x;
  for (int i=t; i<960; i+=256){
    int r = i>>5, c = i&31;
    int iy = r-1, ix = c-1;
    xs[i] = (iy>=0 && iy<28 && ix>=0 && ix<28) ? x[(size_t)b*784 + iy*28 + ix] : 0.f;
  }
  for (int i=t; i<3840; i+=256) ((unsigned long long*)Ls)[i] = 0ULL;
  __syncthreads();
  for (int i=t; i<784; i+=256){
    int py = i/28, px = i - 28*(i/28);
    float tap[9];
    #pragma unroll
    for (int d=0; d<9; d++) tap[d] = xs[(py + d/3)*32 + px + d%3];
    float y[16];
    #pragma unroll
    for (int rot=0; rot<8; rot++){
      #pragma unroll
      for (int u=0; u<2; u++){
        float acc1 = 0.f;
        #pragma unroll
        for (int k=0; k<9; k++) acc1 += wa[u*9+k]*tap[DST[rot][k]];
        y[rot*2+u] = acc1;
      }
    }
    unsigned long long pk[4];
    #pragma unroll
    for (int q=0; q<4; q++){
      float4 A = *(const float4*)(cab + q*4);
      float4 Bv = *(const float4*)(cab + 16 + q*4);
      float r0 = fmaxf(y[q*4+0]*A.x + Bv.x, 0.f);
      float r1 = fmaxf(y[q*4+1]*A.y + Bv.y, 0.f);
      float r2 = fmaxf(y[q*4+2]*A.z + Bv.z, 0.f);
      float r3 = fmaxf(y[q*4+3]*A.w + Bv.w, 0.f);
      pk[q] = (unsigned long long)f2bf(r0)
            | ((unsigned long long)f2bf(r1)<<16)
            | ((unsigned long long)f2bf(r2)<<32)
            | ((unsigned long long)f2bf(r3)<<48);
    }
    int cell = (py+1)*32 + px + 1;
    unsigned long long* dstp = (unsigned long long*)(Ls + cell*16);
    dstp[0]=pk[0]; dstp[1]=pk[1]; dstp[2]=pk[2]; dstp[3]=pk[3];
  }
  __syncthreads();
  f32x4 acc[13];
  #pragma unroll
  for (int j=0;j<13;j++) acc[j] = (f32x4){0.f,0.f,0.f,0.f};
  #pragma unroll
  for (int c=0;c<5;c++){
    int tapA = 2*c, tapB = (2*c+1 < 9) ? 2*c+1 : 8;
    int dyA = tapA/3, dxA = tapA - 3*(tapA/3);
    int dyB = tapB/3, dxB = tapB - 3*(tapB/3);
    bf16x8 Bf = *(const bf16x8*)(B2 + (c*16 + m)*32 + quad*8);
    #pragma unroll
    for (int j=0;j<13;j++){
      int mt = wid + 4*j;
      if (mt >= 49) continue;
      int pos = mt*16 + m;
      int py = pos/28, px = pos - py*28;
      int pix = (quad < 2) ? ((py+dyA)*32 + px+dxA) : ((py+dyB)*32 + px+dxB);
      bf16x8 Af = *(const bf16x8*)(Ls + pix*16 + (quad&1)*8);
      acc[j] = __builtin_amdgcn_mfma_f32_16x16x32_bf16(Af, Bf, acc[j], 0, 0, 0);
    }
  }
  __syncthreads();   // done reading Ls; reuse as out2
  float s = 0.f, sq = 0.f;
  #pragma unroll
  for (int j=0;j<13;j++){
    int mt = wid + 4*j;
    if (mt >= 49) continue;
    #pragma unroll
    for (int p=0;p<2;p++){
      // pos0 = mt*16 + quad*4 + 2p is even and never wraps a row: (r0,r1) horizontal pool pair
      int pos0 = mt*16 + quad*4 + p*2;
      float v0 = acc[j][2*p], v1 = acc[j][2*p+1];
      s += v0 + v1; sq += v0*v0 + v1*v1;
      float hm = fmaxf(v0, v1);
      int py = pos0/28, px2 = (pos0 - py*28)>>1;
      out2[(py*14+px2)*17 + m] = hm;
    }
  }
  s += __shfl_down(s,32);  s += __shfl_down(s,16);
  sq += __shfl_down(sq,32); sq += __shfl_down(sq,16);
  if (lane < 16){ red[wid][m] = s; red[wid][16+m] = sq; }
  __syncthreads();
  if (t < 32){
    float v = red[0][t]+red[1][t]+red[2][t]+red[3][t];
    int ch = t & 15, kind = t >> 4;
    atomicAdd(ST_ADDR(stout, ch, kind, b & 3), v);
  }
  unsigned short* pb = p2b + (size_t)b*4096;
  for (int i=t; i<3136; i+=256){
    int cell = i>>4, oc = i&15;
    int yo = cell/14, xo = cell - yo*14;
    float mx = fmaxf(out2[((2*yo)*14+xo)*17 + oc], out2[((2*yo+1)*14+xo)*17 + oc]);
    pb[((yo+1)*16 + xo + 1)*16 + oc] = f2bf(mx);
  }
  for (int i=t; i<960; i+=256){
    int bc = border_cell(i>>4), oc = i&15;
    pb[bc*16 + oc] = f2bf(SENT);
  }
}

// ---------------- conv3 MFMA: 16->32 rotated over 14x14, bn2 coef in-block; BF16 I/O, loads hoisted ----------------
__global__ __launch_bounds__(256, 2) void k_conv3m(const unsigned short* __restrict__ p2b,
                                                   const unsigned short* __restrict__ B3,  // [5][32][32] bf16
                                                   const float* __restrict__ stin,
                                                   const float* __restrict__ g2, const float* __restrict__ b2,
                                                   unsigned short* __restrict__ y3b,
                                                   float* __restrict__ stout){
  __shared__ unsigned short Ls[256*16];
  __shared__ float ca[16], cb[16];
  __shared__ float red[4][64];
  int t = threadIdx.x;
  int wid = t>>6, lane = t&63;
  int quad = lane>>4, m = lane&15;
  int b = blockIdx.x;
  // staging loads issued FIRST so HBM latency overlaps the stats/coef phase
  const unsigned short* sb = p2b + (size_t)b*4096;
  u16x8 U0 = *(const u16x8*)(sb + (size_t)t*16);
  u16x8 U1 = *(const u16x8*)(sb + (size_t)t*16 + 8);
  if (t < 16){
    const float invN = 1.f/1605632.f;
    float mu = st_read(stin, t, 0)*invN;
    float var = st_read(stin, t, 1)*invN - mu*mu;
    float a = g2[t&1]*rsqrtf(var + 1e-5f);
    ca[t] = a; cb[t] = b2[t&1] - mu*a;
  }
  __syncthreads();
  #pragma unroll
  for (int half=0; half<2; half++){
    const u16x8 U = half ? U1 : U0;
    unsigned long long pk0 = 0, pk1 = 0;
    #pragma unroll
    for (int j=0;j<4;j++){
      float v = bf2f((unsigned short)U[j]);
      float r = fmaxf(v*ca[half*8+j] + cb[half*8+j], 0.f);
      pk0 |= (unsigned long long)f2bf(r) << (16*j);
    }
    #pragma unroll
    for (int j=0;j<4;j++){
      float v = bf2f((unsigned short)U[4+j]);
      float r = fmaxf(v*ca[half*8+4+j] + cb[half*8+4+j], 0.f);
      pk1 |= (unsigned long long)f2bf(r) << (16*j);
    }
    *(unsigned long long*)(Ls + t*16 + half*8)     = pk0;
    *(unsigned long long*)(Ls + t*16 + half*8 + 4) = pk1;
  }
  __syncthreads();
  int py[4], px[4]; bool vt[4];
  #pragma unroll
  for (int j=0;j<4;j++){
    int mt = wid + 4*j;
    int pos = mt*16 + m;
    vt[j] = (mt <= 12);
    if (pos >= 196) pos = 0;
    py[j] = pos/14; px[j] = pos%14;
  }
  unsigned short* yb = y3b + (size_t)b*8192;
  float sa[2], sqa[2];
  #pragma unroll
  for (int nt=0; nt<2; nt++){
    f32x4 acc[4];
    #pragma unroll
    for (int j=0;j<4;j++) acc[j] = (f32x4){0.f,0.f,0.f,0.f};
    #pragma unroll
    for (int c=0;c<5;c++){
      int tapA = 2*c, tapB = (2*c+1 < 9) ? 2*c+1 : 8;
      int dyA = tapA/3, dxA = tapA - 3*(tapA/3);
      int dyB = tapB/3, dxB = tapB - 3*(tapB/3);
      bf16x8 Bf = *(const bf16x8*)(B3 + (c*32 + nt*16 + m)*32 + quad*8);
      #pragma unroll
      for (int j=0;j<4;j++){
        if (!vt[j]) continue;
        int pix = (quad < 2) ? ((py[j]+dyA)*16 + px[j]+dxA) : ((py[j]+dyB)*16 + px[j]+dxB);
        bf16x8 Af = *(const bf16x8*)(Ls + pix*16 + (quad&1)*8);
        acc[j] = __builtin_amdgcn_mfma_f32_16x16x32_bf16(Af, Bf, acc[j], 0, 0, 0);
      }
    }
    float s = 0.f, sq = 0.f;
    #pragma unroll
    for (int j=0;j<4;j++){
      if (!vt[j]) continue;
      int mt = wid + 4*j;
      #pragma unroll
      for (int r=0;r<4;r++){
        int pos = mt*16 + quad*4 + r;
        if (pos < 196){
          float v = acc[j][r];
          int py2 = pos/14, px2 = pos - py2*14;
          yb[(size_t)((py2+1)*16 + px2 + 1)*32 + nt*16 + m] = f2bf(v);
          s += v; sq += v*v;
        }
      }
    }
    s += __shfl_down(s,32);  s += __shfl_down(s,16);
    sq += __shfl_down(sq,32); sq += __shfl_down(sq,16);
    sa[nt] = s; sqa[nt] = sq;
  }
  if (lane < 16){
    red[wid][m]      = sa[0];  red[wid][32+m]      = sqa[0];
    red[wid][16+m]   = sa[1];  red[wid][32+16+m]   = sqa[1];
  }
  __syncthreads();
  if (t < 64){
    float v = red[0][t]+red[1][t]+red[2][t]+red[3][t];
    int ch = t & 31, kind = t >> 5;
    atomicAdd(ST_ADDR(stout, ch, kind, b & 3), v);
  }
  for (int i=t; i<1920; i+=256){
    int bc = border_cell(i>>5), oc = i&31;
    yb[(size_t)bc*32 + oc] = f2bf(SENT);
  }
}

// ---------------- conv4 MFMA: 32->32 over 14x14, bn3 coef in-block, FUSED NMS; BF16 input, loads hoisted ----------------
__global__ __launch_bounds__(256, 2) void k_conv4m(const unsigned short* __restrict__ y3b,
                                                   const unsigned short* __restrict__ wb4, // [9][32][32] bf16
                                                   const float* __restrict__ stin,
                                                   const float* __restrict__ g3, const float* __restrict__ b3,
                                                   float* __restrict__ p4,
                                                   float* __restrict__ stout,
                                                   float* __restrict__ nmsa){
  __shared__ unsigned short L[256*40];   // 20480 B
  __shared__ float hp[98*33];            // 12936 B, horizontal pool staging
  __shared__ float ca[32], cb[32];
  __shared__ float red[4][64];
  __shared__ float nred[4];
  int t = threadIdx.x;
  int wid = t>>6, lane = t&63;
  int quad = lane>>4, m = lane&15;
  int b = blockIdx.x;
  // staging loads issued FIRST so HBM latency overlaps the stats/coef phase
  const unsigned short* sb = y3b + (size_t)b*8192;
  u16x8 U[4];
  #pragma unroll
  for (int it=0; it<4; it++) U[it] = *(const u16x8*)(sb + (size_t)t*32 + it*8);
  if (t < 32){
    const float invN = 1.f/401408.f;
    float mu = st_read(stin, t, 0)*invN;
    float var = st_read(stin, t, 1)*invN - mu*mu;
    float a = g3[t&3]*rsqrtf(var + 1e-5f);
    ca[t] = a; cb[t] = b3[t&3] - mu*a;
  }
  __syncthreads();
  #pragma unroll
  for (int it=0; it<4; it++){
    unsigned long long pk0 = 0, pk1 = 0;
    #pragma unroll
    for (int j=0;j<4;j++){
      float v = bf2f((unsigned short)U[it][j]);
      float r = fmaxf(v*ca[it*8+j] + cb[it*8+j], 0.f);
      pk0 |= (unsigned long long)f2bf(r) << (16*j);
    }
    #pragma unroll
    for (int j=0;j<4;j++){
      float v = bf2f((unsigned short)U[it][4+j]);
      float r = fmaxf(v*ca[it*8+4+j] + cb[it*8+4+j], 0.f);
      pk1 |= (unsigned long long)f2bf(r) << (16*j);
    }
    *(unsigned long long*)(L + t*40 + it*8)     = pk0;
    *(unsigned long long*)(L + t*40 + it*8 + 4) = pk1;
  }
  __syncthreads();
  float nloc = 0.f;
  for (int i=t; i<784; i+=256){
    int hw = i>>2, c4 = i&3;
    int cell = (hw/14 + 1)*16 + hw%14 + 1;
    const unsigned long long* g64 = (const unsigned long long*)(L + cell*40 + c4*8);
    unsigned long long w0 = g64[0], w1 = g64[1];
    float v[8]; float vmax = -1e30f;
    #pragma unroll
    for (int r=0;r<4;r++){
      v[r]   = __uint_as_float((unsigned int)((w0 >> (16*r)) & 0xFFFFu) << 16);
      v[4+r] = __uint_as_float((unsigned int)((w1 >> (16*r)) & 0xFFFFu) << 16);
    }
    #pragma unroll
    for (int r=0;r<8;r++) vmax = fmaxf(vmax, v[r]);
    #pragma unroll
    for (int r=0;r<8;r++) nloc += (v[r] != vmax) ? v[r] : 0.f;
  }
  #pragma unroll
  for (int off=32; off; off>>=1) nloc += __shfl_down(nloc, off);
  if (lane == 0) nred[wid] = nloc;
  int py[4], px[4]; bool vt[4];
  #pragma unroll
  for (int j=0;j<4;j++){
    int mt = wid + 4*j;
    int pos = mt*16 + m;
    vt[j] = (mt <= 12);
    if (pos >= 196) pos = 0;
    py[j] = pos/14; px[j] = pos%14;
  }
  float sa[2], sqa[2];
  #pragma unroll
  for (int nt=0; nt<2; nt++){
    f32x4 acc[4];
    #pragma unroll
    for (int j=0;j<4;j++) acc[j] = (f32x4){0.f,0.f,0.f,0.f};
    for (int tap=0; tap<9; tap++){
      int dy = tap/3, dx = tap - dy*3;
      bf16x8 Bf = *(const bf16x8*)(wb4 + (tap*32 + nt*16 + m)*32 + quad*8);
      bf16x8 Af[4];
      #pragma unroll
      for (int j=0;j<4;j++)
        Af[j] = *(const bf16x8*)(L + ((py[j]+dy)*16 + px[j]+dx)*40 + quad*8);
      #pragma unroll
      for (int j=0;j<4;j++){
        if (!vt[j]) continue;
        acc[j] = __builtin_amdgcn_mfma_f32_16x16x32_bf16(Af[j], Bf, acc[j], 0, 0, 0);
      }
    }
    float s = 0.f, sq = 0.f;
    #pragma unroll
    for (int j=0;j<4;j++){
      if (!vt[j]) continue;
      int mt = wid + 4*j;
      #pragma unroll
      for (int p=0;p<2;p++){
        // pos0 even -> px even -> (v0,v1) is a horizontal 2x2-pool pair
        int pos0 = mt*16 + quad*4 + 2*p;
        if (pos0 + 1 < 196){
          float v0 = acc[j][2*p], v1 = acc[j][2*p+1];
          s += v0 + v1; sq += v0*v0 + v1*v1;
          float hm = fmaxf(v0, v1);
          int py0 = pos0/14, pxh = (pos0 - py0*14)>>1;
          hp[(py0*7 + pxh)*33 + nt*16 + m] = hm;
        }
      }
    }
    s += __shfl_down(s,32);  s += __shfl_down(s,16);
    sq += __shfl_down(sq,32); sq += __shfl_down(sq,16);
    sa[nt] = s; sqa[nt] = sq;
  }
  if (lane < 16){
    red[wid][m]      = sa[0];  red[wid][32+m]      = sqa[0];
    red[wid][16+m]   = sa[1];  red[wid][32+16+m]   = sqa[1];
  }
  __syncthreads();
  if (t == 0) atomicAdd(&nmsa[(b & 7)*32], nred[0]+nred[1]+nred[2]+nred[3]);
  if (t < 64){
    float v = red[0][t]+red[1][t]+red[2][t]+red[3][t];
    int ch = t & 31, kind = t >> 5;
    atomicAdd(ST_ADDR(stout, ch, kind, b & 3), v);
  }
  for (int i=t; i<1568; i+=256){
    int cell = i>>5, oc = i&31;
    int yo = cell/7, xo = cell - yo*7;
    float mx = fmaxf(hp[((2*yo)*7 + xo)*33 + oc], hp[((2*yo+1)*7 + xo)*33 + oc]);
    p4[((size_t)b*49 + cell)*32 + oc] = mx;
  }
}

// ---------------- conv5/conv6 MFMA: CI->64, per-wave batch, bn coef in-block, shift-GEMM over 9 taps ----------------
template<int CI>
__global__ __launch_bounds__(256, 2) void k_conv56m(const float* __restrict__ src,
                                                    const unsigned short* __restrict__ wb,  // [9][64][CI] bf16
                                                    const float* __restrict__ stin,
                                                    const float* __restrict__ g, const float* __restrict__ be,
                                                    float invN,
                                                    float* __restrict__ dst,
                                                    float* __restrict__ stout){
  constexpr int CIP = CI + 8;
  constexpr int KC = CI/32;
  __shared__ unsigned short lin[4][81*CIP];
  __shared__ float red[4][256];
  __shared__ float ca[CI], cb[CI];
  int wid = threadIdx.x>>6, lane = threadIdx.x&63;
  int quad = lane>>4, m = lane&15;
  unsigned short* L = lin[wid];
  if (threadIdx.x < CI){
    int i = threadIdx.x;
    float mu = st_read(stin, i, 0)*invN;
    float var = st_read(stin, i, 1)*invN - mu*mu;
    float a = g[i]*rsqrtf(var + 1e-5f);
    ca[i] = a; cb[i] = be[i] - mu*a;
  }
  for (int i = lane; i < 81*CIP/4; i += 64) ((unsigned long long*)L)[i] = 0ULL;
  __syncthreads();
  int b = blockIdx.x*4 + wid;
  const float* sb = src + (size_t)b*49*CI;
  for (int i = lane; i < 49*CI/4; i += 64){
    int pos = i/(CI/4), cig = i - pos*(CI/4);
    float4 v = *(const float4*)(sb + pos*CI + cig*4);
    float r0 = fmaxf(v.x*ca[cig*4]  +cb[cig*4],   0.f);
    float r1 = fmaxf(v.y*ca[cig*4+1]+cb[cig*4+1], 0.f);
    float r2 = fmaxf(v.z*ca[cig*4+2]+cb[cig*4+2], 0.f);
    float r3 = fmaxf(v.w*ca[cig*4+3]+cb[cig*4+3], 0.f);
    int pos9 = (pos/7 + 1)*9 + pos%7 + 1;
    unsigned long long pk = (unsigned long long)f2bf(r0)
                          | ((unsigned long long)f2bf(r1)<<16)
                          | ((unsigned long long)f2bf(r2)<<32)
                          | ((unsigned long long)f2bf(r3)<<48);
    *(unsigned long long*)(L + pos9*CIP + cig*4) = pk;
  }
  __syncthreads();
  int py[4], px[4];
  #pragma unroll
  for (int mt=0; mt<4; mt++){
    int pos = mt*16 + m;
    if (pos < 49){ py[mt] = pos/7; px[mt] = pos%7; }
    else { py[mt] = 0; px[mt] = 0; }
  }
  f32x4 acc[4][4];
  #pragma unroll
  for (int nt=0; nt<4; nt++)
    #pragma unroll
    for (int mt=0; mt<4; mt++) acc[nt][mt] = (f32x4){0.f,0.f,0.f,0.f};

  for (int tap=0; tap<9; tap++){
    int dy = tap/3, dx = tap - dy*3;
    int o9[4];
    #pragma unroll
    for (int mt=0; mt<4; mt++) o9[mt] = ((py[mt]+dy)*9 + px[mt]+dx)*CIP;
    #pragma unroll
    for (int kc=0; kc<KC; kc++){
      int ko = kc*32 + quad*8;
      bf16x8 Bf[4], Af[4];
      #pragma unroll
      for (int nt=0; nt<4; nt++)
        Bf[nt] = *(const bf16x8*)(wb + (tap*64 + nt*16 + m)*CI + ko);
      #pragma unroll
      for (int mt=0; mt<4; mt++)
        Af[mt] = *(const bf16x8*)(L + o9[mt] + ko);
      #pragma unroll
      for (int nt=0; nt<4; nt++)
        #pragma unroll
        for (int mt=0; mt<4; mt++)
          acc[nt][mt] = __builtin_amdgcn_mfma_f32_16x16x32_bf16(Af[mt], Bf[nt], acc[nt][mt], 0, 0, 0);
    }
  }
  float* db = dst + (size_t)b*49*64;
  float snt[4], sqnt[4];
  #pragma unroll
  for (int nt=0; nt<4; nt++){
    float s = 0.f, sq = 0.f;
    #pragma unroll
    for (int mt=0; mt<4; mt++){
      #pragma unroll
      for (int r=0; r<4; r++){
        int pos = mt*16 + quad*4 + r;
        if (pos < 49){
          float v = acc[nt][mt][r];
          db[pos*64 + nt*16 + m] = v;
          s += v; sq += v*v;
        }
      }
    }
    s += __shfl_down(s, 32);  s += __shfl_down(s, 16);
    sq += __shfl_down(sq, 32); sq += __shfl_down(sq, 16);
    snt[nt] = s; sqnt[nt] = sq;
  }
  if (lane < 16){
    #pragma unroll
    for (int nt=0; nt<4; nt++){
      red[wid][nt*16 + lane] = snt[nt];
      red[wid][128 + nt*16 + lane] = sqnt[nt];
    }
  }
  __syncthreads();
  if (threadIdx.x < 128){
    int c = threadIdx.x & 63;
    int off = (threadIdx.x < 64) ? threadIdx.x : (128 + c);
    float v = red[0][off]+red[1][off]+red[2][off]+red[3][off];
    int kind = (threadIdx.x < 64) ? 0 : 1;
    atomicAdd(ST_ADDR(stout, c, kind, blockIdx.x & 3), v);
  }
}

// ---------------- bn6+relu + 2x2 pool pad 1 (7 -> 4); bn6 coef per-thread; y6 -> p6b bf16 ----------------
__global__ __launch_bounds__(256) void k_pool6(const float* __restrict__ y,
                                               const float* __restrict__ stin,
                                               const float* __restrict__ g6, const float* __restrict__ b6,
                                               unsigned short* __restrict__ p6b){
  int idx = blockIdx.x*256 + threadIdx.x;       // NB*16*64 exact
  int oc = idx & 63; int t2 = idx >> 6;
  int xo = t2 & 3;  int yo = (t2>>2) & 3;  int b = t2 >> 4;
  const float invN = 1.f/100352.f;
  float mu = st_read(stin, oc, 0)*invN;
  float var = st_read(stin, oc, 1)*invN - mu*mu;
  float a = g6[oc]*rsqrtf(var + 1e-5f);
  float bo = b6[oc] - mu*a;
  const float* src = y + (size_t)b*3136;
  float mx = -1e30f;
  #pragma unroll
  for (int dy=0;dy<2;dy++){
    int iy = yo*2 - 1 + dy;
    if (iy < 0 || iy >= 7) continue;
    #pragma unroll
    for (int dx=0;dx<2;dx++){
      int ix = xo*2 - 1 + dx;
      if (ix < 0 || ix >= 7) continue;
      mx = fmaxf(mx, src[(iy*7+ix)*64 + oc]*a + bo);
    }
  }
  p6b[(size_t)b*1024 + (yo*4 + xo)*64 + oc] = f2bf(fmaxf(mx, 0.f));
}

// ---------------- conv7 as GEMM: M=2048 (batch), N=256 (pos25*10+o), K=1024; partial max per N-block ----------------
__global__ __launch_bounds__(256) void k_gemm7(const unsigned short* __restrict__ A,   // [2048][1024] bf16
                                               const unsigned short* __restrict__ Bl,  // [256][1024] bf16
                                               float* __restrict__ part){              // [2048][4][10]
  __shared__ float Lw[4][16*65];
  int wid = threadIdx.x>>6, lane = threadIdx.x&63;
  int quad = lane>>4, m = lane&15;
  int blkm = blockIdx.x >> 2, blkn = blockIdx.x & 3;   // grid 128
  int rowb = blkm*64 + wid*16 + m;
  const unsigned short* Arow = A + (size_t)rowb*1024;
  f32x4 acc[4];
  #pragma unroll
  for (int nt=0; nt<4; nt++) acc[nt] = (f32x4){0.f,0.f,0.f,0.f};
  for (int kc=0; kc<32; kc++){
    bf16x8 Af = *(const bf16x8*)(Arow + kc*32 + quad*8);
    #pragma unroll
    for (int nt=0; nt<4; nt++){
      bf16x8 Bf = *(const bf16x8*)(Bl + (size_t)(blkn*64 + nt*16 + m)*1024 + kc*32 + quad*8);
      acc[nt] = __builtin_amdgcn_mfma_f32_16x16x32_bf16(Af, Bf, acc[nt], 0, 0, 0);
    }
  }
  float* Lp = &Lw[wid][0];
  #pragma unroll
  for (int nt=0; nt<4; nt++)
    #pragma unroll
    for (int r=0; r<4; r++)
      Lp[(quad*4+r)*65 + nt*16 + m] = acc[nt][r];
  __syncthreads();
  for (int i=lane; i<160; i+=64){
    int br = i/10, o = i - 10*(i/10);
    int c0 = ((o - blkn*64) % 10 + 10) % 10;
    float mx = -1e30f;
    for (int c=c0; c<64; c+=10){
      if (blkn*64 + c < 250) mx = fmaxf(mx, Lp[br*65 + c]);
    }
    part[((size_t)(blkm*64 + wid*16 + br)*4 + blkn)*10 + o] = mx;
  }
}

// ---------------- logits: max over 4 N-block partials + bias; nms write ----------------
__global__ __launch_bounds__(256) void k_logits(const float* __restrict__ part,
                                                const float* __restrict__ bias,
                                                const float* __restrict__ nmsa,
                                                float* __restrict__ out){
  int idx = blockIdx.x*256 + threadIdx.x;       // 20480 exact (80 blocks)
  int b = idx/10, o = idx - 10*(idx/10);
  const float* p = part + (size_t)b*40 + o;
  float mx = fmaxf(fmaxf(p[0], p[10]), fmaxf(p[20], p[30]));
  out[idx] = mx + bias[o];
  if (blockIdx.x == 0 && threadIdx.x == 0){
    float nm = 0.f;
    #pragma unroll
    for (int cp=0; cp<8; cp++) nm += nmsa[cp*32];
    out[20480] = nm * (1.f/12845056.f);
  }
}

extern "C" void kernel_launch(void* const* d_in, const int* in_sizes, int n_in,
                              void* d_out, int out_size, void* d_ws, size_t ws_size,
                              hipStream_t stream){
  const float* x  = (const float*)d_in[0];
  const float* w1 = (const float*)d_in[1];
  const float* w2 = (const float*)d_in[2];
  const float* w3 = (const float*)d_in[3];
  const float* w4 = (const float*)d_in[4];
  const float* w5 = (const float*)d_in[5];
  const float* w6 = (const float*)d_in[6];
  const float* w7 = (const float*)d_in[7];
  const float* g1 = (const float*)d_in[8];
  const float* b1 = (const float*)d_in[9];
  const float* g2 = (const float*)d_in[10];
  const float* b2 = (const float*)d_in[11];
  const float* g3 = (const float*)d_in[12];
  const float* b3 = (const float*)d_in[13];
  const float* g4 = (const float*)d_in[14];
  const float* b4 = (const float*)d_in[15];
  const float* g5 = (const float*)d_in[16];
  const float* b5 = (const float*)d_in[17];
  const float* g6 = (const float*)d_in[18];
  const float* b6 = (const float*)d_in[19];
  const float* b7 = (const float*)d_in[20];
  float* out = (float*)d_out;
  float* W = (float*)d_ws;

  // arena (float units)
  unsigned short* p2b = (unsigned short*)(W + 15728640); // 2048*256*16 bf16 (16.8 MB, region holds 33.5 MB)
  unsigned short* y3b = (unsigned short*)(W + 24117248); // 2048*256*32 bf16 (33.6 MB, region holds 67 MB)
  float* p4   = W + 0;                 //  3,211,264  (2048*49*32) -> ends 3,211,264
  // line-padded stats arena lives in the verified-free gap [3211264, 3407872):
  //   6 layers x 8192 floats + 8-copy nms (256) = 49,408 floats -> ends 3,260,672 < 3,407,872.
  float* st   = W + 3211264;
  float* nmsa = st + 6*8192;
  float* y5   = W + 3407872;           //  6,422,528  (2048*49*64)
  float* y6   = W + 10223616;          //  6,422,528
  unsigned short* p6b = (unsigned short*)(W + 16646144); // 2048*1024 bf16
  unsigned short* wb5 = (unsigned short*)(W + 40894464);  // 9*64*32 bf16
  unsigned short* wb6 = (unsigned short*)(W + 40912896);  // 9*64*64 bf16
  unsigned short* wb4 = (unsigned short*)(W + 40931328);  // 9*32*32 bf16
  unsigned short* Bl = (unsigned short*)(W + 40951808);   // 256*1024 bf16
  float* part = W + 41082880;          //  81,920 (2048*4*10)
  unsigned short* B2 = (unsigned short*)(W + 41164800);   // 5*16*32 bf16 (1280 floats)
  unsigned short* B3 = (unsigned short*)(W + 41166080);   // 5*32*32 bf16 (2560 floats)

  hipMemsetAsync(st, 0, 49408*sizeof(float), stream);

  k_pre<<<1819,256,0,stream>>>(x, w1, w2, w3, w4, w5, w6, w7,
                               B2, B3, wb4, wb5, wb6, Bl, st + 0*8192);

  k_conv2m<<<2048,256,0,stream>>>(x, w1, B2, st + 0*8192, g1, b1, p2b, st + 1*8192);

  k_conv3m<<<2048,256,0,stream>>>(p2b, B3, st + 1*8192, g2, b2, y3b, st + 2*8192);

  k_conv4m<<<2048,256,0,stream>>>(y3b, wb4, st + 2*8192, g3, b3, p4, st + 3*8192, nmsa);

  k_conv56m<32><<<512,256,0,stream>>>(p4, wb5, st + 3*8192, g4, b4, 1.f/401408.f, y5, st + 4*8192);

  k_conv56m<64><<<512,256,0,stream>>>(y5, wb6, st + 4*8192, g5, b5, 1.f/100352.f, y6, st + 5*8192);

  k_pool6<<<8192,256,0,stream>>>(y6, st + 5*8192, g6, b6, p6b);

  k_gemm7<<<128,256,0,stream>>>(p6b, Bl, part);
  k_logits<<<80,256,0,stream>>>(part, b7, nmsa, out);
}

// Round 7
// 344.117 us; speedup vs baseline: 1.0424x; 1.0224x over previous
//
#include <hip/hip_runtime.h>

static constexpr int NB = 2048;
static constexpr float SENT = -1e30f;

typedef __attribute__((ext_vector_type(8))) short bf16x8;
typedef __attribute__((ext_vector_type(8))) unsigned short u16x8;
typedef __attribute__((ext_vector_type(4))) float f32x4;

// Stats arena: layer slot = 8192 floats. Line-padded atomics:
//   addr(ch, kind, copy) = base + (ch*4 + copy)*32 + kind*8   (kind 0=sum, 1=sumsq; copy 0..3)
#define ST_ADDR(base, ch, kind, copy) ((base) + (((ch)*4 + (copy))*32 + (kind)*8))

// rotated-3x3 tap permutation: weight tap k of rotation r lands at patch position DST[r][k]
static constexpr int DST[8][9] = {
  {8,7,6,5,4,3,2,1,0},
  {5,8,7,2,4,6,1,0,3},
  {2,5,8,1,4,7,0,3,6},
  {1,2,5,0,4,8,3,6,7},
  {0,1,2,3,4,5,6,7,8},
  {3,0,1,6,4,2,7,8,5},
  {6,3,0,7,4,1,8,5,2},
  {7,6,3,8,4,0,5,2,1},
};

__device__ __forceinline__ unsigned short f2bf(float f){
  unsigned int u = __float_as_uint(f);
  u += 0x7fffu + ((u>>16)&1u);          // RNE
  return (unsigned short)(u>>16);
}

__device__ __forceinline__ float bf2f(unsigned short h){
  return __uint_as_float((unsigned int)h << 16);
}

// 2×f32 -> packed 2×bf16 in ONE instruction (gfx950; no builtin exposed)
__device__ __forceinline__ unsigned int cvtpk(float lo, float hi){
  unsigned int r;
  asm("v_cvt_pk_bf16_f32 %0, %1, %2" : "=v"(r) : "v"(lo), "v"(hi));
  return r;
}

// bn+relu+requant for a packed bf16 pair held in one u32 word
__device__ __forceinline__ unsigned int bnpair(unsigned int w, float a0, float b0, float a1, float b1){
  float vlo = __uint_as_float(w << 16);
  float vhi = __uint_as_float(w & 0xFFFF0000u);
  float r0 = fmaxf(vlo*a0 + b0, 0.f);
  float r1 = fmaxf(vhi*a1 + b1, 0.f);
  return cvtpk(r0, r1);
}

__device__ __forceinline__ float st_read(const float* base, int ch, int kind){
  return base[((ch*4+0)*32 + kind*8)] + base[((ch*4+1)*32 + kind*8)]
       + base[((ch*4+2)*32 + kind*8)] + base[((ch*4+3)*32 + kind*8)];
}

// border cell index (16x16 plane) for border id t<60
__device__ __forceinline__ int border_cell(int t){
  if (t<16) return t;
  if (t<32) return 240 + (t-16);
  if (t<46) return (t-31)*16;
  return (t-45)*16 + 15;
}

// ---------------- pre: weight packs (blocks 0..282) + conv7 B (283..1306) + bn1 stats (1307..1818) ----------------
__global__ __launch_bounds__(256) void k_pre(const float* __restrict__ x, const float* __restrict__ w1,
                                             const float* __restrict__ w2, const float* __restrict__ w3,
                                             const float* __restrict__ w4,
                                             const float* __restrict__ w5, const float* __restrict__ w6,
                                             const float* __restrict__ w7,
                                             unsigned short* __restrict__ B2,
                                             unsigned short* __restrict__ B3,
                                             unsigned short* __restrict__ wb4,
                                             unsigned short* __restrict__ wb5, unsigned short* __restrict__ wb6,
                                             unsigned short* __restrict__ Bl,
                                             float* __restrict__ st){
  int blk = blockIdx.x;
  if (blk < 283){
    int i = blk*256 + threadIdx.x;
    if (i < 18432){                                  // 9*64*32
      int tap = i/2048, rem = i%2048, oc = rem/32, ci = rem%32;
      wb5[i] = f2bf(w5[(oc*32+ci)*9 + tap]);
    } else if (i < 55296){                           // + 9*64*64
      int j = i - 18432;
      int tap = j/4096, rem = j%4096, oc = rem/64, ci = rem%64;
      wb6[j] = f2bf(w6[(oc*64+ci)*9 + tap]);
    } else if (i < 64512){                           // + 9*32*32
      int j = i - 55296;
      int tap = j/1024, rem = j%1024, oc = rem/32, ci = rem%32;
      wb4[j] = f2bf(w4[(oc*32+ci)*9 + tap]);
    } else if (i < 67072){                           // + conv2 tap-pair pack [5][16][32]
      int j = i - 64512;
      int c = j >> 9;
      int rem = j & 511;
      int o = rem >> 5, k = rem & 31;
      int tap = c*2 + (k>>4);
      int ci = k & 15;
      unsigned short v = 0;
      if (tap <= 8){
        int rot = o>>1, u = o&1;
        int bb = ci>>1, ui = ci&1;
        int wc = (((bb - rot) & 7)<<1) | ui;
        int kk = 0;
        #pragma unroll
        for (int q=0;q<9;q++) if (DST[rot][q]==tap) kk=q;
        v = f2bf(w2[(u*16+wc)*9 + kk]);
      }
      B2[j] = v;
    } else if (i < 72192){                           // + conv3 tap-pair pack [5][32][32]
      int j = i - 67072;
      int c = j >> 10;
      int rem = j & 1023;
      int o = rem >> 5, k = rem & 31;
      int tap = c*2 + (k>>4);
      int ci = k & 15;
      unsigned short v = 0;
      if (tap <= 8){
        int rot = o>>2, uh = (o>>1)&1, ul = o&1;
        int bb = ci>>1, ui = ci&1;
        int wc = (((bb - rot) & 7)<<1) | ui;
        int kk = 0;
        #pragma unroll
        for (int q=0;q<9;q++) if (DST[rot][q]==tap) kk=q;
        v = f2bf(w3[uh*288 + (ul*16+wc)*9 + kk]);
      }
      B3[j] = v;
    }
    return;
  }
  if (blk < 1307){
    int i = (blk-283)*256 + threadIdx.x;             // 262144 exact
    int n = i>>10, k = i&1023;
    int pos16 = k>>6, ci = k&63;
    int r = pos16>>2, c = pos16&3;
    unsigned short v = 0;
    if (n < 250){
      int pos = n/10, o = n - 10*(n/10);
      int py = pos/5, px = pos - 5*(pos/5);
      int ky = r - py + 2, kx = c - px + 2;
      if (ky>=0 && ky<4 && kx>=0 && kx<4) v = f2bf(w7[(o*64+ci)*16 + ky*4 + kx]);
    }
    Bl[i] = v;
    return;
  }
  // ---- bn1 stats over y1 = rotconv1(x); w1 (18 floats) in registers, rotation = compile-time tap permutation ----
  __shared__ float red[4][32];
  float wa[18];
  #pragma unroll
  for (int i=0;i<18;i++) wa[i] = w1[i];
  float s[16], s2[16];
  #pragma unroll
  for (int o=0;o<16;o++){ s[o]=0.f; s2[o]=0.f; }
  for (int idx = (blk-1307)*256 + threadIdx.x; idx < NB*784; idx += 512*256){
    int b = idx/784, pix = idx-b*784;
    int py = pix/28, px = pix-py*28;
    const float* xb = x + (size_t)b*784;
    float tap[9];
    #pragma unroll
    for (int d=0; d<9; d++){
      int dy = d/3-1, dx = d%3-1;
      int yy = py+dy, xx = px+dx;
      tap[d] = (yy>=0 && yy<28 && xx>=0 && xx<28) ? xb[yy*28+xx] : 0.f;
    }
    #pragma unroll
    for (int rot=0; rot<8; rot++){
      #pragma unroll
      for (int u=0; u<2; u++){
        float y = 0.f;
        #pragma unroll
        for (int k=0; k<9; k++) y += wa[u*9+k]*tap[DST[rot][k]];
        int ci = rot*2+u;
        s[ci] += y; s2[ci] += y*y;
      }
    }
  }
  int wid = threadIdx.x>>6;
  #pragma unroll
  for (int o=0;o<16;o++){
    float a = s[o], b2 = s2[o];
    #pragma unroll
    for (int off=32; off; off>>=1){ a += __shfl_down(a,off); b2 += __shfl_down(b2,off); }
    if ((threadIdx.x&63)==0){ red[wid][o] = a; red[wid][16+o] = b2; }
  }
  __syncthreads();
  if (threadIdx.x < 32){
    float v = red[0][threadIdx.x]+red[1][threadIdx.x]+red[2][threadIdx.x]+red[3][threadIdx.x];
    int ch = threadIdx.x & 15, kind = threadIdx.x >> 4;
    atomicAdd(ST_ADDR(st, ch, kind, blk & 3), v);
  }
}

// ---------------- conv2 MFMA: recompute y1 from x in-block; bn1 coef in-block; p2 OUTPUT AS BF16 ----------------
__global__ __launch_bounds__(256, 2) void k_conv2m(const float* __restrict__ x,
                                                   const float* __restrict__ w1,
                                                   const unsigned short* __restrict__ B2,  // [5][16][32] bf16
                                                   const float* __restrict__ stin,   // bn1 sums (layer0)
                                                   const float* __restrict__ g1, const float* __restrict__ b1,
                                                   unsigned short* __restrict__ p2b,
                                                   float* __restrict__ stout){
  __shared__ float smemf[8640];
  __shared__ float cab[32];                      // ca[0:16], cb[16:32]
  __shared__ float red[4][32];
  unsigned short* Ls = (unsigned short*)smemf;
  float* xs = smemf + 7680;
  float* out2 = smemf;
  int t = threadIdx.x;
  int wid = t>>6, lane = t&63;
  int quad = lane>>4, m = lane&15;
  float wa[18];
  #pragma unroll
  for (int i=0;i<18;i++) wa[i] = w1[i];
  if (t < 16){
    const float invN = 1.f/1605632.f;
    float mu = st_read(stin, t, 0)*invN;
    float var = st_read(stin, t, 1)*invN - mu*mu;
    float a = g1[t&1]*rsqrtf(var + 1e-5f);
    cab[t] = a; cab[16+t] = b1[t&1] - mu*a;
  }
  int b = blockIdx.x;
  for (int i=t; i<960; i+=256){
    int r = i>>5, c = i&31;
    int iy = r-1, ix = c-1;
    xs[i] = (iy>=0 && iy<28 && ix>=0 && ix<28) ? x[(size_t)b*784 + iy*28 + ix] : 0.f;
  }
  for (int i=t; i<3840; i+=256) ((unsigned long long*)Ls)[i] = 0ULL;
  __syncthreads();
  for (int i=t; i<784; i+=256){
    int py = i/28, px = i - 28*(i/28);
    float tap[9];
    #pragma unroll
    for (int d=0; d<9; d++) tap[d] = xs[(py + d/3)*32 + px + d%3];
    float y[16];
    #pragma unroll
    for (int rot=0; rot<8; rot++){
      #pragma unroll
      for (int u=0; u<2; u++){
        float acc1 = 0.f;
        #pragma unroll
        for (int k=0; k<9; k++) acc1 += wa[u*9+k]*tap[DST[rot][k]];
        y[rot*2+u] = acc1;
      }
    }
    unsigned long long pk[4];
    #pragma unroll
    for (int q=0; q<4; q++){
      float4 A = *(const float4*)(cab + q*4);
      float4 Bv = *(const float4*)(cab + 16 + q*4);
      float r0 = fmaxf(y[q*4+0]*A.x + Bv.x, 0.f);
      float r1 = fmaxf(y[q*4+1]*A.y + Bv.y, 0.f);
      float r2 = fmaxf(y[q*4+2]*A.z + Bv.z, 0.f);
      float r3 = fmaxf(y[q*4+3]*A.w + Bv.w, 0.f);
      unsigned int lo = cvtpk(r0, r1);
      unsigned int hi = cvtpk(r2, r3);
      pk[q] = (unsigned long long)lo | ((unsigned long long)hi<<32);
    }
    int cell = (py+1)*32 + px + 1;
    unsigned long long* dstp = (unsigned long long*)(Ls + cell*16);
    dstp[0]=pk[0]; dstp[1]=pk[1]; dstp[2]=pk[2]; dstp[3]=pk[3];
  }
  __syncthreads();
  // hoisted per-j LDS element offsets; tap deltas are compile-time immediates
  int jb[13];
  #pragma unroll
  for (int j=0;j<13;j++){
    int mt = wid + 4*j;
    int pos = (mt < 49) ? (mt*16 + m) : 0;
    int py = pos/28, px = pos - 28*py;
    jb[j] = (py*32 + px)*16 + (quad&1)*8;
  }
  f32x4 acc[13];
  #pragma unroll
  for (int j=0;j<13;j++) acc[j] = (f32x4){0.f,0.f,0.f,0.f};
  #pragma unroll
  for (int c=0;c<5;c++){
    const int tapA = 2*c, tapB = (2*c+1 < 9) ? 2*c+1 : 8;
    const int offA = ((tapA/3)*32 + tapA%3)*16;
    const int offB = ((tapB/3)*32 + tapB%3)*16;
    int sel = (quad < 2) ? offA : offB;
    bf16x8 Bf = *(const bf16x8*)(B2 + (c*16 + m)*32 + quad*8);
    #pragma unroll
    for (int j=0;j<13;j++){
      int mt = wid + 4*j;
      if (mt >= 49) continue;
      bf16x8 Af = *(const bf16x8*)(Ls + jb[j] + sel);
      acc[j] = __builtin_amdgcn_mfma_f32_16x16x32_bf16(Af, Bf, acc[j], 0, 0, 0);
    }
  }
  __syncthreads();   // done reading Ls; reuse as out2
  float s = 0.f, sq = 0.f;
  #pragma unroll
  for (int j=0;j<13;j++){
    int mt = wid + 4*j;
    if (mt >= 49) continue;
    #pragma unroll
    for (int p=0;p<2;p++){
      // pos0 = mt*16 + quad*4 + 2p is even and never wraps a row: (r0,r1) horizontal pool pair
      int pos0 = mt*16 + quad*4 + p*2;
      float v0 = acc[j][2*p], v1 = acc[j][2*p+1];
      s += v0 + v1; sq += v0*v0 + v1*v1;
      float hm = fmaxf(v0, v1);
      int py = pos0/28, px2 = (pos0 - py*28)>>1;
      out2[(py*14+px2)*17 + m] = hm;
    }
  }
  s += __shfl_down(s,32);  s += __shfl_down(s,16);
  sq += __shfl_down(sq,32); sq += __shfl_down(sq,16);
  if (lane < 16){ red[wid][m] = s; red[wid][16+m] = sq; }
  __syncthreads();
  if (t < 32){
    float v = red[0][t]+red[1][t]+red[2][t]+red[3][t];
    int ch = t & 15, kind = t >> 4;
    atomicAdd(ST_ADDR(stout, ch, kind, b & 3), v);
  }
  unsigned short* pb = p2b + (size_t)b*4096;
  for (int i=t; i<3136; i+=256){
    int cell = i>>4, oc = i&15;
    int yo = cell/14, xo = cell - yo*14;
    float mx = fmaxf(out2[((2*yo)*14+xo)*17 + oc], out2[((2*yo+1)*14+xo)*17 + oc]);
    pb[((yo+1)*16 + xo + 1)*16 + oc] = f2bf(mx);
  }
  for (int i=t; i<960; i+=256){
    int bc = border_cell(i>>4), oc = i&15;
    pb[bc*16 + oc] = f2bf(SENT);
  }
}

// ---------------- conv3 MFMA: 16->32 rotated over 14x14, bn2 coef in-block; BF16 I/O, packed decode/encode ----------------
__global__ __launch_bounds__(256, 2) void k_conv3m(const unsigned short* __restrict__ p2b,
                                                   const unsigned short* __restrict__ B3,  // [5][32][32] bf16
                                                   const float* __restrict__ stin,
                                                   const float* __restrict__ g2, const float* __restrict__ b2,
                                                   unsigned short* __restrict__ y3b,
                                                   float* __restrict__ stout){
  __shared__ unsigned short Ls[256*16];
  __shared__ float ca[16], cb[16];
  __shared__ float red[4][64];
  int t = threadIdx.x;
  int wid = t>>6, lane = t&63;
  int quad = lane>>4, m = lane&15;
  int b = blockIdx.x;
  // staging loads issued FIRST so HBM latency overlaps the stats/coef phase
  const unsigned short* sb = p2b + (size_t)b*4096;
  uint4 Uw0 = *(const uint4*)(sb + (size_t)t*16);
  uint4 Uw1 = *(const uint4*)(sb + (size_t)t*16 + 8);
  if (t < 16){
    const float invN = 1.f/1605632.f;
    float mu = st_read(stin, t, 0)*invN;
    float var = st_read(stin, t, 1)*invN - mu*mu;
    float a = g2[t&1]*rsqrtf(var + 1e-5f);
    ca[t] = a; cb[t] = b2[t&1] - mu*a;
  }
  __syncthreads();
  {
    unsigned int p0 = bnpair(Uw0.x, ca[0],cb[0], ca[1],cb[1]);
    unsigned int p1 = bnpair(Uw0.y, ca[2],cb[2], ca[3],cb[3]);
    unsigned int p2 = bnpair(Uw0.z, ca[4],cb[4], ca[5],cb[5]);
    unsigned int p3 = bnpair(Uw0.w, ca[6],cb[6], ca[7],cb[7]);
    unsigned int p4 = bnpair(Uw1.x, ca[8],cb[8], ca[9],cb[9]);
    unsigned int p5 = bnpair(Uw1.y, ca[10],cb[10], ca[11],cb[11]);
    unsigned int p6 = bnpair(Uw1.z, ca[12],cb[12], ca[13],cb[13]);
    unsigned int p7 = bnpair(Uw1.w, ca[14],cb[14], ca[15],cb[15]);
    unsigned long long* dstp = (unsigned long long*)(Ls + t*16);
    dstp[0] = (unsigned long long)p0 | ((unsigned long long)p1<<32);
    dstp[1] = (unsigned long long)p2 | ((unsigned long long)p3<<32);
    dstp[2] = (unsigned long long)p4 | ((unsigned long long)p5<<32);
    dstp[3] = (unsigned long long)p6 | ((unsigned long long)p7<<32);
  }
  __syncthreads();
  int jb[4]; bool vt[4];
  #pragma unroll
  for (int j=0;j<4;j++){
    int mt = wid + 4*j;
    int pos = mt*16 + m;
    vt[j] = (mt <= 12);
    if (pos >= 196) pos = 0;
    int py = pos/14, px = pos - 14*(pos/14);
    jb[j] = (py*16 + px)*16 + (quad&1)*8;
  }
  unsigned short* yb = y3b + (size_t)b*8192;
  float sa[2], sqa[2];
  #pragma unroll
  for (int nt=0; nt<2; nt++){
    f32x4 acc[4];
    #pragma unroll
    for (int j=0;j<4;j++) acc[j] = (f32x4){0.f,0.f,0.f,0.f};
    #pragma unroll
    for (int c=0;c<5;c++){
      const int tapA = 2*c, tapB = (2*c+1 < 9) ? 2*c+1 : 8;
      const int offA = ((tapA/3)*16 + tapA%3)*16;
      const int offB = ((tapB/3)*16 + tapB%3)*16;
      int sel = (quad < 2) ? offA : offB;
      bf16x8 Bf = *(const bf16x8*)(B3 + (c*32 + nt*16 + m)*32 + quad*8);
      #pragma unroll
      for (int j=0;j<4;j++){
        if (!vt[j]) continue;
        bf16x8 Af = *(const bf16x8*)(Ls + jb[j] + sel);
        acc[j] = __builtin_amdgcn_mfma_f32_16x16x32_bf16(Af, Bf, acc[j], 0, 0, 0);
      }
    }
    float s = 0.f, sq = 0.f;
    #pragma unroll
    for (int j=0;j<4;j++){
      if (!vt[j]) continue;
      int mt = wid + 4*j;
      #pragma unroll
      for (int r=0;r<4;r++){
        int pos = mt*16 + quad*4 + r;
        if (pos < 196){
          float v = acc[j][r];
          int py2 = pos/14, px2 = pos - py2*14;
          yb[(size_t)((py2+1)*16 + px2 + 1)*32 + nt*16 + m] = f2bf(v);
          s += v; sq += v*v;
        }
      }
    }
    s += __shfl_down(s,32);  s += __shfl_down(s,16);
    sq += __shfl_down(sq,32); sq += __shfl_down(sq,16);
    sa[nt] = s; sqa[nt] = sq;
  }
  if (lane < 16){
    red[wid][m]      = sa[0];  red[wid][32+m]      = sqa[0];
    red[wid][16+m]   = sa[1];  red[wid][32+16+m]   = sqa[1];
  }
  __syncthreads();
  if (t < 64){
    float v = red[0][t]+red[1][t]+red[2][t]+red[3][t];
    int ch = t & 31, kind = t >> 5;
    atomicAdd(ST_ADDR(stout, ch, kind, b & 3), v);
  }
  for (int i=t; i<1920; i+=256){
    int bc = border_cell(i>>5), oc = i&31;
    yb[(size_t)bc*32 + oc] = f2bf(SENT);
  }
}

// ---------------- conv4 MFMA: 32->32 over 14x14, bn3 coef in-block, FUSED NMS; packed decode, unrolled taps ----------------
__global__ __launch_bounds__(256, 2) void k_conv4m(const unsigned short* __restrict__ y3b,
                                                   const unsigned short* __restrict__ wb4, // [9][32][32] bf16
                                                   const float* __restrict__ stin,
                                                   const float* __restrict__ g3, const float* __restrict__ b3,
                                                   float* __restrict__ p4,
                                                   float* __restrict__ stout,
                                                   float* __restrict__ nmsa){
  __shared__ unsigned short L[256*40];   // 20480 B
  __shared__ float hp[98*33];            // 12936 B, horizontal pool staging
  __shared__ float ca[32], cb[32];
  __shared__ float red[4][64];
  __shared__ float nred[4];
  int t = threadIdx.x;
  int wid = t>>6, lane = t&63;
  int quad = lane>>4, m = lane&15;
  int b = blockIdx.x;
  // staging loads issued FIRST so HBM latency overlaps the stats/coef phase
  const unsigned short* sb = y3b + (size_t)b*8192;
  uint4 Uw[4];
  #pragma unroll
  for (int it=0; it<4; it++) Uw[it] = *(const uint4*)(sb + (size_t)t*32 + it*8);
  if (t < 32){
    const float invN = 1.f/401408.f;
    float mu = st_read(stin, t, 0)*invN;
    float var = st_read(stin, t, 1)*invN - mu*mu;
    float a = g3[t&3]*rsqrtf(var + 1e-5f);
    ca[t] = a; cb[t] = b3[t&3] - mu*a;
  }
  __syncthreads();
  #pragma unroll
  for (int it=0; it<4; it++){
    int c0 = it*8;
    unsigned int p0 = bnpair(Uw[it].x, ca[c0+0],cb[c0+0], ca[c0+1],cb[c0+1]);
    unsigned int p1 = bnpair(Uw[it].y, ca[c0+2],cb[c0+2], ca[c0+3],cb[c0+3]);
    unsigned int p2 = bnpair(Uw[it].z, ca[c0+4],cb[c0+4], ca[c0+5],cb[c0+5]);
    unsigned int p3 = bnpair(Uw[it].w, ca[c0+6],cb[c0+6], ca[c0+7],cb[c0+7]);
    *(unsigned long long*)(L + t*40 + it*8)     = (unsigned long long)p0 | ((unsigned long long)p1<<32);
    *(unsigned long long*)(L + t*40 + it*8 + 4) = (unsigned long long)p2 | ((unsigned long long)p3<<32);
  }
  __syncthreads();
  float nloc = 0.f;
  for (int i=t; i<784; i+=256){
    int hw = i>>2, c4 = i&3;
    int cell = (hw/14 + 1)*16 + hw%14 + 1;
    const unsigned int* g32 = (const unsigned int*)(L + cell*40 + c4*8);
    unsigned int w0 = g32[0], w1 = g32[1], w2 = g32[2], w3 = g32[3];
    float v[8];
    v[0] = __uint_as_float(w0 << 16); v[1] = __uint_as_float(w0 & 0xFFFF0000u);
    v[2] = __uint_as_float(w1 << 16); v[3] = __uint_as_float(w1 & 0xFFFF0000u);
    v[4] = __uint_as_float(w2 << 16); v[5] = __uint_as_float(w2 & 0xFFFF0000u);
    v[6] = __uint_as_float(w3 << 16); v[7] = __uint_as_float(w3 & 0xFFFF0000u);
    float vmax = -1e30f;
    #pragma unroll
    for (int r=0;r<8;r++) vmax = fmaxf(vmax, v[r]);
    #pragma unroll
    for (int r=0;r<8;r++) nloc += (v[r] != vmax) ? v[r] : 0.f;
  }
  #pragma unroll
  for (int off=32; off; off>>=1) nloc += __shfl_down(nloc, off);
  if (lane == 0) nred[wid] = nloc;
  int jb[4]; bool vt[4];
  #pragma unroll
  for (int j=0;j<4;j++){
    int mt = wid + 4*j;
    int pos = mt*16 + m;
    vt[j] = (mt <= 12);
    if (pos >= 196) pos = 0;
    int py = pos/14, px = pos - 14*(pos/14);
    jb[j] = (py*16 + px)*40 + quad*8;
  }
  float sa[2], sqa[2];
  #pragma unroll
  for (int nt=0; nt<2; nt++){
    f32x4 acc[4];
    #pragma unroll
    for (int j=0;j<4;j++) acc[j] = (f32x4){0.f,0.f,0.f,0.f};
    const unsigned short* wbp = wb4 + (nt*16 + m)*32 + quad*8;
    #pragma unroll
    for (int tap=0; tap<9; tap++){
      const int dy = tap/3, dx = tap - 3*(tap/3);
      const int doff = (dy*16 + dx)*40;
      bf16x8 Bf = *(const bf16x8*)(wbp + tap*1024);
      bf16x8 Af[4];
      #pragma unroll
      for (int j=0;j<4;j++)
        Af[j] = *(const bf16x8*)(L + jb[j] + doff);
      #pragma unroll
      for (int j=0;j<4;j++){
        if (!vt[j]) continue;
        acc[j] = __builtin_amdgcn_mfma_f32_16x16x32_bf16(Af[j], Bf, acc[j], 0, 0, 0);
      }
    }
    float s = 0.f, sq = 0.f;
    #pragma unroll
    for (int j=0;j<4;j++){
      if (!vt[j]) continue;
      int mt = wid + 4*j;
      #pragma unroll
      for (int p=0;p<2;p++){
        // pos0 even -> px even -> (v0,v1) is a horizontal 2x2-pool pair
        int pos0 = mt*16 + quad*4 + 2*p;
        if (pos0 + 1 < 196){
          float v0 = acc[j][2*p], v1 = acc[j][2*p+1];
          s += v0 + v1; sq += v0*v0 + v1*v1;
          float hm = fmaxf(v0, v1);
          int py0 = pos0/14, pxh = (pos0 - py0*14)>>1;
          hp[(py0*7 + pxh)*33 + nt*16 + m] = hm;
        }
      }
    }
    s += __shfl_down(s,32);  s += __shfl_down(s,16);
    sq += __shfl_down(sq,32); sq += __shfl_down(sq,16);
    sa[nt] = s; sqa[nt] = sq;
  }
  if (lane < 16){
    red[wid][m]      = sa[0];  red[wid][32+m]      = sqa[0];
    red[wid][16+m]   = sa[1];  red[wid][32+16+m]   = sqa[1];
  }
  __syncthreads();
  if (t == 0) atomicAdd(&nmsa[(b & 7)*32], nred[0]+nred[1]+nred[2]+nred[3]);
  if (t < 64){
    float v = red[0][t]+red[1][t]+red[2][t]+red[3][t];
    int ch = t & 31, kind = t >> 5;
    atomicAdd(ST_ADDR(stout, ch, kind, b & 3), v);
  }
  for (int i=t; i<1568; i+=256){
    int cell = i>>5, oc = i&31;
    int yo = cell/7, xo = cell - yo*7;
    float mx = fmaxf(hp[((2*yo)*7 + xo)*33 + oc], hp[((2*yo+1)*7 + xo)*33 + oc]);
    p4[((size_t)b*49 + cell)*32 + oc] = mx;
  }
}

// ---------------- conv5/conv6 MFMA: CI->64, per-wave batch, bn coef in-block, shift-GEMM over 9 taps ----------------
template<int CI>
__global__ __launch_bounds__(256, 2) void k_conv56m(const float* __restrict__ src,
                                                    const unsigned short* __restrict__ wb,  // [9][64][CI] bf16
                                                    const float* __restrict__ stin,
                                                    const float* __restrict__ g, const float* __restrict__ be,
                                                    float invN,
                                                    float* __restrict__ dst,
                                                    float* __restrict__ stout){
  constexpr int CIP = CI + 8;
  constexpr int KC = CI/32;
  __shared__ unsigned short lin[4][81*CIP];
  __shared__ float red[4][256];
  __shared__ float ca[CI], cb[CI];
  int wid = threadIdx.x>>6, lane = threadIdx.x&63;
  int quad = lane>>4, m = lane&15;
  unsigned short* L = lin[wid];
  if (threadIdx.x < CI){
    int i = threadIdx.x;
    float mu = st_read(stin, i, 0)*invN;
    float var = st_read(stin, i, 1)*invN - mu*mu;
    float a = g[i]*rsqrtf(var + 1e-5f);
    ca[i] = a; cb[i] = be[i] - mu*a;
  }
  for (int i = lane; i < 81*CIP/4; i += 64) ((unsigned long long*)L)[i] = 0ULL;
  __syncthreads();
  int b = blockIdx.x*4 + wid;
  const float* sb = src + (size_t)b*49*CI;
  for (int i = lane; i < 49*CI/4; i += 64){
    int pos = i/(CI/4), cig = i - pos*(CI/4);
    float4 v = *(const float4*)(sb + pos*CI + cig*4);
    float r0 = fmaxf(v.x*ca[cig*4]  +cb[cig*4],   0.f);
    float r1 = fmaxf(v.y*ca[cig*4+1]+cb[cig*4+1], 0.f);
    float r2 = fmaxf(v.z*ca[cig*4+2]+cb[cig*4+2], 0.f);
    float r3 = fmaxf(v.w*ca[cig*4+3]+cb[cig*4+3], 0.f);
    int pos9 = (pos/7 + 1)*9 + pos%7 + 1;
    unsigned int lo = cvtpk(r0, r1);
    unsigned int hi = cvtpk(r2, r3);
    *(unsigned long long*)(L + pos9*CIP + cig*4) =
        (unsigned long long)lo | ((unsigned long long)hi<<32);
  }
  __syncthreads();
  int py[4], px[4];
  #pragma unroll
  for (int mt=0; mt<4; mt++){
    int pos = mt*16 + m;
    if (pos < 49){ py[mt] = pos/7; px[mt] = pos%7; }
    else { py[mt] = 0; px[mt] = 0; }
  }
  f32x4 acc[4][4];
  #pragma unroll
  for (int nt=0; nt<4; nt++)
    #pragma unroll
    for (int mt=0; mt<4; mt++) acc[nt][mt] = (f32x4){0.f,0.f,0.f,0.f};

  for (int tap=0; tap<9; tap++){
    int dy = tap/3, dx = tap - dy*3;
    int o9[4];
    #pragma unroll
    for (int mt=0; mt<4; mt++) o9[mt] = ((py[mt]+dy)*9 + px[mt]+dx)*CIP;
    #pragma unroll
    for (int kc=0; kc<KC; kc++){
      int ko = kc*32 + quad*8;
      bf16x8 Bf[4], Af[4];
      #pragma unroll
      for (int nt=0; nt<4; nt++)
        Bf[nt] = *(const bf16x8*)(wb + (tap*64 + nt*16 + m)*CI + ko);
      #pragma unroll
      for (int mt=0; mt<4; mt++)
        Af[mt] = *(const bf16x8*)(L + o9[mt] + ko);
      #pragma unroll
      for (int nt=0; nt<4; nt++)
        #pragma unroll
        for (int mt=0; mt<4; mt++)
          acc[nt][mt] = __builtin_amdgcn_mfma_f32_16x16x32_bf16(Af[mt], Bf[nt], acc[nt][mt], 0, 0, 0);
    }
  }
  float* db = dst + (size_t)b*49*64;
  float snt[4], sqnt[4];
  #pragma unroll
  for (int nt=0; nt<4; nt++){
    float s = 0.f, sq = 0.f;
    #pragma unroll
    for (int mt=0; mt<4; mt++){
      #pragma unroll
      for (int r=0; r<4; r++){
        int pos = mt*16 + quad*4 + r;
        if (pos < 49){
          float v = acc[nt][mt][r];
          db[pos*64 + nt*16 + m] = v;
          s += v; sq += v*v;
        }
      }
    }
    s += __shfl_down(s, 32);  s += __shfl_down(s, 16);
    sq += __shfl_down(sq, 32); sq += __shfl_down(sq, 16);
    snt[nt] = s; sqnt[nt] = sq;
  }
  if (lane < 16){
    #pragma unroll
    for (int nt=0; nt<4; nt++){
      red[wid][nt*16 + lane] = snt[nt];
      red[wid][128 + nt*16 + lane] = sqnt[nt];
    }
  }
  __syncthreads();
  if (threadIdx.x < 128){
    int c = threadIdx.x & 63;
    int off = (threadIdx.x < 64) ? threadIdx.x : (128 + c);
    float v = red[0][off]+red[1][off]+red[2][off]+red[3][off];
    int kind = (threadIdx.x < 64) ? 0 : 1;
    atomicAdd(ST_ADDR(stout, c, kind, blockIdx.x & 3), v);
  }
}

// ---------------- bn6+relu + 2x2 pool pad 1 (7 -> 4); bn6 coef per-thread; y6 -> p6b bf16 ----------------
__global__ __launch_bounds__(256) void k_pool6(const float* __restrict__ y,
                                               const float* __restrict__ stin,
                                               const float* __restrict__ g6, const float* __restrict__ b6,
                                               unsigned short* __restrict__ p6b){
  int idx = blockIdx.x*256 + threadIdx.x;       // NB*16*64 exact
  int oc = idx & 63; int t2 = idx >> 6;
  int xo = t2 & 3;  int yo = (t2>>2) & 3;  int b = t2 >> 4;
  const float invN = 1.f/100352.f;
  float mu = st_read(stin, oc, 0)*invN;
  float var = st_read(stin, oc, 1)*invN - mu*mu;
  float a = g6[oc]*rsqrtf(var + 1e-5f);
  float bo = b6[oc] - mu*a;
  const float* src = y + (size_t)b*3136;
  float mx = -1e30f;
  #pragma unroll
  for (int dy=0;dy<2;dy++){
    int iy = yo*2 - 1 + dy;
    if (iy < 0 || iy >= 7) continue;
    #pragma unroll
    for (int dx=0;dx<2;dx++){
      int ix = xo*2 - 1 + dx;
      if (ix < 0 || ix >= 7) continue;
      mx = fmaxf(mx, src[(iy*7+ix)*64 + oc]*a + bo);
    }
  }
  p6b[(size_t)b*1024 + (yo*4 + xo)*64 + oc] = f2bf(fmaxf(mx, 0.f));
}

// ---------------- conv7 as GEMM: M=2048 (batch), N=256 (pos25*10+o), K=1024; partial max per N-block ----------------
__global__ __launch_bounds__(256) void k_gemm7(const unsigned short* __restrict__ A,   // [2048][1024] bf16
                                               const unsigned short* __restrict__ Bl,  // [256][1024] bf16
                                               float* __restrict__ part){              // [2048][4][10]
  __shared__ float Lw[4][16*65];
  int wid = threadIdx.x>>6, lane = threadIdx.x&63;
  int quad = lane>>4, m = lane&15;
  int blkm = blockIdx.x >> 2, blkn = blockIdx.x & 3;   // grid 128
  int rowb = blkm*64 + wid*16 + m;
  const unsigned short* Arow = A + (size_t)rowb*1024;
  f32x4 acc[4];
  #pragma unroll
  for (int nt=0; nt<4; nt++) acc[nt] = (f32x4){0.f,0.f,0.f,0.f};
  for (int kc=0; kc<32; kc++){
    bf16x8 Af = *(const bf16x8*)(Arow + kc*32 + quad*8);
    #pragma unroll
    for (int nt=0; nt<4; nt++){
      bf16x8 Bf = *(const bf16x8*)(Bl + (size_t)(blkn*64 + nt*16 + m)*1024 + kc*32 + quad*8);
      acc[nt] = __builtin_amdgcn_mfma_f32_16x16x32_bf16(Af, Bf, acc[nt], 0, 0, 0);
    }
  }
  float* Lp = &Lw[wid][0];
  #pragma unroll
  for (int nt=0; nt<4; nt++)
    #pragma unroll
    for (int r=0; r<4; r++)
      Lp[(quad*4+r)*65 + nt*16 + m] = acc[nt][r];
  __syncthreads();
  for (int i=lane; i<160; i+=64){
    int br = i/10, o = i - 10*(i/10);
    int c0 = ((o - blkn*64) % 10 + 10) % 10;
    float mx = -1e30f;
    for (int c=c0; c<64; c+=10){
      if (blkn*64 + c < 250) mx = fmaxf(mx, Lp[br*65 + c]);
    }
    part[((size_t)(blkm*64 + wid*16 + br)*4 + blkn)*10 + o] = mx;
  }
}

// ---------------- logits: max over 4 N-block partials + bias; nms write ----------------
__global__ __launch_bounds__(256) void k_logits(const float* __restrict__ part,
                                                const float* __restrict__ bias,
                                                const float* __restrict__ nmsa,
                                                float* __restrict__ out){
  int idx = blockIdx.x*256 + threadIdx.x;       // 20480 exact (80 blocks)
  int b = idx/10, o = idx - 10*(idx/10);
  const float* p = part + (size_t)b*40 + o;
  float mx = fmaxf(fmaxf(p[0], p[10]), fmaxf(p[20], p[30]));
  out[idx] = mx + bias[o];
  if (blockIdx.x == 0 && threadIdx.x == 0){
    float nm = 0.f;
    #pragma unroll
    for (int cp=0; cp<8; cp++) nm += nmsa[cp*32];
    out[20480] = nm * (1.f/12845056.f);
  }
}

extern "C" void kernel_launch(void* const* d_in, const int* in_sizes, int n_in,
                              void* d_out, int out_size, void* d_ws, size_t ws_size,
                              hipStream_t stream){
  const float* x  = (const float*)d_in[0];
  const float* w1 = (const float*)d_in[1];
  const float* w2 = (const float*)d_in[2];
  const float* w3 = (const float*)d_in[3];
  const float* w4 = (const float*)d_in[4];
  const float* w5 = (const float*)d_in[5];
  const float* w6 = (const float*)d_in[6];
  const float* w7 = (const float*)d_in[7];
  const float* g1 = (const float*)d_in[8];
  const float* b1 = (const float*)d_in[9];
  const float* g2 = (const float*)d_in[10];
  const float* b2 = (const float*)d_in[11];
  const float* g3 = (const float*)d_in[12];
  const float* b3 = (const float*)d_in[13];
  const float* g4 = (const float*)d_in[14];
  const float* b4 = (const float*)d_in[15];
  const float* g5 = (const float*)d_in[16];
  const float* b5 = (const float*)d_in[17];
  const float* g6 = (const float*)d_in[18];
  const float* b6 = (const float*)d_in[19];
  const float* b7 = (const float*)d_in[20];
  float* out = (float*)d_out;
  float* W = (float*)d_ws;

  // arena (float units)
  unsigned short* p2b = (unsigned short*)(W + 15728640); // 2048*256*16 bf16 (16.8 MB, region holds 33.5 MB)
  unsigned short* y3b = (unsigned short*)(W + 24117248); // 2048*256*32 bf16 (33.6 MB, region holds 67 MB)
  float* p4   = W + 0;                 //  3,211,264  (2048*49*32) -> ends 3,211,264
  // line-padded stats arena lives in the verified-free gap [3211264, 3407872):
  //   6 layers x 8192 floats + 8-copy nms (256) = 49,408 floats -> ends 3,260,672 < 3,407,872.
  float* st   = W + 3211264;
  float* nmsa = st + 6*8192;
  float* y5   = W + 3407872;           //  6,422,528  (2048*49*64)
  float* y6   = W + 10223616;          //  6,422,528
  unsigned short* p6b = (unsigned short*)(W + 16646144); // 2048*1024 bf16
  unsigned short* wb5 = (unsigned short*)(W + 40894464);  // 9*64*32 bf16
  unsigned short* wb6 = (unsigned short*)(W + 40912896);  // 9*64*64 bf16
  unsigned short* wb4 = (unsigned short*)(W + 40931328);  // 9*32*32 bf16
  unsigned short* Bl = (unsigned short*)(W + 40951808);   // 256*1024 bf16
  float* part = W + 41082880;          //  81,920 (2048*4*10)
  unsigned short* B2 = (unsigned short*)(W + 41164800);   // 5*16*32 bf16 (1280 floats)
  unsigned short* B3 = (unsigned short*)(W + 41166080);   // 5*32*32 bf16 (2560 floats)

  hipMemsetAsync(st, 0, 49408*sizeof(float), stream);

  k_pre<<<1819,256,0,stream>>>(x, w1, w2, w3, w4, w5, w6, w7,
                               B2, B3, wb4, wb5, wb6, Bl, st + 0*8192);

  k_conv2m<<<2048,256,0,stream>>>(x, w1, B2, st + 0*8192, g1, b1, p2b, st + 1*8192);

  k_conv3m<<<2048,256,0,stream>>>(p2b, B3, st + 1*8192, g2, b2, y3b, st + 2*8192);

  k_conv4m<<<2048,256,0,stream>>>(y3b, wb4, st + 2*8192, g3, b3, p4, st + 3*8192, nmsa);

  k_conv56m<32><<<512,256,0,stream>>>(p4, wb5, st + 3*8192, g4, b4, 1.f/401408.f, y5, st + 4*8192);

  k_conv56m<64><<<512,256,0,stream>>>(y5, wb6, st + 4*8192, g5, b5, 1.f/100352.f, y6, st + 5*8192);

  k_pool6<<<8192,256,0,stream>>>(y6, st + 5*8192, g6, b6, p6b);

  k_gemm7<<<128,256,0,stream>>>(p6b, Bl, part);
  k_logits<<<80,256,0,stream>>>(part, b7, nmsa, out);
}

// Round 9
// 313.195 us; speedup vs baseline: 1.1453x; 1.0987x over previous
//
#include <hip/hip_runtime.h>

static constexpr int NB = 2048;
static constexpr float SENT = -1e30f;

typedef __attribute__((ext_vector_type(8))) short bf16x8;
typedef __attribute__((ext_vector_type(8))) unsigned short u16x8;
typedef __attribute__((ext_vector_type(4))) float f32x4;

// Stats arena: layer slot = 8192 floats. Line-padded atomics:
//   addr(ch, kind, copy) = base + (ch*4 + copy)*32 + kind*8   (kind 0=sum, 1=sumsq; copy 0..3)
#define ST_ADDR(base, ch, kind, copy) ((base) + (((ch)*4 + (copy))*32 + (kind)*8))

// rotated-3x3 tap permutation: weight tap k of rotation r lands at patch position DST[r][k]
static constexpr int DST[8][9] = {
  {8,7,6,5,4,3,2,1,0},
  {5,8,7,2,4,6,1,0,3},
  {2,5,8,1,4,7,0,3,6},
  {1,2,5,0,4,8,3,6,7},
  {0,1,2,3,4,5,6,7,8},
  {3,0,1,6,4,2,7,8,5},
  {6,3,0,7,4,1,8,5,2},
  {7,6,3,8,4,0,5,2,1},
};

__device__ __forceinline__ unsigned short f2bf(float f){
  unsigned int u = __float_as_uint(f);
  u += 0x7fffu + ((u>>16)&1u);          // RNE
  return (unsigned short)(u>>16);
}

__device__ __forceinline__ float bf2f(unsigned short h){
  return __uint_as_float((unsigned int)h << 16);
}

// 2×f32 -> packed 2×bf16 in ONE instruction (gfx950; no builtin exposed)
__device__ __forceinline__ unsigned int cvtpk(float lo, float hi){
  unsigned int r;
  asm("v_cvt_pk_bf16_f32 %0, %1, %2" : "=v"(r) : "v"(lo), "v"(hi));
  return r;
}

// bn+relu+requant for a packed bf16 pair held in one u32 word
__device__ __forceinline__ unsigned int bnpair(unsigned int w, float a0, float b0, float a1, float b1){
  float vlo = __uint_as_float(w << 16);
  float vhi = __uint_as_float(w & 0xFFFF0000u);
  float r0 = fmaxf(vlo*a0 + b0, 0.f);
  float r1 = fmaxf(vhi*a1 + b1, 0.f);
  return cvtpk(r0, r1);
}

__device__ __forceinline__ float st_read(const float* base, int ch, int kind){
  return base[((ch*4+0)*32 + kind*8)] + base[((ch*4+1)*32 + kind*8)]
       + base[((ch*4+2)*32 + kind*8)] + base[((ch*4+3)*32 + kind*8)];
}

// border cell index (16x16 plane) for border id t<60
__device__ __forceinline__ int border_cell(int t){
  if (t<16) return t;
  if (t<32) return 240 + (t-16);
  if (t<46) return (t-31)*16;
  return (t-45)*16 + 15;
}

// ---------------- pre: weight packs (blocks 0..282) + conv7 B (283..1306) + bn1 stats (1307..1818) ----------------
__global__ __launch_bounds__(256) void k_pre(const float* __restrict__ x, const float* __restrict__ w1,
                                             const float* __restrict__ w2, const float* __restrict__ w3,
                                             const float* __restrict__ w4,
                                             const float* __restrict__ w5, const float* __restrict__ w6,
                                             const float* __restrict__ w7,
                                             unsigned short* __restrict__ B2,
                                             unsigned short* __restrict__ B3,
                                             unsigned short* __restrict__ wb4,
                                             unsigned short* __restrict__ wb5, unsigned short* __restrict__ wb6,
                                             unsigned short* __restrict__ Bl,
                                             float* __restrict__ st){
  int blk = blockIdx.x;
  if (blk < 283){
    int i = blk*256 + threadIdx.x;
    if (i < 18432){                                  // 9*64*32
      int tap = i/2048, rem = i%2048, oc = rem/32, ci = rem%32;
      wb5[i] = f2bf(w5[(oc*32+ci)*9 + tap]);
    } else if (i < 55296){                           // + 9*64*64
      int j = i - 18432;
      int tap = j/4096, rem = j%4096, oc = rem/64, ci = rem%64;
      wb6[j] = f2bf(w6[(oc*64+ci)*9 + tap]);
    } else if (i < 64512){                           // + 9*32*32
      int j = i - 55296;
      int tap = j/1024, rem = j%1024, oc = rem/32, ci = rem%32;
      wb4[j] = f2bf(w4[(oc*32+ci)*9 + tap]);
    } else if (i < 67072){                           // + conv2 tap-pair pack [5][16][32]
      int j = i - 64512;
      int c = j >> 9;
      int rem = j & 511;
      int o = rem >> 5, k = rem & 31;
      int tap = c*2 + (k>>4);
      int ci = k & 15;
      unsigned short v = 0;
      if (tap <= 8){
        int rot = o>>1, u = o&1;
        int bb = ci>>1, ui = ci&1;
        int wc = (((bb - rot) & 7)<<1) | ui;
        int kk = 0;
        #pragma unroll
        for (int q=0;q<9;q++) if (DST[rot][q]==tap) kk=q;
        v = f2bf(w2[(u*16+wc)*9 + kk]);
      }
      B2[j] = v;
    } else if (i < 72192){                           // + conv3 tap-pair pack [5][32][32]
      int j = i - 67072;
      int c = j >> 10;
      int rem = j & 1023;
      int o = rem >> 5, k = rem & 31;
      int tap = c*2 + (k>>4);
      int ci = k & 15;
      unsigned short v = 0;
      if (tap <= 8){
        int rot = o>>2, uh = (o>>1)&1, ul = o&1;
        int bb = ci>>1, ui = ci&1;
        int wc = (((bb - rot) & 7)<<1) | ui;
        int kk = 0;
        #pragma unroll
        for (int q=0;q<9;q++) if (DST[rot][q]==tap) kk=q;
        v = f2bf(w3[uh*288 + (ul*16+wc)*9 + kk]);
      }
      B3[j] = v;
    }
    return;
  }
  if (blk < 1307){
    int i = (blk-283)*256 + threadIdx.x;             // 262144 exact
    int n = i>>10, k = i&1023;
    int pos16 = k>>6, ci = k&63;
    int r = pos16>>2, c = pos16&3;
    unsigned short v = 0;
    if (n < 250){
      int pos = n/10, o = n - 10*(n/10);
      int py = pos/5, px = pos - 5*(pos/5);
      int ky = r - py + 2, kx = c - px + 2;
      if (ky>=0 && ky<4 && kx>=0 && kx<4) v = f2bf(w7[(o*64+ci)*16 + ky*4 + kx]);
    }
    Bl[i] = v;
    return;
  }
  // ---- bn1 stats over y1 = rotconv1(x); w1 (18 floats) in registers, rotation = compile-time tap permutation ----
  __shared__ float red[4][32];
  float wa[18];
  #pragma unroll
  for (int i=0;i<18;i++) wa[i] = w1[i];
  float s[16], s2[16];
  #pragma unroll
  for (int o=0;o<16;o++){ s[o]=0.f; s2[o]=0.f; }
  for (int idx = (blk-1307)*256 + threadIdx.x; idx < NB*784; idx += 512*256){
    int b = idx/784, pix = idx-b*784;
    int py = pix/28, px = pix-py*28;
    const float* xb = x + (size_t)b*784;
    float tap[9];
    #pragma unroll
    for (int d=0; d<9; d++){
      int dy = d/3-1, dx = d%3-1;
      int yy = py+dy, xx = px+dx;
      tap[d] = (yy>=0 && yy<28 && xx>=0 && xx<28) ? xb[yy*28+xx] : 0.f;
    }
    #pragma unroll
    for (int rot=0; rot<8; rot++){
      #pragma unroll
      for (int u=0; u<2; u++){
        float y = 0.f;
        #pragma unroll
        for (int k=0; k<9; k++) y += wa[u*9+k]*tap[DST[rot][k]];
        int ci = rot*2+u;
        s[ci] += y; s2[ci] += y*y;
      }
    }
  }
  int wid = threadIdx.x>>6;
  #pragma unroll
  for (int o=0;o<16;o++){
    float a = s[o], b2 = s2[o];
    #pragma unroll
    for (int off=32; off; off>>=1){ a += __shfl_down(a,off); b2 += __shfl_down(b2,off); }
    if ((threadIdx.x&63)==0){ red[wid][o] = a; red[wid][16+o] = b2; }
  }
  __syncthreads();
  if (threadIdx.x < 32){
    float v = red[0][threadIdx.x]+red[1][threadIdx.x]+red[2][threadIdx.x]+red[3][threadIdx.x];
    int ch = threadIdx.x & 15, kind = threadIdx.x >> 4;
    atomicAdd(ST_ADDR(st, ch, kind, blk & 3), v);
  }
}

// ---------------- conv2 MFMA: recompute y1 from x in-block; bn1 coef in-block; p2 OUTPUT AS BF16 ----------------
__global__ __launch_bounds__(256, 2) void k_conv2m(const float* __restrict__ x,
                                                   const float* __restrict__ w1,
                                                   const unsigned short* __restrict__ B2,  // [5][16][32] bf16
                                                   const float* __restrict__ stin,   // bn1 sums (layer0)
                                                   const float* __restrict__ g1, const float* __restrict__ b1,
                                                   unsigned short* __restrict__ p2b,
                                                   float* __restrict__ stout){
  __shared__ float smemf[8640];
  __shared__ float cab[32];                      // ca[0:16], cb[16:32]
  __shared__ float red[4][32];
  unsigned short* Ls = (unsigned short*)smemf;
  float* xs = smemf + 7680;
  float* out2 = smemf;
  int t = threadIdx.x;
  int wid = t>>6, lane = t&63;
  int quad = lane>>4, m = lane&15;
  float wa[18];
  #pragma unroll
  for (int i=0;i<18;i++) wa[i] = w1[i];
  if (t < 16){
    const float invN = 1.f/1605632.f;
    float mu = st_read(stin, t, 0)*invN;
    float var = st_read(stin, t, 1)*invN - mu*mu;
    float a = g1[t&1]*rsqrtf(var + 1e-5f);
    cab[t] = a; cab[16+t] = b1[t&1] - mu*a;
  }
  int b = blockIdx.x;
  for (int i=t; i<960; i+=256){
    int r = i>>5, c = i&31;
    int iy = r-1, ix = c-1;
    xs[i] = (iy>=0 && iy<28 && ix>=0 && ix<28) ? x[(size_t)b*784 + iy*28 + ix] : 0.f;
  }
  for (int i=t; i<3840; i+=256) ((unsigned long long*)Ls)[i] = 0ULL;
  __syncthreads();
  for (int i=t; i<784; i+=256){
    int py = i/28, px = i - 28*(i/28);
    float tap[9];
    #pragma unroll
    for (int d=0; d<9; d++) tap[d] = xs[(py + d/3)*32 + px + d%3];
    float y[16];
    #pragma unroll
    for (int rot=0; rot<8; rot++){
      #pragma unroll
      for (int u=0; u<2; u++){
        float acc1 = 0.f;
        #pragma unroll
        for (int k=0; k<9; k++) acc1 += wa[u*9+k]*tap[DST[rot][k]];
        y[rot*2+u] = acc1;
      }
    }
    unsigned long long pk[4];
    #pragma unroll
    for (int q=0; q<4; q++){
      float4 A = *(const float4*)(cab + q*4);
      float4 Bv = *(const float4*)(cab + 16 + q*4);
      float r0 = fmaxf(y[q*4+0]*A.x + Bv.x, 0.f);
      float r1 = fmaxf(y[q*4+1]*A.y + Bv.y, 0.f);
      float r2 = fmaxf(y[q*4+2]*A.z + Bv.z, 0.f);
      float r3 = fmaxf(y[q*4+3]*A.w + Bv.w, 0.f);
      unsigned int lo = cvtpk(r0, r1);
      unsigned int hi = cvtpk(r2, r3);
      pk[q] = (unsigned long long)lo | ((unsigned long long)hi<<32);
    }
    int cell = (py+1)*32 + px + 1;
    unsigned long long* dstp = (unsigned long long*)(Ls + cell*16);
    dstp[0]=pk[0]; dstp[1]=pk[1]; dstp[2]=pk[2]; dstp[3]=pk[3];
  }
  __syncthreads();
  // hoisted per-j LDS element offsets; tap deltas are compile-time immediates
  int jb[13];
  #pragma unroll
  for (int j=0;j<13;j++){
    int mt = wid + 4*j;
    int pos = (mt < 49) ? (mt*16 + m) : 0;
    int py = pos/28, px = pos - 28*py;
    jb[j] = (py*32 + px)*16 + (quad&1)*8;
  }
  f32x4 acc[13];
  #pragma unroll
  for (int j=0;j<13;j++) acc[j] = (f32x4){0.f,0.f,0.f,0.f};
  #pragma unroll
  for (int c=0;c<5;c++){
    const int tapA = 2*c, tapB = (2*c+1 < 9) ? 2*c+1 : 8;
    const int offA = ((tapA/3)*32 + tapA%3)*16;
    const int offB = ((tapB/3)*32 + tapB%3)*16;
    int sel = (quad < 2) ? offA : offB;
    bf16x8 Bf = *(const bf16x8*)(B2 + (c*16 + m)*32 + quad*8);
    #pragma unroll
    for (int j=0;j<13;j++){
      int mt = wid + 4*j;
      if (mt >= 49) continue;
      bf16x8 Af = *(const bf16x8*)(Ls + jb[j] + sel);
      acc[j] = __builtin_amdgcn_mfma_f32_16x16x32_bf16(Af, Bf, acc[j], 0, 0, 0);
    }
  }
  __syncthreads();   // done reading Ls; reuse as out2
  float s = 0.f, sq = 0.f;
  #pragma unroll
  for (int j=0;j<13;j++){
    int mt = wid + 4*j;
    if (mt >= 49) continue;
    #pragma unroll
    for (int p=0;p<2;p++){
      // pos0 = mt*16 + quad*4 + 2p is even and never wraps a row: (r0,r1) horizontal pool pair
      int pos0 = mt*16 + quad*4 + p*2;
      float v0 = acc[j][2*p], v1 = acc[j][2*p+1];
      s += v0 + v1; sq += v0*v0 + v1*v1;
      float hm = fmaxf(v0, v1);
      int py = pos0/28, px2 = (pos0 - py*28)>>1;
      out2[(py*14+px2)*17 + m] = hm;
    }
  }
  s += __shfl_down(s,32);  s += __shfl_down(s,16);
  sq += __shfl_down(sq,32); sq += __shfl_down(sq,16);
  if (lane < 16){ red[wid][m] = s; red[wid][16+m] = sq; }
  __syncthreads();
  if (t < 32){
    float v = red[0][t]+red[1][t]+red[2][t]+red[3][t];
    int ch = t & 15, kind = t >> 4;
    atomicAdd(ST_ADDR(stout, ch, kind, b & 3), v);
  }
  unsigned short* pb = p2b + (size_t)b*4096;
  for (int i=t; i<3136; i+=256){
    int cell = i>>4, oc = i&15;
    int yo = cell/14, xo = cell - yo*14;
    float mx = fmaxf(out2[((2*yo)*14+xo)*17 + oc], out2[((2*yo+1)*14+xo)*17 + oc]);
    pb[((yo+1)*16 + xo + 1)*16 + oc] = f2bf(mx);
  }
  for (int i=t; i<960; i+=256){
    int bc = border_cell(i>>4), oc = i&15;
    pb[bc*16 + oc] = f2bf(SENT);
  }
}

// ---------------- conv3 MFMA: 16->32 rotated over 14x14, bn2 coef in-block; BF16 I/O, packed decode/encode ----------------
__global__ __launch_bounds__(256, 2) void k_conv3m(const unsigned short* __restrict__ p2b,
                                                   const unsigned short* __restrict__ B3,  // [5][32][32] bf16
                                                   const float* __restrict__ stin,
                                                   const float* __restrict__ g2, const float* __restrict__ b2,
                                                   unsigned short* __restrict__ y3b,
                                                   float* __restrict__ stout){
  __shared__ unsigned short Ls[256*16];
  __shared__ float ca[16], cb[16];
  __shared__ float red[4][64];
  int t = threadIdx.x;
  int wid = t>>6, lane = t&63;
  int quad = lane>>4, m = lane&15;
  int b = blockIdx.x;
  // staging loads issued FIRST so HBM latency overlaps the stats/coef phase
  const unsigned short* sb = p2b + (size_t)b*4096;
  uint4 Uw0 = *(const uint4*)(sb + (size_t)t*16);
  uint4 Uw1 = *(const uint4*)(sb + (size_t)t*16 + 8);
  if (t < 16){
    const float invN = 1.f/1605632.f;
    float mu = st_read(stin, t, 0)*invN;
    float var = st_read(stin, t, 1)*invN - mu*mu;
    float a = g2[t&1]*rsqrtf(var + 1e-5f);
    ca[t] = a; cb[t] = b2[t&1] - mu*a;
  }
  __syncthreads();
  {
    unsigned int p0 = bnpair(Uw0.x, ca[0],cb[0], ca[1],cb[1]);
    unsigned int p1 = bnpair(Uw0.y, ca[2],cb[2], ca[3],cb[3]);
    unsigned int p2 = bnpair(Uw0.z, ca[4],cb[4], ca[5],cb[5]);
    unsigned int p3 = bnpair(Uw0.w, ca[6],cb[6], ca[7],cb[7]);
    unsigned int p4 = bnpair(Uw1.x, ca[8],cb[8], ca[9],cb[9]);
    unsigned int p5 = bnpair(Uw1.y, ca[10],cb[10], ca[11],cb[11]);
    unsigned int p6 = bnpair(Uw1.z, ca[12],cb[12], ca[13],cb[13]);
    unsigned int p7 = bnpair(Uw1.w, ca[14],cb[14], ca[15],cb[15]);
    unsigned long long* dstp = (unsigned long long*)(Ls + t*16);
    dstp[0] = (unsigned long long)p0 | ((unsigned long long)p1<<32);
    dstp[1] = (unsigned long long)p2 | ((unsigned long long)p3<<32);
    dstp[2] = (unsigned long long)p4 | ((unsigned long long)p5<<32);
    dstp[3] = (unsigned long long)p6 | ((unsigned long long)p7<<32);
  }
  __syncthreads();
  int jb[4]; bool vt[4];
  #pragma unroll
  for (int j=0;j<4;j++){
    int mt = wid + 4*j;
    int pos = mt*16 + m;
    vt[j] = (mt <= 12);
    if (pos >= 196) pos = 0;
    int py = pos/14, px = pos - 14*(pos/14);
    jb[j] = (py*16 + px)*16 + (quad&1)*8;
  }
  unsigned short* yb = y3b + (size_t)b*8192;
  float sa[2], sqa[2];
  #pragma unroll
  for (int nt=0; nt<2; nt++){
    f32x4 acc[4];
    #pragma unroll
    for (int j=0;j<4;j++) acc[j] = (f32x4){0.f,0.f,0.f,0.f};
    #pragma unroll
    for (int c=0;c<5;c++){
      const int tapA = 2*c, tapB = (2*c+1 < 9) ? 2*c+1 : 8;
      const int offA = ((tapA/3)*16 + tapA%3)*16;
      const int offB = ((tapB/3)*16 + tapB%3)*16;
      int sel = (quad < 2) ? offA : offB;
      bf16x8 Bf = *(const bf16x8*)(B3 + (c*32 + nt*16 + m)*32 + quad*8);
      #pragma unroll
      for (int j=0;j<4;j++){
        if (!vt[j]) continue;
        bf16x8 Af = *(const bf16x8*)(Ls + jb[j] + sel);
        acc[j] = __builtin_amdgcn_mfma_f32_16x16x32_bf16(Af, Bf, acc[j], 0, 0, 0);
      }
    }
    float s = 0.f, sq = 0.f;
    #pragma unroll
    for (int j=0;j<4;j++){
      if (!vt[j]) continue;
      int mt = wid + 4*j;
      #pragma unroll
      for (int r=0;r<4;r++){
        int pos = mt*16 + quad*4 + r;
        if (pos < 196){
          float v = acc[j][r];
          int py2 = pos/14, px2 = pos - py2*14;
          yb[(size_t)((py2+1)*16 + px2 + 1)*32 + nt*16 + m] = f2bf(v);
          s += v; sq += v*v;
        }
      }
    }
    s += __shfl_down(s,32);  s += __shfl_down(s,16);
    sq += __shfl_down(sq,32); sq += __shfl_down(sq,16);
    sa[nt] = s; sqa[nt] = sq;
  }
  if (lane < 16){
    red[wid][m]      = sa[0];  red[wid][32+m]      = sqa[0];
    red[wid][16+m]   = sa[1];  red[wid][32+16+m]   = sqa[1];
  }
  __syncthreads();
  if (t < 64){
    float v = red[0][t]+red[1][t]+red[2][t]+red[3][t];
    int ch = t & 31, kind = t >> 5;
    atomicAdd(ST_ADDR(stout, ch, kind, b & 3), v);
  }
  for (int i=t; i<1920; i+=256){
    int bc = border_cell(i>>5), oc = i&31;
    yb[(size_t)bc*32 + oc] = f2bf(SENT);
  }
}

// ---------------- conv4 WAVE-PER-IMAGE: grid 512 x 4 waves; zero barriers in main flow ----------------
// Each wave owns image b = blk*4+wid and a private 16KB LDS act plane [256 cells][32ch bf16],
// stored with a 16B-chunk XOR swizzle (chunk' = chunk ^ (cell&3)) for conflict-free b128 reads.
// Single fused nt pass (acc[13][2], Af reused for both oc halves). hp pool staging reuses act.
__global__ __launch_bounds__(256, 2) void k_conv4w(const unsigned short* __restrict__ y3b,
                                                   const unsigned short* __restrict__ wb4, // [9][32][32] bf16
                                                   const float* __restrict__ stin,
                                                   const float* __restrict__ g3, const float* __restrict__ b3,
                                                   float* __restrict__ p4,
                                                   float* __restrict__ stout,
                                                   float* __restrict__ nmsa){
  __shared__ unsigned short act[4][8192];   // 64 KB: per-wave act plane, later reused as hp f32 [98][33]
  __shared__ float ca[32], cb[32];
  __shared__ float red[4][64];
  int t = threadIdx.x;
  int wid = t>>6, lane = t&63;
  int quad = lane>>4, m = lane&15;
  if (t < 32){
    const float invN = 1.f/401408.f;
    float mu = st_read(stin, t, 0)*invN;
    float var = st_read(stin, t, 1)*invN - mu*mu;
    float a = g3[t&3]*rsqrtf(var + 1e-5f);
    ca[t] = a; cb[t] = b3[t&3] - mu*a;
  }
  __syncthreads();                           // ONLY entry barrier (coef ready)
  int b = blockIdx.x*4 + wid;
  unsigned short* A = act[wid];
  const unsigned short* sb = y3b + (size_t)b*8192;
  // ---- staging: 4 cells per lane, chunk-swizzled ds writes (own region, no barrier) ----
  #pragma unroll
  for (int k=0;k<4;k++){
    int cell = lane + 64*k;
    const uint4* src = (const uint4*)(sb + cell*32);
    int sw = cell & 3;
    unsigned short* dst = A + cell*32;
    #pragma unroll
    for (int c=0;c<4;c++){
      uint4 W = src[c];
      int c0 = c*8;
      unsigned int q0 = bnpair(W.x, ca[c0+0],cb[c0+0], ca[c0+1],cb[c0+1]);
      unsigned int q1 = bnpair(W.y, ca[c0+2],cb[c0+2], ca[c0+3],cb[c0+3]);
      unsigned int q2 = bnpair(W.z, ca[c0+4],cb[c0+4], ca[c0+5],cb[c0+5]);
      unsigned int q3 = bnpair(W.w, ca[c0+6],cb[c0+6], ca[c0+7],cb[c0+7]);
      unsigned long long* q = (unsigned long long*)(dst + ((c ^ sw)<<3));
      q[0] = (unsigned long long)q0 | ((unsigned long long)q1<<32);
      q[1] = (unsigned long long)q2 | ((unsigned long long)q3<<32);
    }
  }
  asm volatile("s_waitcnt lgkmcnt(0)" ::: "memory");
  __builtin_amdgcn_sched_barrier(0);
  // ---- NMS over own image (reads act, wave-local) ----
  float nloc = 0.f;
  for (int i=lane; i<784; i+=64){
    int hw = i>>2, c4 = i&3;
    int cell = (hw/14 + 1)*16 + hw%14 + 1;
    const unsigned int* g32 = (const unsigned int*)(A + cell*32 + ((c4 ^ (cell&3))<<3));
    unsigned int w0 = g32[0], w1 = g32[1], w2 = g32[2], w3 = g32[3];
    float v[8];
    v[0] = __uint_as_float(w0 << 16); v[1] = __uint_as_float(w0 & 0xFFFF0000u);
    v[2] = __uint_as_float(w1 << 16); v[3] = __uint_as_float(w1 & 0xFFFF0000u);
    v[4] = __uint_as_float(w2 << 16); v[5] = __uint_as_float(w2 & 0xFFFF0000u);
    v[6] = __uint_as_float(w3 << 16); v[7] = __uint_as_float(w3 & 0xFFFF0000u);
    float vmax = -1e30f;
    #pragma unroll
    for (int r=0;r<8;r++) vmax = fmaxf(vmax, v[r]);
    #pragma unroll
    for (int r=0;r<8;r++) nloc += (v[r] != vmax) ? v[r] : 0.f;
  }
  #pragma unroll
  for (int off=32; off; off>>=1) nloc += __shfl_down(nloc, off);
  if (lane == 0) atomicAdd(&nmsa[(b & 7)*32], nloc);
  // ---- MFMA: 13 m-tiles x 9 taps x 2 oc-halves, Af shared across halves ----
  int jc[13], jp[13];
  #pragma unroll
  for (int j=0;j<13;j++){
    int pos = j*16 + m;
    if (pos >= 196) pos = 0;
    int py = pos/14, px = pos - 14*(pos/14);
    jc[j] = py*16 + px;
    jp[j] = px;
  }
  f32x4 acc[13][2];
  #pragma unroll
  for (int j=0;j<13;j++){ acc[j][0] = (f32x4){0,0,0,0}; acc[j][1] = (f32x4){0,0,0,0}; }
  #pragma unroll
  for (int tap=0; tap<9; tap++){
    const int dy = tap/3, dx = tap - 3*(tap/3);
    bf16x8 Bf0 = *(const bf16x8*)(wb4 + (tap*32 + m)*32 + quad*8);
    bf16x8 Bf1 = *(const bf16x8*)(wb4 + (tap*32 + 16 + m)*32 + quad*8);
    #pragma unroll
    for (int j=0;j<13;j++){
      int ci = jc[j] + dy*16 + dx;
      int ph = quad ^ ((jp[j]+dx)&3);
      bf16x8 Af = *(const bf16x8*)(A + ci*32 + ph*8);
      acc[j][0] = __builtin_amdgcn_mfma_f32_16x16x32_bf16(Af, Bf0, acc[j][0], 0, 0, 0);
      acc[j][1] = __builtin_amdgcn_mfma_f32_16x16x32_bf16(Af, Bf1, acc[j][1], 0, 0, 0);
    }
  }
  asm volatile("s_waitcnt lgkmcnt(0)" ::: "memory");
  __builtin_amdgcn_sched_barrier(0);
  // ---- epilogue: stats + in-register horizontal pool -> hp (reuses act region), wave-local ----
  float* hp = (float*)A;                    // 98*33*4 = 12936 B <= 16384 B
  float s0=0.f, sq0=0.f, s1=0.f, sq1=0.f;
  #pragma unroll
  for (int j=0;j<13;j++){
    #pragma unroll
    for (int p=0;p<2;p++){
      int pos0 = j*16 + quad*4 + 2*p;       // even, px even -> horizontal pool pair
      if (pos0 + 1 < 196){
        float a0 = acc[j][0][2*p], a1 = acc[j][0][2*p+1];
        float b0 = acc[j][1][2*p], b1 = acc[j][1][2*p+1];
        s0 += a0 + a1; sq0 += a0*a0 + a1*a1;
        s1 += b0 + b1; sq1 += b0*b0 + b1*b1;
        int py0 = pos0/14, pxh = (pos0 - py0*14)>>1;
        hp[(py0*7 + pxh)*33 + m]      = fmaxf(a0, a1);
        hp[(py0*7 + pxh)*33 + 16 + m] = fmaxf(b0, b1);
      }
    }
  }
  s0 += __shfl_down(s0,32); s0 += __shfl_down(s0,16);
  sq0 += __shfl_down(sq0,32); sq0 += __shfl_down(sq0,16);
  s1 += __shfl_down(s1,32); s1 += __shfl_down(s1,16);
  sq1 += __shfl_down(sq1,32); sq1 += __shfl_down(sq1,16);
  if (lane < 16){
    red[wid][m]      = s0;  red[wid][32+m]      = sq0;
    red[wid][16+m]   = s1;  red[wid][32+16+m]   = sq1;
  }
  asm volatile("s_waitcnt lgkmcnt(0)" ::: "memory");
  __builtin_amdgcn_sched_barrier(0);
  // ---- vertical pool from hp -> p4 (wave-local) ----
  for (int i=lane; i<1568; i+=64){
    int cell = i>>5, oc = i&31;
    int yo = cell/7, xo = cell - yo*7;
    float mx = fmaxf(hp[((2*yo)*7 + xo)*33 + oc], hp[((2*yo+1)*7 + xo)*33 + oc]);
    p4[((size_t)b*49 + cell)*32 + oc] = mx;
  }
  __syncthreads();                           // ONLY exit barrier (stats reduce)
  if (t < 64){
    float v = red[0][t]+red[1][t]+red[2][t]+red[3][t];
    int ch = t & 31, kind = t >> 5;
    atomicAdd(ST_ADDR(stout, ch, kind, blockIdx.x & 3), v);
  }
}

// ---------------- conv5/conv6 MFMA: CI->64, per-wave batch, bn coef in-block, shift-GEMM over 9 taps ----------------
template<int CI>
__global__ __launch_bounds__(256, 2) void k_conv56m(const float* __restrict__ src,
                                                    const unsigned short* __restrict__ wb,  // [9][64][CI] bf16
                                                    const float* __restrict__ stin,
                                                    const float* __restrict__ g, const float* __restrict__ be,
                                                    float invN,
                                                    float* __restrict__ dst,
                                                    float* __restrict__ stout){
  constexpr int CIP = CI + 8;
  constexpr int KC = CI/32;
  __shared__ unsigned short lin[4][81*CIP];
  __shared__ float red[4][256];
  __shared__ float ca[CI], cb[CI];
  int wid = threadIdx.x>>6, lane = threadIdx.x&63;
  int quad = lane>>4, m = lane&15;
  unsigned short* L = lin[wid];
  if (threadIdx.x < CI){
    int i = threadIdx.x;
    float mu = st_read(stin, i, 0)*invN;
    float var = st_read(stin, i, 1)*invN - mu*mu;
    float a = g[i]*rsqrtf(var + 1e-5f);
    ca[i] = a; cb[i] = be[i] - mu*a;
  }
  for (int i = lane; i < 81*CIP/4; i += 64) ((unsigned long long*)L)[i] = 0ULL;
  __syncthreads();
  int b = blockIdx.x*4 + wid;
  const float* sb = src + (size_t)b*49*CI;
  for (int i = lane; i < 49*CI/4; i += 64){
    int pos = i/(CI/4), cig = i - pos*(CI/4);
    float4 v = *(const float4*)(sb + pos*CI + cig*4);
    float r0 = fmaxf(v.x*ca[cig*4]  +cb[cig*4],   0.f);
    float r1 = fmaxf(v.y*ca[cig*4+1]+cb[cig*4+1], 0.f);
    float r2 = fmaxf(v.z*ca[cig*4+2]+cb[cig*4+2], 0.f);
    float r3 = fmaxf(v.w*ca[cig*4+3]+cb[cig*4+3], 0.f);
    int pos9 = (pos/7 + 1)*9 + pos%7 + 1;
    unsigned int lo = cvtpk(r0, r1);
    unsigned int hi = cvtpk(r2, r3);
    *(unsigned long long*)(L + pos9*CIP + cig*4) =
        (unsigned long long)lo | ((unsigned long long)hi<<32);
  }
  __syncthreads();
  int py[4], px[4];
  #pragma unroll
  for (int mt=0; mt<4; mt++){
    int pos = mt*16 + m;
    if (pos < 49){ py[mt] = pos/7; px[mt] = pos%7; }
    else { py[mt] = 0; px[mt] = 0; }
  }
  f32x4 acc[4][4];
  #pragma unroll
  for (int nt=0; nt<4; nt++)
    #pragma unroll
    for (int mt=0; mt<4; mt++) acc[nt][mt] = (f32x4){0.f,0.f,0.f,0.f};

  for (int tap=0; tap<9; tap++){
    int dy = tap/3, dx = tap - dy*3;
    int o9[4];
    #pragma unroll
    for (int mt=0; mt<4; mt++) o9[mt] = ((py[mt]+dy)*9 + px[mt]+dx)*CIP;
    #pragma unroll
    for (int kc=0; kc<KC; kc++){
      int ko = kc*32 + quad*8;
      bf16x8 Bf[4], Af[4];
      #pragma unroll
      for (int nt=0; nt<4; nt++)
        Bf[nt] = *(const bf16x8*)(wb + (tap*64 + nt*16 + m)*CI + ko);
      #pragma unroll
      for (int mt=0; mt<4; mt++)
        Af[mt] = *(const bf16x8*)(L + o9[mt] + ko);
      #pragma unroll
      for (int nt=0; nt<4; nt++)
        #pragma unroll
        for (int mt=0; mt<4; mt++)
          acc[nt][mt] = __builtin_amdgcn_mfma_f32_16x16x32_bf16(Af[mt], Bf[nt], acc[nt][mt], 0, 0, 0);
    }
  }
  float* db = dst + (size_t)b*49*64;
  float snt[4], sqnt[4];
  #pragma unroll
  for (int nt=0; nt<4; nt++){
    float s = 0.f, sq = 0.f;
    #pragma unroll
    for (int mt=0; mt<4; mt++){
      #pragma unroll
      for (int r=0; r<4; r++){
        int pos = mt*16 + quad*4 + r;
        if (pos < 49){
          float v = acc[nt][mt][r];
          db[pos*64 + nt*16 + m] = v;
          s += v; sq += v*v;
        }
      }
    }
    s += __shfl_down(s, 32);  s += __shfl_down(s, 16);
    sq += __shfl_down(sq, 32); sq += __shfl_down(sq, 16);
    snt[nt] = s; sqnt[nt] = sq;
  }
  if (lane < 16){
    #pragma unroll
    for (int nt=0; nt<4; nt++){
      red[wid][nt*16 + lane] = snt[nt];
      red[wid][128 + nt*16 + lane] = sqnt[nt];
    }
  }
  __syncthreads();
  if (threadIdx.x < 128){
    int c = threadIdx.x & 63;
    int off = (threadIdx.x < 64) ? threadIdx.x : (128 + c);
    float v = red[0][off]+red[1][off]+red[2][off]+red[3][off];
    int kind = (threadIdx.x < 64) ? 0 : 1;
    atomicAdd(ST_ADDR(stout, c, kind, blockIdx.x & 3), v);
  }
}

// ---------------- bn6+relu + 2x2 pool pad 1 (7 -> 4); bn6 coef per-thread; y6 -> p6b bf16 ----------------
__global__ __launch_bounds__(256) void k_pool6(const float* __restrict__ y,
                                               const float* __restrict__ stin,
                                               const float* __restrict__ g6, const float* __restrict__ b6,
                                               unsigned short* __restrict__ p6b){
  int idx = blockIdx.x*256 + threadIdx.x;       // NB*16*64 exact
  int oc = idx & 63; int t2 = idx >> 6;
  int xo = t2 & 3;  int yo = (t2>>2) & 3;  int b = t2 >> 4;
  const float invN = 1.f/100352.f;
  float mu = st_read(stin, oc, 0)*invN;
  float var = st_read(stin, oc, 1)*invN - mu*mu;
  float a = g6[oc]*rsqrtf(var + 1e-5f);
  float bo = b6[oc] - mu*a;
  const float* src = y + (size_t)b*3136;
  float mx = -1e30f;
  #pragma unroll
  for (int dy=0;dy<2;dy++){
    int iy = yo*2 - 1 + dy;
    if (iy < 0 || iy >= 7) continue;
    #pragma unroll
    for (int dx=0;dx<2;dx++){
      int ix = xo*2 - 1 + dx;
      if (ix < 0 || ix >= 7) continue;
      mx = fmaxf(mx, src[(iy*7+ix)*64 + oc]*a + bo);
    }
  }
  p6b[(size_t)b*1024 + (yo*4 + xo)*64 + oc] = f2bf(fmaxf(mx, 0.f));
}

// ---------------- conv7 as GEMM: M=2048 (batch), N=256 (pos25*10+o), K=1024; partial max per N-block ----------------
__global__ __launch_bounds__(256) void k_gemm7(const unsigned short* __restrict__ A,   // [2048][1024] bf16
                                               const unsigned short* __restrict__ Bl,  // [256][1024] bf16
                                               float* __restrict__ part){              // [2048][4][10]
  __shared__ float Lw[4][16*65];
  int wid = threadIdx.x>>6, lane = threadIdx.x&63;
  int quad = lane>>4, m = lane&15;
  int blkm = blockIdx.x >> 2, blkn = blockIdx.x & 3;   // grid 128
  int rowb = blkm*64 + wid*16 + m;
  const unsigned short* Arow = A + (size_t)rowb*1024;
  f32x4 acc[4];
  #pragma unroll
  for (int nt=0; nt<4; nt++) acc[nt] = (f32x4){0.f,0.f,0.f,0.f};
  for (int kc=0; kc<32; kc++){
    bf16x8 Af = *(const bf16x8*)(Arow + kc*32 + quad*8);
    #pragma unroll
    for (int nt=0; nt<4; nt++){
      bf16x8 Bf = *(const bf16x8*)(Bl + (size_t)(blkn*64 + nt*16 + m)*1024 + kc*32 + quad*8);
      acc[nt] = __builtin_amdgcn_mfma_f32_16x16x32_bf16(Af, Bf, acc[nt], 0, 0, 0);
    }
  }
  float* Lp = &Lw[wid][0];
  #pragma unroll
  for (int nt=0; nt<4; nt++)
    #pragma unroll
    for (int r=0; r<4; r++)
      Lp[(quad*4+r)*65 + nt*16 + m] = acc[nt][r];
  __syncthreads();
  for (int i=lane; i<160; i+=64){
    int br = i/10, o = i - 10*(i/10);
    int c0 = ((o - blkn*64) % 10 + 10) % 10;
    float mx = -1e30f;
    for (int c=c0; c<64; c+=10){
      if (blkn*64 + c < 250) mx = fmaxf(mx, Lp[br*65 + c]);
    }
    part[((size_t)(blkm*64 + wid*16 + br)*4 + blkn)*10 + o] = mx;
  }
}

// ---------------- logits: max over 4 N-block partials + bias; nms write ----------------
__global__ __launch_bounds__(256) void k_logits(const float* __restrict__ part,
                                                const float* __restrict__ bias,
                                                const float* __restrict__ nmsa,
                                                float* __restrict__ out){
  int idx = blockIdx.x*256 + threadIdx.x;       // 20480 exact (80 blocks)
  int b = idx/10, o = idx - 10*(idx/10);
  const float* p = part + (size_t)b*40 + o;
  float mx = fmaxf(fmaxf(p[0], p[10]), fmaxf(p[20], p[30]));
  out[idx] = mx + bias[o];
  if (blockIdx.x == 0 && threadIdx.x == 0){
    float nm = 0.f;
    #pragma unroll
    for (int cp=0; cp<8; cp++) nm += nmsa[cp*32];
    out[20480] = nm * (1.f/12845056.f);
  }
}

extern "C" void kernel_launch(void* const* d_in, const int* in_sizes, int n_in,
                              void* d_out, int out_size, void* d_ws, size_t ws_size,
                              hipStream_t stream){
  const float* x  = (const float*)d_in[0];
  const float* w1 = (const float*)d_in[1];
  const float* w2 = (const float*)d_in[2];
  const float* w3 = (const float*)d_in[3];
  const float* w4 = (const float*)d_in[4];
  const float* w5 = (const float*)d_in[5];
  const float* w6 = (const float*)d_in[6];
  const float* w7 = (const float*)d_in[7];
  const float* g1 = (const float*)d_in[8];
  const float* b1 = (const float*)d_in[9];
  const float* g2 = (const float*)d_in[10];
  const float* b2 = (const float*)d_in[11];
  const float* g3 = (const float*)d_in[12];
  const float* b3 = (const float*)d_in[13];
  const float* g4 = (const float*)d_in[14];
  const float* b4 = (const float*)d_in[15];
  const float* g5 = (const float*)d_in[16];
  const float* b5 = (const float*)d_in[17];
  const float* g6 = (const float*)d_in[18];
  const float* b6 = (const float*)d_in[19];
  const float* b7 = (const float*)d_in[20];
  float* out = (float*)d_out;
  float* W = (float*)d_ws;

  // arena (float units)
  unsigned short* p2b = (unsigned short*)(W + 15728640); // 2048*256*16 bf16 (16.8 MB, region holds 33.5 MB)
  unsigned short* y3b = (unsigned short*)(W + 24117248); // 2048*256*32 bf16 (33.6 MB, region holds 67 MB)
  float* p4   = W + 0;                 //  3,211,264  (2048*49*32) -> ends 3,211,264
  // line-padded stats arena lives in the verified-free gap [3211264, 3407872):
  //   6 layers x 8192 floats + 8-copy nms (256) = 49,408 floats -> ends 3,260,672 < 3,407,872.
  float* st   = W + 3211264;
  float* nmsa = st + 6*8192;
  float* y5   = W + 3407872;           //  6,422,528  (2048*49*64)
  float* y6   = W + 10223616;          //  6,422,528
  unsigned short* p6b = (unsigned short*)(W + 16646144); // 2048*1024 bf16
  unsigned short* wb5 = (unsigned short*)(W + 40894464);  // 9*64*32 bf16
  unsigned short* wb6 = (unsigned short*)(W + 40912896);  // 9*64*64 bf16
  unsigned short* wb4 = (unsigned short*)(W + 40931328);  // 9*32*32 bf16
  unsigned short* Bl = (unsigned short*)(W + 40951808);   // 256*1024 bf16
  float* part = W + 41082880;          //  81,920 (2048*4*10)
  unsigned short* B2 = (unsigned short*)(W + 41164800);   // 5*16*32 bf16 (1280 floats)
  unsigned short* B3 = (unsigned short*)(W + 41166080);   // 5*32*32 bf16 (2560 floats)

  hipMemsetAsync(st, 0, 49408*sizeof(float), stream);

  k_pre<<<1819,256,0,stream>>>(x, w1, w2, w3, w4, w5, w6, w7,
                               B2, B3, wb4, wb5, wb6, Bl, st + 0*8192);

  k_conv2m<<<2048,256,0,stream>>>(x, w1, B2, st + 0*8192, g1, b1, p2b, st + 1*8192);

  k_conv3m<<<2048,256,0,stream>>>(p2b, B3, st + 1*8192, g2, b2, y3b, st + 2*8192);

  k_conv4w<<<512,256,0,stream>>>(y3b, wb4, st + 2*8192, g3, b3, p4, st + 3*8192, nmsa);

  k_conv56m<32><<<512,256,0,stream>>>(p4, wb5, st + 3*8192, g4, b4, 1.f/401408.f, y5, st + 4*8192);

  k_conv56m<64><<<512,256,0,stream>>>(y5, wb6, st + 4*8192, g5, b5, 1.f/100352.f, y6, st + 5*8192);

  k_pool6<<<8192,256,0,stream>>>(y6, st + 5*8192, g6, b6, p6b);

  k_gemm7<<<128,256,0,stream>>>(p6b, Bl, part);
  k_logits<<<80,256,0,stream>>>(part, b7, nmsa, out);
}

// Round 10
// 281.777 us; speedup vs baseline: 1.2730x; 1.1115x over previous
//
#include <hip/hip_runtime.h>

static constexpr int NB = 2048;
static constexpr float SENT = -1e30f;

typedef __attribute__((ext_vector_type(8))) short bf16x8;
typedef __attribute__((ext_vector_type(8))) unsigned short u16x8;
typedef __attribute__((ext_vector_type(4))) float f32x4;

// Stats arena: layer slot = 8192 floats. Line-padded atomics:
//   addr(ch, kind, copy) = base + (ch*4 + copy)*32 + kind*8   (kind 0=sum, 1=sumsq; copy 0..3)
#define ST_ADDR(base, ch, kind, copy) ((base) + (((ch)*4 + (copy))*32 + (kind)*8))

// rotated-3x3 tap permutation: weight tap k of rotation r lands at patch position DST[r][k]
static constexpr int DST[8][9] = {
  {8,7,6,5,4,3,2,1,0},
  {5,8,7,2,4,6,1,0,3},
  {2,5,8,1,4,7,0,3,6},
  {1,2,5,0,4,8,3,6,7},
  {0,1,2,3,4,5,6,7,8},
  {3,0,1,6,4,2,7,8,5},
  {6,3,0,7,4,1,8,5,2},
  {7,6,3,8,4,0,5,2,1},
};

__device__ __forceinline__ unsigned short f2bf(float f){
  unsigned int u = __float_as_uint(f);
  u += 0x7fffu + ((u>>16)&1u);          // RNE
  return (unsigned short)(u>>16);
}

__device__ __forceinline__ float bf2f(unsigned short h){
  return __uint_as_float((unsigned int)h << 16);
}

// 2×f32 -> packed 2×bf16 in ONE instruction (gfx950; no builtin exposed)
__device__ __forceinline__ unsigned int cvtpk(float lo, float hi){
  unsigned int r;
  asm("v_cvt_pk_bf16_f32 %0, %1, %2" : "=v"(r) : "v"(lo), "v"(hi));
  return r;
}

// bn+relu+requant for a packed bf16 pair held in one u32 word
__device__ __forceinline__ unsigned int bnpair(unsigned int w, float a0, float b0, float a1, float b1){
  float vlo = __uint_as_float(w << 16);
  float vhi = __uint_as_float(w & 0xFFFF0000u);
  float r0 = fmaxf(vlo*a0 + b0, 0.f);
  float r1 = fmaxf(vhi*a1 + b1, 0.f);
  return cvtpk(r0, r1);
}

__device__ __forceinline__ float st_read(const float* base, int ch, int kind){
  return base[((ch*4+0)*32 + kind*8)] + base[((ch*4+1)*32 + kind*8)]
       + base[((ch*4+2)*32 + kind*8)] + base[((ch*4+3)*32 + kind*8)];
}

// border cell index (16x16 plane) for border id t<60
__device__ __forceinline__ int border_cell(int t){
  if (t<16) return t;
  if (t<32) return 240 + (t-16);
  if (t<46) return (t-31)*16;
  return (t-45)*16 + 15;
}

// ---------------- pre: weight packs (blocks 0..282) + conv7 B (283..1306) + bn1 stats (1307..1818) ----------------
__global__ __launch_bounds__(256) void k_pre(const float* __restrict__ x, const float* __restrict__ w1,
                                             const float* __restrict__ w2, const float* __restrict__ w3,
                                             const float* __restrict__ w4,
                                             const float* __restrict__ w5, const float* __restrict__ w6,
                                             const float* __restrict__ w7,
                                             unsigned short* __restrict__ B2,
                                             unsigned short* __restrict__ B3,
                                             unsigned short* __restrict__ wb4,
                                             unsigned short* __restrict__ wb5, unsigned short* __restrict__ wb6,
                                             unsigned short* __restrict__ Bl,
                                             float* __restrict__ st){
  int blk = blockIdx.x;
  if (blk < 283){
    int i = blk*256 + threadIdx.x;
    if (i < 18432){                                  // 9*64*32
      int tap = i/2048, rem = i%2048, oc = rem/32, ci = rem%32;
      wb5[i] = f2bf(w5[(oc*32+ci)*9 + tap]);
    } else if (i < 55296){                           // + 9*64*64
      int j = i - 18432;
      int tap = j/4096, rem = j%4096, oc = rem/64, ci = rem%64;
      wb6[j] = f2bf(w6[(oc*64+ci)*9 + tap]);
    } else if (i < 64512){                           // + 9*32*32
      int j = i - 55296;
      int tap = j/1024, rem = j%1024, oc = rem/32, ci = rem%32;
      wb4[j] = f2bf(w4[(oc*32+ci)*9 + tap]);
    } else if (i < 67072){                           // + conv2 tap-pair pack [5][16][32]
      int j = i - 64512;
      int c = j >> 9;
      int rem = j & 511;
      int o = rem >> 5, k = rem & 31;
      int tap = c*2 + (k>>4);
      int ci = k & 15;
      unsigned short v = 0;
      if (tap <= 8){
        int rot = o>>1, u = o&1;
        int bb = ci>>1, ui = ci&1;
        int wc = (((bb - rot) & 7)<<1) | ui;
        int kk = 0;
        #pragma unroll
        for (int q=0;q<9;q++) if (DST[rot][q]==tap) kk=q;
        v = f2bf(w2[(u*16+wc)*9 + kk]);
      }
      B2[j] = v;
    } else if (i < 72192){                           // + conv3 tap-pair pack [5][32][32]
      int j = i - 67072;
      int c = j >> 10;
      int rem = j & 1023;
      int o = rem >> 5, k = rem & 31;
      int tap = c*2 + (k>>4);
      int ci = k & 15;
      unsigned short v = 0;
      if (tap <= 8){
        int rot = o>>2, uh = (o>>1)&1, ul = o&1;
        int bb = ci>>1, ui = ci&1;
        int wc = (((bb - rot) & 7)<<1) | ui;
        int kk = 0;
        #pragma unroll
        for (int q=0;q<9;q++) if (DST[rot][q]==tap) kk=q;
        v = f2bf(w3[uh*288 + (ul*16+wc)*9 + kk]);
      }
      B3[j] = v;
    }
    return;
  }
  if (blk < 1307){
    int i = (blk-283)*256 + threadIdx.x;             // 262144 exact
    int n = i>>10, k = i&1023;
    int pos16 = k>>6, ci = k&63;
    int r = pos16>>2, c = pos16&3;
    unsigned short v = 0;
    if (n < 250){
      int pos = n/10, o = n - 10*(n/10);
      int py = pos/5, px = pos - 5*(pos/5);
      int ky = r - py + 2, kx = c - px + 2;
      if (ky>=0 && ky<4 && kx>=0 && kx<4) v = f2bf(w7[(o*64+ci)*16 + ky*4 + kx]);
    }
    Bl[i] = v;
    return;
  }
  // ---- bn1 stats over y1 = rotconv1(x); w1 (18 floats) in registers, rotation = compile-time tap permutation ----
  __shared__ float red[4][32];
  float wa[18];
  #pragma unroll
  for (int i=0;i<18;i++) wa[i] = w1[i];
  float s[16], s2[16];
  #pragma unroll
  for (int o=0;o<16;o++){ s[o]=0.f; s2[o]=0.f; }
  for (int idx = (blk-1307)*256 + threadIdx.x; idx < NB*784; idx += 512*256){
    int b = idx/784, pix = idx-b*784;
    int py = pix/28, px = pix-py*28;
    const float* xb = x + (size_t)b*784;
    float tap[9];
    #pragma unroll
    for (int d=0; d<9; d++){
      int dy = d/3-1, dx = d%3-1;
      int yy = py+dy, xx = px+dx;
      tap[d] = (yy>=0 && yy<28 && xx>=0 && xx<28) ? xb[yy*28+xx] : 0.f;
    }
    #pragma unroll
    for (int rot=0; rot<8; rot++){
      #pragma unroll
      for (int u=0; u<2; u++){
        float y = 0.f;
        #pragma unroll
        for (int k=0; k<9; k++) y += wa[u*9+k]*tap[DST[rot][k]];
        int ci = rot*2+u;
        s[ci] += y; s2[ci] += y*y;
      }
    }
  }
  int wid = threadIdx.x>>6;
  #pragma unroll
  for (int o=0;o<16;o++){
    float a = s[o], b2 = s2[o];
    #pragma unroll
    for (int off=32; off; off>>=1){ a += __shfl_down(a,off); b2 += __shfl_down(b2,off); }
    if ((threadIdx.x&63)==0){ red[wid][o] = a; red[wid][16+o] = b2; }
  }
  __syncthreads();
  if (threadIdx.x < 32){
    float v = red[0][threadIdx.x]+red[1][threadIdx.x]+red[2][threadIdx.x]+red[3][threadIdx.x];
    int ch = threadIdx.x & 15, kind = threadIdx.x >> 4;
    atomicAdd(ST_ADDR(st, ch, kind, blk & 3), v);
  }
}

// ---------------- coef: collapse line-padded stats into compact [CI] a / [CI] b coefficients ----------------
template<int CI>
__global__ __launch_bounds__(64) void k_coef(const float* __restrict__ stin,
                                             const float* __restrict__ g, const float* __restrict__ be,
                                             float invN, int gmask,
                                             float* __restrict__ cf){
  int i = threadIdx.x;
  if (i < CI){
    float mu = st_read(stin, i, 0)*invN;
    float var = st_read(stin, i, 1)*invN - mu*mu;
    float a = g[i & gmask]*rsqrtf(var + 1e-5f);
    cf[i] = a; cf[CI + i] = be[i & gmask] - mu*a;
  }
}

// ---------------- conv2 MFMA: recompute y1 from x in-block; bn1 coef in-block; p2 OUTPUT AS BF16 ----------------
__global__ __launch_bounds__(256, 2) void k_conv2m(const float* __restrict__ x,
                                                   const float* __restrict__ w1,
                                                   const unsigned short* __restrict__ B2,  // [5][16][32] bf16
                                                   const float* __restrict__ stin,   // bn1 sums (layer0)
                                                   const float* __restrict__ g1, const float* __restrict__ b1,
                                                   unsigned short* __restrict__ p2b,
                                                   float* __restrict__ stout){
  __shared__ float smemf[8640];
  __shared__ float cab[32];                      // ca[0:16], cb[16:32]
  __shared__ float red[4][32];
  unsigned short* Ls = (unsigned short*)smemf;
  float* xs = smemf + 7680;
  float* out2 = smemf;
  int t = threadIdx.x;
  int wid = t>>6, lane = t&63;
  int quad = lane>>4, m = lane&15;
  float wa[18];
  #pragma unroll
  for (int i=0;i<18;i++) wa[i] = w1[i];
  if (t < 16){
    const float invN = 1.f/1605632.f;
    float mu = st_read(stin, t, 0)*invN;
    float var = st_read(stin, t, 1)*invN - mu*mu;
    float a = g1[t&1]*rsqrtf(var + 1e-5f);
    cab[t] = a; cab[16+t] = b1[t&1] - mu*a;
  }
  int b = blockIdx.x;
  for (int i=t; i<960; i+=256){
    int r = i>>5, c = i&31;
    int iy = r-1, ix = c-1;
    xs[i] = (iy>=0 && iy<28 && ix>=0 && ix<28) ? x[(size_t)b*784 + iy*28 + ix] : 0.f;
  }
  for (int i=t; i<3840; i+=256) ((unsigned long long*)Ls)[i] = 0ULL;
  __syncthreads();
  for (int i=t; i<784; i+=256){
    int py = i/28, px = i - 28*(i/28);
    float tap[9];
    #pragma unroll
    for (int d=0; d<9; d++) tap[d] = xs[(py + d/3)*32 + px + d%3];
    float y[16];
    #pragma unroll
    for (int rot=0; rot<8; rot++){
      #pragma unroll
      for (int u=0; u<2; u++){
        float acc1 = 0.f;
        #pragma unroll
        for (int k=0; k<9; k++) acc1 += wa[u*9+k]*tap[DST[rot][k]];
        y[rot*2+u] = acc1;
      }
    }
    unsigned long long pk[4];
    #pragma unroll
    for (int q=0; q<4; q++){
      float4 A = *(const float4*)(cab + q*4);
      float4 Bv = *(const float4*)(cab + 16 + q*4);
      float r0 = fmaxf(y[q*4+0]*A.x + Bv.x, 0.f);
      float r1 = fmaxf(y[q*4+1]*A.y + Bv.y, 0.f);
      float r2 = fmaxf(y[q*4+2]*A.z + Bv.z, 0.f);
      float r3 = fmaxf(y[q*4+3]*A.w + Bv.w, 0.f);
      unsigned int lo = cvtpk(r0, r1);
      unsigned int hi = cvtpk(r2, r3);
      pk[q] = (unsigned long long)lo | ((unsigned long long)hi<<32);
    }
    int cell = (py+1)*32 + px + 1;
    unsigned long long* dstp = (unsigned long long*)(Ls + cell*16);
    dstp[0]=pk[0]; dstp[1]=pk[1]; dstp[2]=pk[2]; dstp[3]=pk[3];
  }
  __syncthreads();
  // hoisted per-j LDS element offsets; tap deltas are compile-time immediates
  int jb[13];
  #pragma unroll
  for (int j=0;j<13;j++){
    int mt = wid + 4*j;
    int pos = (mt < 49) ? (mt*16 + m) : 0;
    int py = pos/28, px = pos - 28*py;
    jb[j] = (py*32 + px)*16 + (quad&1)*8;
  }
  f32x4 acc[13];
  #pragma unroll
  for (int j=0;j<13;j++) acc[j] = (f32x4){0.f,0.f,0.f,0.f};
  #pragma unroll
  for (int c=0;c<5;c++){
    const int tapA = 2*c, tapB = (2*c+1 < 9) ? 2*c+1 : 8;
    const int offA = ((tapA/3)*32 + tapA%3)*16;
    const int offB = ((tapB/3)*32 + tapB%3)*16;
    int sel = (quad < 2) ? offA : offB;
    bf16x8 Bf = *(const bf16x8*)(B2 + (c*16 + m)*32 + quad*8);
    #pragma unroll
    for (int j=0;j<13;j++){
      int mt = wid + 4*j;
      if (mt >= 49) continue;
      bf16x8 Af = *(const bf16x8*)(Ls + jb[j] + sel);
      acc[j] = __builtin_amdgcn_mfma_f32_16x16x32_bf16(Af, Bf, acc[j], 0, 0, 0);
    }
  }
  __syncthreads();   // done reading Ls; reuse as out2
  float s = 0.f, sq = 0.f;
  #pragma unroll
  for (int j=0;j<13;j++){
    int mt = wid + 4*j;
    if (mt >= 49) continue;
    #pragma unroll
    for (int p=0;p<2;p++){
      // pos0 = mt*16 + quad*4 + 2p is even and never wraps a row: (r0,r1) horizontal pool pair
      int pos0 = mt*16 + quad*4 + p*2;
      float v0 = acc[j][2*p], v1 = acc[j][2*p+1];
      s += v0 + v1; sq += v0*v0 + v1*v1;
      float hm = fmaxf(v0, v1);
      int py = pos0/28, px2 = (pos0 - py*28)>>1;
      out2[(py*14+px2)*17 + m] = hm;
    }
  }
  s += __shfl_down(s,32);  s += __shfl_down(s,16);
  sq += __shfl_down(sq,32); sq += __shfl_down(sq,16);
  if (lane < 16){ red[wid][m] = s; red[wid][16+m] = sq; }
  __syncthreads();
  if (t < 32){
    float v = red[0][t]+red[1][t]+red[2][t]+red[3][t];
    int ch = t & 15, kind = t >> 4;
    atomicAdd(ST_ADDR(stout, ch, kind, b & 3), v);
  }
  unsigned short* pb = p2b + (size_t)b*4096;
  for (int i=t; i<3136; i+=256){
    int cell = i>>4, oc = i&15;
    int yo = cell/14, xo = cell - yo*14;
    float mx = fmaxf(out2[((2*yo)*14+xo)*17 + oc], out2[((2*yo+1)*14+xo)*17 + oc]);
    pb[((yo+1)*16 + xo + 1)*16 + oc] = f2bf(mx);
  }
  for (int i=t; i<960; i+=256){
    int bc = border_cell(i>>4), oc = i&15;
    pb[bc*16 + oc] = f2bf(SENT);
  }
}

// ---------------- conv3 MFMA: 16->32 rotated over 14x14, bn2 coef in-block; BF16 I/O, packed decode/encode ----------------
__global__ __launch_bounds__(256, 2) void k_conv3m(const unsigned short* __restrict__ p2b,
                                                   const unsigned short* __restrict__ B3,  // [5][32][32] bf16
                                                   const float* __restrict__ stin,
                                                   const float* __restrict__ g2, const float* __restrict__ b2,
                                                   unsigned short* __restrict__ y3b,
                                                   float* __restrict__ stout){
  __shared__ unsigned short Ls[256*16];
  __shared__ float ca[16], cb[16];
  __shared__ float red[4][64];
  int t = threadIdx.x;
  int wid = t>>6, lane = t&63;
  int quad = lane>>4, m = lane&15;
  int b = blockIdx.x;
  // staging loads issued FIRST so HBM latency overlaps the stats/coef phase
  const unsigned short* sb = p2b + (size_t)b*4096;
  uint4 Uw0 = *(const uint4*)(sb + (size_t)t*16);
  uint4 Uw1 = *(const uint4*)(sb + (size_t)t*16 + 8);
  if (t < 16){
    const float invN = 1.f/1605632.f;
    float mu = st_read(stin, t, 0)*invN;
    float var = st_read(stin, t, 1)*invN - mu*mu;
    float a = g2[t&1]*rsqrtf(var + 1e-5f);
    ca[t] = a; cb[t] = b2[t&1] - mu*a;
  }
  __syncthreads();
  {
    unsigned int p0 = bnpair(Uw0.x, ca[0],cb[0], ca[1],cb[1]);
    unsigned int p1 = bnpair(Uw0.y, ca[2],cb[2], ca[3],cb[3]);
    unsigned int p2 = bnpair(Uw0.z, ca[4],cb[4], ca[5],cb[5]);
    unsigned int p3 = bnpair(Uw0.w, ca[6],cb[6], ca[7],cb[7]);
    unsigned int p4 = bnpair(Uw1.x, ca[8],cb[8], ca[9],cb[9]);
    unsigned int p5 = bnpair(Uw1.y, ca[10],cb[10], ca[11],cb[11]);
    unsigned int p6 = bnpair(Uw1.z, ca[12],cb[12], ca[13],cb[13]);
    unsigned int p7 = bnpair(Uw1.w, ca[14],cb[14], ca[15],cb[15]);
    unsigned long long* dstp = (unsigned long long*)(Ls + t*16);
    dstp[0] = (unsigned long long)p0 | ((unsigned long long)p1<<32);
    dstp[1] = (unsigned long long)p2 | ((unsigned long long)p3<<32);
    dstp[2] = (unsigned long long)p4 | ((unsigned long long)p5<<32);
    dstp[3] = (unsigned long long)p6 | ((unsigned long long)p7<<32);
  }
  __syncthreads();
  int jb[4]; bool vt[4];
  #pragma unroll
  for (int j=0;j<4;j++){
    int mt = wid + 4*j;
    int pos = mt*16 + m;
    vt[j] = (mt <= 12);
    if (pos >= 196) pos = 0;
    int py = pos/14, px = pos - 14*(pos/14);
    jb[j] = (py*16 + px)*16 + (quad&1)*8;
  }
  unsigned short* yb = y3b + (size_t)b*8192;
  float sa[2], sqa[2];
  #pragma unroll
  for (int nt=0; nt<2; nt++){
    f32x4 acc[4];
    #pragma unroll
    for (int j=0;j<4;j++) acc[j] = (f32x4){0.f,0.f,0.f,0.f};
    #pragma unroll
    for (int c=0;c<5;c++){
      const int tapA = 2*c, tapB = (2*c+1 < 9) ? 2*c+1 : 8;
      const int offA = ((tapA/3)*16 + tapA%3)*16;
      const int offB = ((tapB/3)*16 + tapB%3)*16;
      int sel = (quad < 2) ? offA : offB;
      bf16x8 Bf = *(const bf16x8*)(B3 + (c*32 + nt*16 + m)*32 + quad*8);
      #pragma unroll
      for (int j=0;j<4;j++){
        if (!vt[j]) continue;
        bf16x8 Af = *(const bf16x8*)(Ls + jb[j] + sel);
        acc[j] = __builtin_amdgcn_mfma_f32_16x16x32_bf16(Af, Bf, acc[j], 0, 0, 0);
      }
    }
    float s = 0.f, sq = 0.f;
    #pragma unroll
    for (int j=0;j<4;j++){
      if (!vt[j]) continue;
      int mt = wid + 4*j;
      #pragma unroll
      for (int r=0;r<4;r++){
        int pos = mt*16 + quad*4 + r;
        if (pos < 196){
          float v = acc[j][r];
          int py2 = pos/14, px2 = pos - py2*14;
          yb[(size_t)((py2+1)*16 + px2 + 1)*32 + nt*16 + m] = f2bf(v);
          s += v; sq += v*v;
        }
      }
    }
    s += __shfl_down(s,32);  s += __shfl_down(s,16);
    sq += __shfl_down(sq,32); sq += __shfl_down(sq,16);
    sa[nt] = s; sqa[nt] = sq;
  }
  if (lane < 16){
    red[wid][m]      = sa[0];  red[wid][32+m]      = sqa[0];
    red[wid][16+m]   = sa[1];  red[wid][32+16+m]   = sqa[1];
  }
  __syncthreads();
  if (t < 64){
    float v = red[0][t]+red[1][t]+red[2][t]+red[3][t];
    int ch = t & 31, kind = t >> 5;
    atomicAdd(ST_ADDR(stout, ch, kind, b & 3), v);
  }
  for (int i=t; i<1920; i+=256){
    int bc = border_cell(i>>5), oc = i&31;
    yb[(size_t)bc*32 + oc] = f2bf(SENT);
  }
}

// ---------------- conv4 WAVE-PER-IMAGE: grid 512 x 4 waves; zero barriers in main flow ----------------
// Each wave owns image b = blk*4+wid and a private 16KB LDS act plane [256 cells][32ch bf16],
// stored with a 16B-chunk XOR swizzle (chunk' = chunk ^ (cell&3)) for conflict-free b128 reads.
// Single fused nt pass (acc[13][2], Af reused for both oc halves). hp pool staging reuses act.
__global__ __launch_bounds__(256, 2) void k_conv4w(const unsigned short* __restrict__ y3b,
                                                   const unsigned short* __restrict__ wb4, // [9][32][32] bf16
                                                   const float* __restrict__ stin,
                                                   const float* __restrict__ g3, const float* __restrict__ b3,
                                                   float* __restrict__ p4,
                                                   float* __restrict__ stout,
                                                   float* __restrict__ nmsa){
  __shared__ unsigned short act[4][8192];   // 64 KB: per-wave act plane, later reused as hp f32 [98][33]
  __shared__ float ca[32], cb[32];
  __shared__ float red[4][64];
  int t = threadIdx.x;
  int wid = t>>6, lane = t&63;
  int quad = lane>>4, m = lane&15;
  if (t < 32){
    const float invN = 1.f/401408.f;
    float mu = st_read(stin, t, 0)*invN;
    float var = st_read(stin, t, 1)*invN - mu*mu;
    float a = g3[t&3]*rsqrtf(var + 1e-5f);
    ca[t] = a; cb[t] = b3[t&3] - mu*a;
  }
  __syncthreads();                           // ONLY entry barrier (coef ready)
  int b = blockIdx.x*4 + wid;
  unsigned short* A = act[wid];
  const unsigned short* sb = y3b + (size_t)b*8192;
  // ---- staging: 4 cells per lane, chunk-swizzled ds writes (own region, no barrier) ----
  #pragma unroll
  for (int k=0;k<4;k++){
    int cell = lane + 64*k;
    const uint4* src = (const uint4*)(sb + cell*32);
    int sw = cell & 3;
    unsigned short* dst = A + cell*32;
    #pragma unroll
    for (int c=0;c<4;c++){
      uint4 W = src[c];
      int c0 = c*8;
      unsigned int q0 = bnpair(W.x, ca[c0+0],cb[c0+0], ca[c0+1],cb[c0+1]);
      unsigned int q1 = bnpair(W.y, ca[c0+2],cb[c0+2], ca[c0+3],cb[c0+3]);
      unsigned int q2 = bnpair(W.z, ca[c0+4],cb[c0+4], ca[c0+5],cb[c0+5]);
      unsigned int q3 = bnpair(W.w, ca[c0+6],cb[c0+6], ca[c0+7],cb[c0+7]);
      unsigned long long* q = (unsigned long long*)(dst + ((c ^ sw)<<3));
      q[0] = (unsigned long long)q0 | ((unsigned long long)q1<<32);
      q[1] = (unsigned long long)q2 | ((unsigned long long)q3<<32);
    }
  }
  asm volatile("s_waitcnt lgkmcnt(0)" ::: "memory");
  __builtin_amdgcn_sched_barrier(0);
  // ---- NMS over own image (reads act, wave-local) ----
  float nloc = 0.f;
  for (int i=lane; i<784; i+=64){
    int hw = i>>2, c4 = i&3;
    int cell = (hw/14 + 1)*16 + hw%14 + 1;
    const unsigned int* g32 = (const unsigned int*)(A + cell*32 + ((c4 ^ (cell&3))<<3));
    unsigned int w0 = g32[0], w1 = g32[1], w2 = g32[2], w3 = g32[3];
    float v[8];
    v[0] = __uint_as_float(w0 << 16); v[1] = __uint_as_float(w0 & 0xFFFF0000u);
    v[2] = __uint_as_float(w1 << 16); v[3] = __uint_as_float(w1 & 0xFFFF0000u);
    v[4] = __uint_as_float(w2 << 16); v[5] = __uint_as_float(w2 & 0xFFFF0000u);
    v[6] = __uint_as_float(w3 << 16); v[7] = __uint_as_float(w3 & 0xFFFF0000u);
    float vmax = -1e30f;
    #pragma unroll
    for (int r=0;r<8;r++) vmax = fmaxf(vmax, v[r]);
    #pragma unroll
    for (int r=0;r<8;r++) nloc += (v[r] != vmax) ? v[r] : 0.f;
  }
  #pragma unroll
  for (int off=32; off; off>>=1) nloc += __shfl_down(nloc, off);
  if (lane == 0) atomicAdd(&nmsa[(b & 7)*32], nloc);
  // ---- MFMA: 13 m-tiles x 9 taps x 2 oc-halves, Af shared across halves ----
  int jc[13], jp[13];
  #pragma unroll
  for (int j=0;j<13;j++){
    int pos = j*16 + m;
    if (pos >= 196) pos = 0;
    int py = pos/14, px = pos - 14*(pos/14);
    jc[j] = py*16 + px;
    jp[j] = px;
  }
  f32x4 acc[13][2];
  #pragma unroll
  for (int j=0;j<13;j++){ acc[j][0] = (f32x4){0,0,0,0}; acc[j][1] = (f32x4){0,0,0,0}; }
  #pragma unroll
  for (int tap=0; tap<9; tap++){
    const int dy = tap/3, dx = tap - 3*(tap/3);
    bf16x8 Bf0 = *(const bf16x8*)(wb4 + (tap*32 + m)*32 + quad*8);
    bf16x8 Bf1 = *(const bf16x8*)(wb4 + (tap*32 + 16 + m)*32 + quad*8);
    #pragma unroll
    for (int j=0;j<13;j++){
      int ci = jc[j] + dy*16 + dx;
      int ph = quad ^ ((jp[j]+dx)&3);
      bf16x8 Af = *(const bf16x8*)(A + ci*32 + ph*8);
      acc[j][0] = __builtin_amdgcn_mfma_f32_16x16x32_bf16(Af, Bf0, acc[j][0], 0, 0, 0);
      acc[j][1] = __builtin_amdgcn_mfma_f32_16x16x32_bf16(Af, Bf1, acc[j][1], 0, 0, 0);
    }
  }
  asm volatile("s_waitcnt lgkmcnt(0)" ::: "memory");
  __builtin_amdgcn_sched_barrier(0);
  // ---- epilogue: stats + in-register horizontal pool -> hp (reuses act region), wave-local ----
  float* hp = (float*)A;                    // 98*33*4 = 12936 B <= 16384 B
  float s0=0.f, sq0=0.f, s1=0.f, sq1=0.f;
  #pragma unroll
  for (int j=0;j<13;j++){
    #pragma unroll
    for (int p=0;p<2;p++){
      int pos0 = j*16 + quad*4 + 2*p;       // even, px even -> horizontal pool pair
      if (pos0 + 1 < 196){
        float a0 = acc[j][0][2*p], a1 = acc[j][0][2*p+1];
        float b0 = acc[j][1][2*p], b1 = acc[j][1][2*p+1];
        s0 += a0 + a1; sq0 += a0*a0 + a1*a1;
        s1 += b0 + b1; sq1 += b0*b0 + b1*b1;
        int py0 = pos0/14, pxh = (pos0 - py0*14)>>1;
        hp[(py0*7 + pxh)*33 + m]      = fmaxf(a0, a1);
        hp[(py0*7 + pxh)*33 + 16 + m] = fmaxf(b0, b1);
      }
    }
  }
  s0 += __shfl_down(s0,32); s0 += __shfl_down(s0,16);
  sq0 += __shfl_down(sq0,32); sq0 += __shfl_down(sq0,16);
  s1 += __shfl_down(s1,32); s1 += __shfl_down(s1,16);
  sq1 += __shfl_down(sq1,32); sq1 += __shfl_down(sq1,16);
  if (lane < 16){
    red[wid][m]      = s0;  red[wid][32+m]      = sq0;
    red[wid][16+m]   = s1;  red[wid][32+16+m]   = sq1;
  }
  asm volatile("s_waitcnt lgkmcnt(0)" ::: "memory");
  __builtin_amdgcn_sched_barrier(0);
  // ---- vertical pool from hp -> p4 (wave-local) ----
  for (int i=lane; i<1568; i+=64){
    int cell = i>>5, oc = i&31;
    int yo = cell/7, xo = cell - yo*7;
    float mx = fmaxf(hp[((2*yo)*7 + xo)*33 + oc], hp[((2*yo+1)*7 + xo)*33 + oc]);
    p4[((size_t)b*49 + cell)*32 + oc] = mx;
  }
  __syncthreads();                           // ONLY exit barrier (stats reduce)
  if (t < 64){
    float v = red[0][t]+red[1][t]+red[2][t]+red[3][t];
    int ch = t & 31, kind = t >> 5;
    atomicAdd(ST_ADDR(stout, ch, kind, blockIdx.x & 3), v);
  }
}

// ---------------- conv5/conv6 MFMA: CI->64, per-wave batch, bn coef in-block, shift-GEMM over 9 taps ----------------
template<int CI>
__global__ __launch_bounds__(256, 2) void k_conv56m(const float* __restrict__ src,
                                                    const unsigned short* __restrict__ wb,  // [9][64][CI] bf16
                                                    const float* __restrict__ stin,
                                                    const float* __restrict__ g, const float* __restrict__ be,
                                                    float invN,
                                                    float* __restrict__ dst,
                                                    float* __restrict__ stout){
  constexpr int CIP = CI + 8;
  constexpr int KC = CI/32;
  __shared__ unsigned short lin[4][81*CIP];
  __shared__ float red[4][256];
  __shared__ float ca[CI], cb[CI];
  int wid = threadIdx.x>>6, lane = threadIdx.x&63;
  int quad = lane>>4, m = lane&15;
  unsigned short* L = lin[wid];
  if (threadIdx.x < CI){
    int i = threadIdx.x;
    float mu = st_read(stin, i, 0)*invN;
    float var = st_read(stin, i, 1)*invN - mu*mu;
    float a = g[i]*rsqrtf(var + 1e-5f);
    ca[i] = a; cb[i] = be[i] - mu*a;
  }
  for (int i = lane; i < 81*CIP/4; i += 64) ((unsigned long long*)L)[i] = 0ULL;
  __syncthreads();
  int b = blockIdx.x*4 + wid;
  const float* sb = src + (size_t)b*49*CI;
  for (int i = lane; i < 49*CI/4; i += 64){
    int pos = i/(CI/4), cig = i - pos*(CI/4);
    float4 v = *(const float4*)(sb + pos*CI + cig*4);
    float r0 = fmaxf(v.x*ca[cig*4]  +cb[cig*4],   0.f);
    float r1 = fmaxf(v.y*ca[cig*4+1]+cb[cig*4+1], 0.f);
    float r2 = fmaxf(v.z*ca[cig*4+2]+cb[cig*4+2], 0.f);
    float r3 = fmaxf(v.w*ca[cig*4+3]+cb[cig*4+3], 0.f);
    int pos9 = (pos/7 + 1)*9 + pos%7 + 1;
    unsigned int lo = cvtpk(r0, r1);
    unsigned int hi = cvtpk(r2, r3);
    *(unsigned long long*)(L + pos9*CIP + cig*4) =
        (unsigned long long)lo | ((unsigned long long)hi<<32);
  }
  __syncthreads();
  int py[4], px[4];
  #pragma unroll
  for (int mt=0; mt<4; mt++){
    int pos = mt*16 + m;
    if (pos < 49){ py[mt] = pos/7; px[mt] = pos%7; }
    else { py[mt] = 0; px[mt] = 0; }
  }
  f32x4 acc[4][4];
  #pragma unroll
  for (int nt=0; nt<4; nt++)
    #pragma unroll
    for (int mt=0; mt<4; mt++) acc[nt][mt] = (f32x4){0.f,0.f,0.f,0.f};

  for (int tap=0; tap<9; tap++){
    int dy = tap/3, dx = tap - dy*3;
    int o9[4];
    #pragma unroll
    for (int mt=0; mt<4; mt++) o9[mt] = ((py[mt]+dy)*9 + px[mt]+dx)*CIP;
    #pragma unroll
    for (int kc=0; kc<KC; kc++){
      int ko = kc*32 + quad*8;
      bf16x8 Bf[4], Af[4];
      #pragma unroll
      for (int nt=0; nt<4; nt++)
        Bf[nt] = *(const bf16x8*)(wb + (tap*64 + nt*16 + m)*CI + ko);
      #pragma unroll
      for (int mt=0; mt<4; mt++)
        Af[mt] = *(const bf16x8*)(L + o9[mt] + ko);
      #pragma unroll
      for (int nt=0; nt<4; nt++)
        #pragma unroll
        for (int mt=0; mt<4; mt++)
          acc[nt][mt] = __builtin_amdgcn_mfma_f32_16x16x32_bf16(Af[mt], Bf[nt], acc[nt][mt], 0, 0, 0);
    }
  }
  float* db = dst + (size_t)b*49*64;
  float snt[4], sqnt[4];
  #pragma unroll
  for (int nt=0; nt<4; nt++){
    float s = 0.f, sq = 0.f;
    #pragma unroll
    for (int mt=0; mt<4; mt++){
      #pragma unroll
      for (int r=0; r<4; r++){
        int pos = mt*16 + quad*4 + r;
        if (pos < 49){
          float v = acc[nt][mt][r];
          db[pos*64 + nt*16 + m] = v;
          s += v; sq += v*v;
        }
      }
    }
    s += __shfl_down(s, 32);  s += __shfl_down(s, 16);
    sq += __shfl_down(sq, 32); sq += __shfl_down(sq, 16);
    snt[nt] = s; sqnt[nt] = sq;
  }
  if (lane < 16){
    #pragma unroll
    for (int nt=0; nt<4; nt++){
      red[wid][nt*16 + lane] = snt[nt];
      red[wid][128 + nt*16 + lane] = sqnt[nt];
    }
  }
  __syncthreads();
  if (threadIdx.x < 128){
    int c = threadIdx.x & 63;
    int off = (threadIdx.x < 64) ? threadIdx.x : (128 + c);
    float v = red[0][off]+red[1][off]+red[2][off]+red[3][off];
    int kind = (threadIdx.x < 64) ? 0 : 1;
    atomicAdd(ST_ADDR(stout, c, kind, blockIdx.x & 3), v);
  }
}

// ---------------- bn6+relu + 2x2 pool pad 1 (7 -> 4); COMPACT PRECOMPUTED COEF; y6 -> p6b bf16 ----------------
__global__ __launch_bounds__(256) void k_pool6(const float* __restrict__ y,
                                               const float* __restrict__ cf,   // [64] a | [64] b
                                               unsigned short* __restrict__ p6b){
  int idx = blockIdx.x*256 + threadIdx.x;       // NB*16*64 exact
  int oc = idx & 63; int t2 = idx >> 6;
  int xo = t2 & 3;  int yo = (t2>>2) & 3;  int b = t2 >> 4;
  float a = cf[oc];
  float bo = cf[64 + oc];
  const float* src = y + (size_t)b*3136;
  float mx = -1e30f;
  #pragma unroll
  for (int dy=0;dy<2;dy++){
    int iy = yo*2 - 1 + dy;
    if (iy < 0 || iy >= 7) continue;
    #pragma unroll
    for (int dx=0;dx<2;dx++){
      int ix = xo*2 - 1 + dx;
      if (ix < 0 || ix >= 7) continue;
      mx = fmaxf(mx, src[(iy*7+ix)*64 + oc]*a + bo);
    }
  }
  p6b[(size_t)b*1024 + (yo*4 + xo)*64 + oc] = f2bf(fmaxf(mx, 0.f));
}

// ---------------- conv7 as GEMM: M=2048 (batch), N=256 (pos25*10+o), K=1024; partial max per N-block ----------------
__global__ __launch_bounds__(256) void k_gemm7(const unsigned short* __restrict__ A,   // [2048][1024] bf16
                                               const unsigned short* __restrict__ Bl,  // [256][1024] bf16
                                               float* __restrict__ part){              // [2048][4][10]
  __shared__ float Lw[4][16*65];
  int wid = threadIdx.x>>6, lane = threadIdx.x&63;
  int quad = lane>>4, m = lane&15;
  int blkm = blockIdx.x >> 2, blkn = blockIdx.x & 3;   // grid 128
  int rowb = blkm*64 + wid*16 + m;
  const unsigned short* Arow = A + (size_t)rowb*1024;
  f32x4 acc[4];
  #pragma unroll
  for (int nt=0; nt<4; nt++) acc[nt] = (f32x4){0.f,0.f,0.f,0.f};
  for (int kc=0; kc<32; kc++){
    bf16x8 Af = *(const bf16x8*)(Arow + kc*32 + quad*8);
    #pragma unroll
    for (int nt=0; nt<4; nt++){
      bf16x8 Bf = *(const bf16x8*)(Bl + (size_t)(blkn*64 + nt*16 + m)*1024 + kc*32 + quad*8);
      acc[nt] = __builtin_amdgcn_mfma_f32_16x16x32_bf16(Af, Bf, acc[nt], 0, 0, 0);
    }
  }
  float* Lp = &Lw[wid][0];
  #pragma unroll
  for (int nt=0; nt<4; nt++)
    #pragma unroll
    for (int r=0; r<4; r++)
      Lp[(quad*4+r)*65 + nt*16 + m] = acc[nt][r];
  __syncthreads();
  for (int i=lane; i<160; i+=64){
    int br = i/10, o = i - 10*(i/10);
    int c0 = ((o - blkn*64) % 10 + 10) % 10;
    float mx = -1e30f;
    for (int c=c0; c<64; c+=10){
      if (blkn*64 + c < 250) mx = fmaxf(mx, Lp[br*65 + c]);
    }
    part[((size_t)(blkm*64 + wid*16 + br)*4 + blkn)*10 + o] = mx;
  }
}

// ---------------- logits: max over 4 N-block partials + bias; nms write ----------------
__global__ __launch_bounds__(256) void k_logits(const float* __restrict__ part,
                                                const float* __restrict__ bias,
                                                const float* __restrict__ nmsa,
                                                float* __restrict__ out){
  int idx = blockIdx.x*256 + threadIdx.x;       // 20480 exact (80 blocks)
  int b = idx/10, o = idx - 10*(idx/10);
  const float* p = part + (size_t)b*40 + o;
  float mx = fmaxf(fmaxf(p[0], p[10]), fmaxf(p[20], p[30]));
  out[idx] = mx + bias[o];
  if (blockIdx.x == 0 && threadIdx.x == 0){
    float nm = 0.f;
    #pragma unroll
    for (int cp=0; cp<8; cp++) nm += nmsa[cp*32];
    out[20480] = nm * (1.f/12845056.f);
  }
}

extern "C" void kernel_launch(void* const* d_in, const int* in_sizes, int n_in,
                              void* d_out, int out_size, void* d_ws, size_t ws_size,
                              hipStream_t stream){
  const float* x  = (const float*)d_in[0];
  const float* w1 = (const float*)d_in[1];
  const float* w2 = (const float*)d_in[2];
  const float* w3 = (const float*)d_in[3];
  const float* w4 = (const float*)d_in[4];
  const float* w5 = (const float*)d_in[5];
  const float* w6 = (const float*)d_in[6];
  const float* w7 = (const float*)d_in[7];
  const float* g1 = (const float*)d_in[8];
  const float* b1 = (const float*)d_in[9];
  const float* g2 = (const float*)d_in[10];
  const float* b2 = (const float*)d_in[11];
  const float* g3 = (const float*)d_in[12];
  const float* b3 = (const float*)d_in[13];
  const float* g4 = (const float*)d_in[14];
  const float* b4 = (const float*)d_in[15];
  const float* g5 = (const float*)d_in[16];
  const float* b5 = (const float*)d_in[17];
  const float* g6 = (const float*)d_in[18];
  const float* b6 = (const float*)d_in[19];
  const float* b7 = (const float*)d_in[20];
  float* out = (float*)d_out;
  float* W = (float*)d_ws;

  // arena (float units)
  unsigned short* p2b = (unsigned short*)(W + 15728640); // 2048*256*16 bf16 (16.8 MB, region holds 33.5 MB)
  unsigned short* y3b = (unsigned short*)(W + 24117248); // 2048*256*32 bf16 (33.6 MB, region holds 67 MB)
  float* p4   = W + 0;                 //  3,211,264  (2048*49*32) -> ends 3,211,264
  // line-padded stats arena lives in the verified-free gap [3211264, 3407872):
  //   6 layers x 8192 floats + 8-copy nms (256) + cf6 (128) = 49,536 floats -> ends 3,260,800 < 3,407,872.
  float* st   = W + 3211264;
  float* nmsa = st + 6*8192;
  float* cf6  = nmsa + 256;
  float* y5   = W + 3407872;           //  6,422,528  (2048*49*64)
  float* y6   = W + 10223616;          //  6,422,528
  unsigned short* p6b = (unsigned short*)(W + 16646144); // 2048*1024 bf16
  unsigned short* wb5 = (unsigned short*)(W + 40894464);  // 9*64*32 bf16
  unsigned short* wb6 = (unsigned short*)(W + 40912896);  // 9*64*64 bf16
  unsigned short* wb4 = (unsigned short*)(W + 40931328);  // 9*32*32 bf16
  unsigned short* Bl = (unsigned short*)(W + 40951808);   // 256*1024 bf16
  float* part = W + 41082880;          //  81,920 (2048*4*10)
  unsigned short* B2 = (unsigned short*)(W + 41164800);   // 5*16*32 bf16 (1280 floats)
  unsigned short* B3 = (unsigned short*)(W + 41166080);   // 5*32*32 bf16 (2560 floats)

  hipMemsetAsync(st, 0, 49536*sizeof(float), stream);

  k_pre<<<1819,256,0,stream>>>(x, w1, w2, w3, w4, w5, w6, w7,
                               B2, B3, wb4, wb5, wb6, Bl, st + 0*8192);

  k_conv2m<<<2048,256,0,stream>>>(x, w1, B2, st + 0*8192, g1, b1, p2b, st + 1*8192);

  k_conv3m<<<2048,256,0,stream>>>(p2b, B3, st + 1*8192, g2, b2, y3b, st + 2*8192);

  k_conv4w<<<512,256,0,stream>>>(y3b, wb4, st + 2*8192, g3, b3, p4, st + 3*8192, nmsa);

  k_conv56m<32><<<512,256,0,stream>>>(p4, wb5, st + 3*8192, g4, b4, 1.f/401408.f, y5, st + 4*8192);

  k_conv56m<64><<<512,256,0,stream>>>(y5, wb6, st + 4*8192, g5, b5, 1.f/100352.f, y6, st + 5*8192);

  k_coef<64><<<1,64,0,stream>>>(st + 5*8192, g6, b6, 1.f/100352.f, 63, cf6);

  k_pool6<<<8192,256,0,stream>>>(y6, cf6, p6b);

  k_gemm7<<<128,256,0,stream>>>(p6b, Bl, part);
  k_logits<<<80,256,0,stream>>>(part, b7, nmsa, out);
}

// Round 11
// 263.039 us; speedup vs baseline: 1.3637x; 1.0712x over previous
//
#include <hip/hip_runtime.h>

static constexpr int NB = 2048;
static constexpr float SENT = -1e30f;

typedef __attribute__((ext_vector_type(8))) short bf16x8;
typedef __attribute__((ext_vector_type(8))) unsigned short u16x8;
typedef __attribute__((ext_vector_type(4))) float f32x4;

// Stats arena: layer slot = 8192 floats. Line-padded atomics:
//   addr(ch, kind, copy) = base + (ch*4 + copy)*32 + kind*8   (kind 0=sum, 1=sumsq; copy 0..3)
#define ST_ADDR(base, ch, kind, copy) ((base) + (((ch)*4 + (copy))*32 + (kind)*8))

// rotated-3x3 tap permutation: weight tap k of rotation r lands at patch position DST[r][k]
static constexpr int DST[8][9] = {
  {8,7,6,5,4,3,2,1,0},
  {5,8,7,2,4,6,1,0,3},
  {2,5,8,1,4,7,0,3,6},
  {1,2,5,0,4,8,3,6,7},
  {0,1,2,3,4,5,6,7,8},
  {3,0,1,6,4,2,7,8,5},
  {6,3,0,7,4,1,8,5,2},
  {7,6,3,8,4,0,5,2,1},
};

__device__ __forceinline__ unsigned short f2bf(float f){
  unsigned int u = __float_as_uint(f);
  u += 0x7fffu + ((u>>16)&1u);          // RNE
  return (unsigned short)(u>>16);
}

__device__ __forceinline__ float bf2f(unsigned short h){
  return __uint_as_float((unsigned int)h << 16);
}

// 2×f32 -> packed 2×bf16 in ONE instruction (gfx950; no builtin exposed)
__device__ __forceinline__ unsigned int cvtpk(float lo, float hi){
  unsigned int r;
  asm("v_cvt_pk_bf16_f32 %0, %1, %2" : "=v"(r) : "v"(lo), "v"(hi));
  return r;
}

// bn+relu+requant for a packed bf16 pair held in one u32 word
__device__ __forceinline__ unsigned int bnpair(unsigned int w, float a0, float b0, float a1, float b1){
  float vlo = __uint_as_float(w << 16);
  float vhi = __uint_as_float(w & 0xFFFF0000u);
  float r0 = fmaxf(vlo*a0 + b0, 0.f);
  float r1 = fmaxf(vhi*a1 + b1, 0.f);
  return cvtpk(r0, r1);
}

__device__ __forceinline__ float st_read(const float* base, int ch, int kind){
  return base[((ch*4+0)*32 + kind*8)] + base[((ch*4+1)*32 + kind*8)]
       + base[((ch*4+2)*32 + kind*8)] + base[((ch*4+3)*32 + kind*8)];
}

// border cell index (16x16 plane) for border id t<60
__device__ __forceinline__ int border_cell(int t){
  if (t<16) return t;
  if (t<32) return 240 + (t-16);
  if (t<46) return (t-31)*16;
  return (t-45)*16 + 15;
}

// ---------------- pre: weight packs (blocks 0..282) + conv7 B (283..1306) + bn1 stats (1307..1818) ----------------
__global__ __launch_bounds__(256) void k_pre(const float* __restrict__ x, const float* __restrict__ w1,
                                             const float* __restrict__ w2, const float* __restrict__ w3,
                                             const float* __restrict__ w4,
                                             const float* __restrict__ w5, const float* __restrict__ w6,
                                             const float* __restrict__ w7,
                                             unsigned short* __restrict__ B2,
                                             unsigned short* __restrict__ B3,
                                             unsigned short* __restrict__ wb4,
                                             unsigned short* __restrict__ wb5, unsigned short* __restrict__ wb6,
                                             unsigned short* __restrict__ Bl,
                                             float* __restrict__ st){
  int blk = blockIdx.x;
  if (blk < 283){
    int i = blk*256 + threadIdx.x;
    if (i < 18432){                                  // 9*64*32
      int tap = i/2048, rem = i%2048, oc = rem/32, ci = rem%32;
      wb5[i] = f2bf(w5[(oc*32+ci)*9 + tap]);
    } else if (i < 55296){                           // + 9*64*64
      int j = i - 18432;
      int tap = j/4096, rem = j%4096, oc = rem/64, ci = rem%64;
      wb6[j] = f2bf(w6[(oc*64+ci)*9 + tap]);
    } else if (i < 64512){                           // + 9*32*32
      int j = i - 55296;
      int tap = j/1024, rem = j%1024, oc = rem/32, ci = rem%32;
      wb4[j] = f2bf(w4[(oc*32+ci)*9 + tap]);
    } else if (i < 67072){                           // + conv2 tap-pair pack [5][16][32]
      int j = i - 64512;
      int c = j >> 9;
      int rem = j & 511;
      int o = rem >> 5, k = rem & 31;
      int tap = c*2 + (k>>4);
      int ci = k & 15;
      unsigned short v = 0;
      if (tap <= 8){
        int rot = o>>1, u = o&1;
        int bb = ci>>1, ui = ci&1;
        int wc = (((bb - rot) & 7)<<1) | ui;
        int kk = 0;
        #pragma unroll
        for (int q=0;q<9;q++) if (DST[rot][q]==tap) kk=q;
        v = f2bf(w2[(u*16+wc)*9 + kk]);
      }
      B2[j] = v;
    } else if (i < 72192){                           // + conv3 tap-pair pack [5][32][32]
      int j = i - 67072;
      int c = j >> 10;
      int rem = j & 1023;
      int o = rem >> 5, k = rem & 31;
      int tap = c*2 + (k>>4);
      int ci = k & 15;
      unsigned short v = 0;
      if (tap <= 8){
        int rot = o>>2, uh = (o>>1)&1, ul = o&1;
        int bb = ci>>1, ui = ci&1;
        int wc = (((bb - rot) & 7)<<1) | ui;
        int kk = 0;
        #pragma unroll
        for (int q=0;q<9;q++) if (DST[rot][q]==tap) kk=q;
        v = f2bf(w3[uh*288 + (ul*16+wc)*9 + kk]);
      }
      B3[j] = v;
    }
    return;
  }
  if (blk < 1307){
    int i = (blk-283)*256 + threadIdx.x;             // 262144 exact
    int n = i>>10, k = i&1023;
    int pos16 = k>>6, ci = k&63;
    int r = pos16>>2, c = pos16&3;
    unsigned short v = 0;
    if (n < 250){
      int pos = n/10, o = n - 10*(n/10);
      int py = pos/5, px = pos - 5*(pos/5);
      int ky = r - py + 2, kx = c - px + 2;
      if (ky>=0 && ky<4 && kx>=0 && kx<4) v = f2bf(w7[(o*64+ci)*16 + ky*4 + kx]);
    }
    Bl[i] = v;
    return;
  }
  // ---- bn1 stats over y1 = rotconv1(x); w1 (18 floats) in registers, rotation = compile-time tap permutation ----
  __shared__ float red[4][32];
  float wa[18];
  #pragma unroll
  for (int i=0;i<18;i++) wa[i] = w1[i];
  float s[16], s2[16];
  #pragma unroll
  for (int o=0;o<16;o++){ s[o]=0.f; s2[o]=0.f; }
  for (int idx = (blk-1307)*256 + threadIdx.x; idx < NB*784; idx += 512*256){
    int b = idx/784, pix = idx-b*784;
    int py = pix/28, px = pix-py*28;
    const float* xb = x + (size_t)b*784;
    float tap[9];
    #pragma unroll
    for (int d=0; d<9; d++){
      int dy = d/3-1, dx = d%3-1;
      int yy = py+dy, xx = px+dx;
      tap[d] = (yy>=0 && yy<28 && xx>=0 && xx<28) ? xb[yy*28+xx] : 0.f;
    }
    #pragma unroll
    for (int rot=0; rot<8; rot++){
      #pragma unroll
      for (int u=0; u<2; u++){
        float y = 0.f;
        #pragma unroll
        for (int k=0; k<9; k++) y += wa[u*9+k]*tap[DST[rot][k]];
        int ci = rot*2+u;
        s[ci] += y; s2[ci] += y*y;
      }
    }
  }
  int wid = threadIdx.x>>6;
  #pragma unroll
  for (int o=0;o<16;o++){
    float a = s[o], b2 = s2[o];
    #pragma unroll
    for (int off=32; off; off>>=1){ a += __shfl_down(a,off); b2 += __shfl_down(b2,off); }
    if ((threadIdx.x&63)==0){ red[wid][o] = a; red[wid][16+o] = b2; }
  }
  __syncthreads();
  if (threadIdx.x < 32){
    float v = red[0][threadIdx.x]+red[1][threadIdx.x]+red[2][threadIdx.x]+red[3][threadIdx.x];
    int ch = threadIdx.x & 15, kind = threadIdx.x >> 4;
    atomicAdd(ST_ADDR(st, ch, kind, blk & 3), v);
  }
}

// ---------------- coef: collapse line-padded stats into compact [CI] a / [CI] b coefficients ----------------
template<int CI>
__global__ __launch_bounds__(64) void k_coef(const float* __restrict__ stin,
                                             const float* __restrict__ g, const float* __restrict__ be,
                                             float invN, int gmask,
                                             float* __restrict__ cf){
  int i = threadIdx.x;
  if (i < CI){
    float mu = st_read(stin, i, 0)*invN;
    float var = st_read(stin, i, 1)*invN - mu*mu;
    float a = g[i & gmask]*rsqrtf(var + 1e-5f);
    cf[i] = a; cf[CI + i] = be[i & gmask] - mu*a;
  }
}

// ---------------- conv2 MFMA: recompute y1 from x in-block; bn1 coef in-block; p2 OUTPUT AS BF16 ----------------
__global__ __launch_bounds__(256, 2) void k_conv2m(const float* __restrict__ x,
                                                   const float* __restrict__ w1,
                                                   const unsigned short* __restrict__ B2,  // [5][16][32] bf16
                                                   const float* __restrict__ stin,   // bn1 sums (layer0)
                                                   const float* __restrict__ g1, const float* __restrict__ b1,
                                                   unsigned short* __restrict__ p2b,
                                                   float* __restrict__ stout){
  __shared__ float smemf[8640];
  __shared__ float cab[32];                      // ca[0:16], cb[16:32]
  __shared__ float red[4][32];
  unsigned short* Ls = (unsigned short*)smemf;
  float* xs = smemf + 7680;
  float* out2 = smemf;
  int t = threadIdx.x;
  int wid = t>>6, lane = t&63;
  int quad = lane>>4, m = lane&15;
  float wa[18];
  #pragma unroll
  for (int i=0;i<18;i++) wa[i] = w1[i];
  if (t < 16){
    const float invN = 1.f/1605632.f;
    float mu = st_read(stin, t, 0)*invN;
    float var = st_read(stin, t, 1)*invN - mu*mu;
    float a = g1[t&1]*rsqrtf(var + 1e-5f);
    cab[t] = a; cab[16+t] = b1[t&1] - mu*a;
  }
  int b = blockIdx.x;
  for (int i=t; i<960; i+=256){
    int r = i>>5, c = i&31;
    int iy = r-1, ix = c-1;
    xs[i] = (iy>=0 && iy<28 && ix>=0 && ix<28) ? x[(size_t)b*784 + iy*28 + ix] : 0.f;
  }
  for (int i=t; i<3840; i+=256) ((unsigned long long*)Ls)[i] = 0ULL;
  __syncthreads();
  for (int i=t; i<784; i+=256){
    int py = i/28, px = i - 28*(i/28);
    float tap[9];
    #pragma unroll
    for (int d=0; d<9; d++) tap[d] = xs[(py + d/3)*32 + px + d%3];
    float y[16];
    #pragma unroll
    for (int rot=0; rot<8; rot++){
      #pragma unroll
      for (int u=0; u<2; u++){
        float acc1 = 0.f;
        #pragma unroll
        for (int k=0; k<9; k++) acc1 += wa[u*9+k]*tap[DST[rot][k]];
        y[rot*2+u] = acc1;
      }
    }
    unsigned long long pk[4];
    #pragma unroll
    for (int q=0; q<4; q++){
      float4 A = *(const float4*)(cab + q*4);
      float4 Bv = *(const float4*)(cab + 16 + q*4);
      float r0 = fmaxf(y[q*4+0]*A.x + Bv.x, 0.f);
      float r1 = fmaxf(y[q*4+1]*A.y + Bv.y, 0.f);
      float r2 = fmaxf(y[q*4+2]*A.z + Bv.z, 0.f);
      float r3 = fmaxf(y[q*4+3]*A.w + Bv.w, 0.f);
      unsigned int lo = cvtpk(r0, r1);
      unsigned int hi = cvtpk(r2, r3);
      pk[q] = (unsigned long long)lo | ((unsigned long long)hi<<32);
    }
    int cell = (py+1)*32 + px + 1;
    unsigned long long* dstp = (unsigned long long*)(Ls + cell*16);
    dstp[0]=pk[0]; dstp[1]=pk[1]; dstp[2]=pk[2]; dstp[3]=pk[3];
  }
  __syncthreads();
  // hoisted per-j LDS element offsets; tap deltas are compile-time immediates
  int jb[13];
  #pragma unroll
  for (int j=0;j<13;j++){
    int mt = wid + 4*j;
    int pos = (mt < 49) ? (mt*16 + m) : 0;
    int py = pos/28, px = pos - 28*py;
    jb[j] = (py*32 + px)*16 + (quad&1)*8;
  }
  f32x4 acc[13];
  #pragma unroll
  for (int j=0;j<13;j++) acc[j] = (f32x4){0.f,0.f,0.f,0.f};
  #pragma unroll
  for (int c=0;c<5;c++){
    const int tapA = 2*c, tapB = (2*c+1 < 9) ? 2*c+1 : 8;
    const int offA = ((tapA/3)*32 + tapA%3)*16;
    const int offB = ((tapB/3)*32 + tapB%3)*16;
    int sel = (quad < 2) ? offA : offB;
    bf16x8 Bf = *(const bf16x8*)(B2 + (c*16 + m)*32 + quad*8);
    #pragma unroll
    for (int j=0;j<13;j++){
      int mt = wid + 4*j;
      if (mt >= 49) continue;
      bf16x8 Af = *(const bf16x8*)(Ls + jb[j] + sel);
      acc[j] = __builtin_amdgcn_mfma_f32_16x16x32_bf16(Af, Bf, acc[j], 0, 0, 0);
    }
  }
  __syncthreads();   // done reading Ls; reuse as out2
  float s = 0.f, sq = 0.f;
  #pragma unroll
  for (int j=0;j<13;j++){
    int mt = wid + 4*j;
    if (mt >= 49) continue;
    #pragma unroll
    for (int p=0;p<2;p++){
      // pos0 = mt*16 + quad*4 + 2p is even and never wraps a row: (r0,r1) horizontal pool pair
      int pos0 = mt*16 + quad*4 + p*2;
      float v0 = acc[j][2*p], v1 = acc[j][2*p+1];
      s += v0 + v1; sq += v0*v0 + v1*v1;
      float hm = fmaxf(v0, v1);
      int py = pos0/28, px2 = (pos0 - py*28)>>1;
      out2[(py*14+px2)*17 + m] = hm;
    }
  }
  s += __shfl_down(s,32);  s += __shfl_down(s,16);
  sq += __shfl_down(sq,32); sq += __shfl_down(sq,16);
  if (lane < 16){ red[wid][m] = s; red[wid][16+m] = sq; }
  __syncthreads();
  if (t < 32){
    float v = red[0][t]+red[1][t]+red[2][t]+red[3][t];
    int ch = t & 15, kind = t >> 4;
    atomicAdd(ST_ADDR(stout, ch, kind, b & 3), v);
  }
  unsigned short* pb = p2b + (size_t)b*4096;
  for (int i=t; i<3136; i+=256){
    int cell = i>>4, oc = i&15;
    int yo = cell/14, xo = cell - yo*14;
    float mx = fmaxf(out2[((2*yo)*14+xo)*17 + oc], out2[((2*yo+1)*14+xo)*17 + oc]);
    pb[((yo+1)*16 + xo + 1)*16 + oc] = f2bf(mx);
  }
  for (int i=t; i<960; i+=256){
    int bc = border_cell(i>>4), oc = i&15;
    pb[bc*16 + oc] = f2bf(SENT);
  }
}

// ---------------- conv3 WAVE-PER-IMAGE: grid 512 x 4 waves; zero barriers in main flow ----------------
// Each wave owns image b = blk*4+wid and a private LDS input plane [256 cells][16ci] padded to
// 24-ushort stride (48B) so b128 reads step 12 banks -> 2-way (free) instead of 8 banks (4-way).
// Af fragments shared across both oc halves; y3b + stats written directly from accumulators.
__global__ __launch_bounds__(256, 2) void k_conv3w(const unsigned short* __restrict__ p2b,
                                                   const unsigned short* __restrict__ B3,  // [5][32][32] bf16
                                                   const float* __restrict__ stin,
                                                   const float* __restrict__ g2, const float* __restrict__ b2,
                                                   unsigned short* __restrict__ y3b,
                                                   float* __restrict__ stout){
  __shared__ unsigned short act[4][256*24];   // 48 KB
  __shared__ float ca[16], cb[16];
  __shared__ float red[4][64];
  int t = threadIdx.x;
  int wid = t>>6, lane = t&63;
  int quad = lane>>4, m = lane&15;
  if (t < 16){
    const float invN = 1.f/1605632.f;
    float mu = st_read(stin, t, 0)*invN;
    float var = st_read(stin, t, 1)*invN - mu*mu;
    float a = g2[t&1]*rsqrtf(var + 1e-5f);
    ca[t] = a; cb[t] = b2[t&1] - mu*a;
  }
  __syncthreads();                           // ONLY entry barrier (coef ready)
  int b = blockIdx.x*4 + wid;
  unsigned short* A = act[wid];
  const unsigned short* sb = p2b + (size_t)b*4096;
  // ---- staging: 4 cells per lane, bn+relu+requant, write 48B-stride LDS rows (own region) ----
  #pragma unroll
  for (int k=0;k<4;k++){
    int cell = lane + 64*k;
    uint4 U0 = *(const uint4*)(sb + cell*16);
    uint4 U1 = *(const uint4*)(sb + cell*16 + 8);
    unsigned int p0 = bnpair(U0.x, ca[0],cb[0], ca[1],cb[1]);
    unsigned int p1 = bnpair(U0.y, ca[2],cb[2], ca[3],cb[3]);
    unsigned int p2 = bnpair(U0.z, ca[4],cb[4], ca[5],cb[5]);
    unsigned int p3 = bnpair(U0.w, ca[6],cb[6], ca[7],cb[7]);
    unsigned int p4 = bnpair(U1.x, ca[8],cb[8], ca[9],cb[9]);
    unsigned int p5 = bnpair(U1.y, ca[10],cb[10], ca[11],cb[11]);
    unsigned int p6 = bnpair(U1.z, ca[12],cb[12], ca[13],cb[13]);
    unsigned int p7 = bnpair(U1.w, ca[14],cb[14], ca[15],cb[15]);
    unsigned long long* q = (unsigned long long*)(A + cell*24);
    q[0] = (unsigned long long)p0 | ((unsigned long long)p1<<32);
    q[1] = (unsigned long long)p2 | ((unsigned long long)p3<<32);
    q[2] = (unsigned long long)p4 | ((unsigned long long)p5<<32);
    q[3] = (unsigned long long)p6 | ((unsigned long long)p7<<32);
  }
  asm volatile("s_waitcnt lgkmcnt(0)" ::: "memory");
  __builtin_amdgcn_sched_barrier(0);
  // ---- MFMA: 13 m-tiles x 5 tap-pairs x 2 oc-halves, Af shared across halves ----
  int jpix[13];
  #pragma unroll
  for (int j=0;j<13;j++){
    int pos = j*16 + m;
    if (pos >= 196) pos = 0;
    int py = pos/14, px = pos - 14*(pos/14);
    jpix[j] = py*16 + px;
  }
  f32x4 acc[13][2];
  #pragma unroll
  for (int j=0;j<13;j++){ acc[j][0] = (f32x4){0,0,0,0}; acc[j][1] = (f32x4){0,0,0,0}; }
  int half = (quad&1)*8;
  #pragma unroll
  for (int c=0;c<5;c++){
    const int tapA = 2*c, tapB = (2*c+1 < 9) ? 2*c+1 : 8;
    const int offA = (tapA/3)*16 + tapA%3;
    const int offB = (tapB/3)*16 + tapB%3;
    int sel = (quad < 2) ? offA : offB;
    bf16x8 Bf0 = *(const bf16x8*)(B3 + (c*32 + m)*32 + quad*8);
    bf16x8 Bf1 = *(const bf16x8*)(B3 + (c*32 + 16 + m)*32 + quad*8);
    #pragma unroll
    for (int j=0;j<13;j++){
      bf16x8 Af = *(const bf16x8*)(A + (jpix[j] + sel)*24 + half);
      acc[j][0] = __builtin_amdgcn_mfma_f32_16x16x32_bf16(Af, Bf0, acc[j][0], 0, 0, 0);
      acc[j][1] = __builtin_amdgcn_mfma_f32_16x16x32_bf16(Af, Bf1, acc[j][1], 0, 0, 0);
    }
  }
  asm volatile("s_waitcnt lgkmcnt(0)" ::: "memory");
  __builtin_amdgcn_sched_barrier(0);
  // ---- epilogue: y3b writes + stats, wave-local ----
  unsigned short* yb = y3b + (size_t)b*8192;
  float s0=0.f, sq0=0.f, s1=0.f, sq1=0.f;
  #pragma unroll
  for (int j=0;j<13;j++){
    #pragma unroll
    for (int r=0;r<4;r++){
      int pos = j*16 + quad*4 + r;
      if (pos < 196){
        float v0 = acc[j][0][r], v1 = acc[j][1][r];
        int py2 = pos/14, px2 = pos - py2*14;
        int cell = (py2+1)*16 + px2 + 1;
        yb[cell*32 + m]      = f2bf(v0);
        yb[cell*32 + 16 + m] = f2bf(v1);
        s0 += v0; sq0 += v0*v0; s1 += v1; sq1 += v1*v1;
      }
    }
  }
  // border sentinels as packed u32 pairs
  {
    unsigned short sh = f2bf(SENT);
    unsigned int SP = (unsigned int)sh | ((unsigned int)sh << 16);
    for (int i=lane; i<960; i+=64){
      int bc = border_cell(i>>4);
      int p = i & 15;
      *(unsigned int*)(yb + bc*32 + p*2) = SP;
    }
  }
  s0 += __shfl_down(s0,32); s0 += __shfl_down(s0,16);
  sq0 += __shfl_down(sq0,32); sq0 += __shfl_down(sq0,16);
  s1 += __shfl_down(s1,32); s1 += __shfl_down(s1,16);
  sq1 += __shfl_down(sq1,32); sq1 += __shfl_down(sq1,16);
  if (lane < 16){
    red[wid][m]      = s0;  red[wid][32+m]      = sq0;
    red[wid][16+m]   = s1;  red[wid][32+16+m]   = sq1;
  }
  __syncthreads();                           // ONLY exit barrier (stats reduce)
  if (t < 64){
    float v = red[0][t]+red[1][t]+red[2][t]+red[3][t];
    int ch = t & 31, kind = t >> 5;
    atomicAdd(ST_ADDR(stout, ch, kind, blockIdx.x & 3), v);
  }
}

// ---------------- conv4 WAVE-PER-IMAGE: grid 512 x 4 waves; zero barriers in main flow ----------------
__global__ __launch_bounds__(256, 2) void k_conv4w(const unsigned short* __restrict__ y3b,
                                                   const unsigned short* __restrict__ wb4, // [9][32][32] bf16
                                                   const float* __restrict__ stin,
                                                   const float* __restrict__ g3, const float* __restrict__ b3,
                                                   float* __restrict__ p4,
                                                   float* __restrict__ stout,
                                                   float* __restrict__ nmsa){
  __shared__ unsigned short act[4][8192];   // 64 KB: per-wave act plane, later reused as hp f32 [98][33]
  __shared__ float ca[32], cb[32];
  __shared__ float red[4][64];
  int t = threadIdx.x;
  int wid = t>>6, lane = t&63;
  int quad = lane>>4, m = lane&15;
  if (t < 32){
    const float invN = 1.f/401408.f;
    float mu = st_read(stin, t, 0)*invN;
    float var = st_read(stin, t, 1)*invN - mu*mu;
    float a = g3[t&3]*rsqrtf(var + 1e-5f);
    ca[t] = a; cb[t] = b3[t&3] - mu*a;
  }
  __syncthreads();                           // ONLY entry barrier (coef ready)
  int b = blockIdx.x*4 + wid;
  unsigned short* A = act[wid];
  const unsigned short* sb = y3b + (size_t)b*8192;
  // ---- staging: 4 cells per lane, chunk-swizzled ds writes (own region, no barrier) ----
  #pragma unroll
  for (int k=0;k<4;k++){
    int cell = lane + 64*k;
    const uint4* src = (const uint4*)(sb + cell*32);
    int sw = cell & 3;
    unsigned short* dst = A + cell*32;
    #pragma unroll
    for (int c=0;c<4;c++){
      uint4 W = src[c];
      int c0 = c*8;
      unsigned int q0 = bnpair(W.x, ca[c0+0],cb[c0+0], ca[c0+1],cb[c0+1]);
      unsigned int q1 = bnpair(W.y, ca[c0+2],cb[c0+2], ca[c0+3],cb[c0+3]);
      unsigned int q2 = bnpair(W.z, ca[c0+4],cb[c0+4], ca[c0+5],cb[c0+5]);
      unsigned int q3 = bnpair(W.w, ca[c0+6],cb[c0+6], ca[c0+7],cb[c0+7]);
      unsigned long long* q = (unsigned long long*)(dst + ((c ^ sw)<<3));
      q[0] = (unsigned long long)q0 | ((unsigned long long)q1<<32);
      q[1] = (unsigned long long)q2 | ((unsigned long long)q3<<32);
    }
  }
  asm volatile("s_waitcnt lgkmcnt(0)" ::: "memory");
  __builtin_amdgcn_sched_barrier(0);
  // ---- NMS over own image (reads act, wave-local) ----
  float nloc = 0.f;
  for (int i=lane; i<784; i+=64){
    int hw = i>>2, c4 = i&3;
    int cell = (hw/14 + 1)*16 + hw%14 + 1;
    const unsigned int* g32 = (const unsigned int*)(A + cell*32 + ((c4 ^ (cell&3))<<3));
    unsigned int w0 = g32[0], w1 = g32[1], w2 = g32[2], w3 = g32[3];
    float v[8];
    v[0] = __uint_as_float(w0 << 16); v[1] = __uint_as_float(w0 & 0xFFFF0000u);
    v[2] = __uint_as_float(w1 << 16); v[3] = __uint_as_float(w1 & 0xFFFF0000u);
    v[4] = __uint_as_float(w2 << 16); v[5] = __uint_as_float(w2 & 0xFFFF0000u);
    v[6] = __uint_as_float(w3 << 16); v[7] = __uint_as_float(w3 & 0xFFFF0000u);
    float vmax = -1e30f;
    #pragma unroll
    for (int r=0;r<8;r++) vmax = fmaxf(vmax, v[r]);
    #pragma unroll
    for (int r=0;r<8;r++) nloc += (v[r] != vmax) ? v[r] : 0.f;
  }
  #pragma unroll
  for (int off=32; off; off>>=1) nloc += __shfl_down(nloc, off);
  if (lane == 0) atomicAdd(&nmsa[(b & 7)*32], nloc);
  // ---- MFMA: 13 m-tiles x 9 taps x 2 oc-halves, Af shared across halves ----
  int jc[13], jp[13];
  #pragma unroll
  for (int j=0;j<13;j++){
    int pos = j*16 + m;
    if (pos >= 196) pos = 0;
    int py = pos/14, px = pos - 14*(pos/14);
    jc[j] = py*16 + px;
    jp[j] = px;
  }
  f32x4 acc[13][2];
  #pragma unroll
  for (int j=0;j<13;j++){ acc[j][0] = (f32x4){0,0,0,0}; acc[j][1] = (f32x4){0,0,0,0}; }
  #pragma unroll
  for (int tap=0; tap<9; tap++){
    const int dy = tap/3, dx = tap - 3*(tap/3);
    bf16x8 Bf0 = *(const bf16x8*)(wb4 + (tap*32 + m)*32 + quad*8);
    bf16x8 Bf1 = *(const bf16x8*)(wb4 + (tap*32 + 16 + m)*32 + quad*8);
    #pragma unroll
    for (int j=0;j<13;j++){
      int ci = jc[j] + dy*16 + dx;
      int ph = quad ^ ((jp[j]+dx)&3);
      bf16x8 Af = *(const bf16x8*)(A + ci*32 + ph*8);
      acc[j][0] = __builtin_amdgcn_mfma_f32_16x16x32_bf16(Af, Bf0, acc[j][0], 0, 0, 0);
      acc[j][1] = __builtin_amdgcn_mfma_f32_16x16x32_bf16(Af, Bf1, acc[j][1], 0, 0, 0);
    }
  }
  asm volatile("s_waitcnt lgkmcnt(0)" ::: "memory");
  __builtin_amdgcn_sched_barrier(0);
  // ---- epilogue: stats + in-register horizontal pool -> hp (reuses act region), wave-local ----
  float* hp = (float*)A;                    // 98*33*4 = 12936 B <= 16384 B
  float s0=0.f, sq0=0.f, s1=0.f, sq1=0.f;
  #pragma unroll
  for (int j=0;j<13;j++){
    #pragma unroll
    for (int p=0;p<2;p++){
      int pos0 = j*16 + quad*4 + 2*p;       // even, px even -> horizontal pool pair
      if (pos0 + 1 < 196){
        float a0 = acc[j][0][2*p], a1 = acc[j][0][2*p+1];
        float b0 = acc[j][1][2*p], b1 = acc[j][1][2*p+1];
        s0 += a0 + a1; sq0 += a0*a0 + a1*a1;
        s1 += b0 + b1; sq1 += b0*b0 + b1*b1;
        int py0 = pos0/14, pxh = (pos0 - py0*14)>>1;
        hp[(py0*7 + pxh)*33 + m]      = fmaxf(a0, a1);
        hp[(py0*7 + pxh)*33 + 16 + m] = fmaxf(b0, b1);
      }
    }
  }
  s0 += __shfl_down(s0,32); s0 += __shfl_down(s0,16);
  sq0 += __shfl_down(sq0,32); sq0 += __shfl_down(sq0,16);
  s1 += __shfl_down(s1,32); s1 += __shfl_down(s1,16);
  sq1 += __shfl_down(sq1,32); sq1 += __shfl_down(sq1,16);
  if (lane < 16){
    red[wid][m]      = s0;  red[wid][32+m]      = sq0;
    red[wid][16+m]   = s1;  red[wid][32+16+m]   = sq1;
  }
  asm volatile("s_waitcnt lgkmcnt(0)" ::: "memory");
  __builtin_amdgcn_sched_barrier(0);
  // ---- vertical pool from hp -> p4 (wave-local) ----
  for (int i=lane; i<1568; i+=64){
    int cell = i>>5, oc = i&31;
    int yo = cell/7, xo = cell - yo*7;
    float mx = fmaxf(hp[((2*yo)*7 + xo)*33 + oc], hp[((2*yo+1)*7 + xo)*33 + oc]);
    p4[((size_t)b*49 + cell)*32 + oc] = mx;
  }
  __syncthreads();                           // ONLY exit barrier (stats reduce)
  if (t < 64){
    float v = red[0][t]+red[1][t]+red[2][t]+red[3][t];
    int ch = t & 31, kind = t >> 5;
    atomicAdd(ST_ADDR(stout, ch, kind, blockIdx.x & 3), v);
  }
}

// ---------------- conv5/conv6 MFMA: CI->64, per-wave batch, bn coef in-block, shift-GEMM over 9 taps ----------------
template<int CI>
__global__ __launch_bounds__(256, 2) void k_conv56m(const float* __restrict__ src,
                                                    const unsigned short* __restrict__ wb,  // [9][64][CI] bf16
                                                    const float* __restrict__ stin,
                                                    const float* __restrict__ g, const float* __restrict__ be,
                                                    float invN,
                                                    float* __restrict__ dst,
                                                    float* __restrict__ stout){
  constexpr int CIP = CI + 8;
  constexpr int KC = CI/32;
  __shared__ unsigned short lin[4][81*CIP];
  __shared__ float red[4][256];
  __shared__ float ca[CI], cb[CI];
  int wid = threadIdx.x>>6, lane = threadIdx.x&63;
  int quad = lane>>4, m = lane&15;
  unsigned short* L = lin[wid];
  if (threadIdx.x < CI){
    int i = threadIdx.x;
    float mu = st_read(stin, i, 0)*invN;
    float var = st_read(stin, i, 1)*invN - mu*mu;
    float a = g[i]*rsqrtf(var + 1e-5f);
    ca[i] = a; cb[i] = be[i] - mu*a;
  }
  for (int i = lane; i < 81*CIP/4; i += 64) ((unsigned long long*)L)[i] = 0ULL;
  __syncthreads();
  int b = blockIdx.x*4 + wid;
  const float* sb = src + (size_t)b*49*CI;
  for (int i = lane; i < 49*CI/4; i += 64){
    int pos = i/(CI/4), cig = i - pos*(CI/4);
    float4 v = *(const float4*)(sb + pos*CI + cig*4);
    float r0 = fmaxf(v.x*ca[cig*4]  +cb[cig*4],   0.f);
    float r1 = fmaxf(v.y*ca[cig*4+1]+cb[cig*4+1], 0.f);
    float r2 = fmaxf(v.z*ca[cig*4+2]+cb[cig*4+2], 0.f);
    float r3 = fmaxf(v.w*ca[cig*4+3]+cb[cig*4+3], 0.f);
    int pos9 = (pos/7 + 1)*9 + pos%7 + 1;
    unsigned int lo = cvtpk(r0, r1);
    unsigned int hi = cvtpk(r2, r3);
    *(unsigned long long*)(L + pos9*CIP + cig*4) =
        (unsigned long long)lo | ((unsigned long long)hi<<32);
  }
  __syncthreads();
  int py[4], px[4];
  #pragma unroll
  for (int mt=0; mt<4; mt++){
    int pos = mt*16 + m;
    if (pos < 49){ py[mt] = pos/7; px[mt] = pos%7; }
    else { py[mt] = 0; px[mt] = 0; }
  }
  f32x4 acc[4][4];
  #pragma unroll
  for (int nt=0; nt<4; nt++)
    #pragma unroll
    for (int mt=0; mt<4; mt++) acc[nt][mt] = (f32x4){0.f,0.f,0.f,0.f};

  for (int tap=0; tap<9; tap++){
    int dy = tap/3, dx = tap - dy*3;
    int o9[4];
    #pragma unroll
    for (int mt=0; mt<4; mt++) o9[mt] = ((py[mt]+dy)*9 + px[mt]+dx)*CIP;
    #pragma unroll
    for (int kc=0; kc<KC; kc++){
      int ko = kc*32 + quad*8;
      bf16x8 Bf[4], Af[4];
      #pragma unroll
      for (int nt=0; nt<4; nt++)
        Bf[nt] = *(const bf16x8*)(wb + (tap*64 + nt*16 + m)*CI + ko);
      #pragma unroll
      for (int mt=0; mt<4; mt++)
        Af[mt] = *(const bf16x8*)(L + o9[mt] + ko);
      #pragma unroll
      for (int nt=0; nt<4; nt++)
        #pragma unroll
        for (int mt=0; mt<4; mt++)
          acc[nt][mt] = __builtin_amdgcn_mfma_f32_16x16x32_bf16(Af[mt], Bf[nt], acc[nt][mt], 0, 0, 0);
    }
  }
  float* db = dst + (size_t)b*49*64;
  float snt[4], sqnt[4];
  #pragma unroll
  for (int nt=0; nt<4; nt++){
    float s = 0.f, sq = 0.f;
    #pragma unroll
    for (int mt=0; mt<4; mt++){
      #pragma unroll
      for (int r=0; r<4; r++){
        int pos = mt*16 + quad*4 + r;
        if (pos < 49){
          float v = acc[nt][mt][r];
          db[pos*64 + nt*16 + m] = v;
          s += v; sq += v*v;
        }
      }
    }
    s += __shfl_down(s, 32);  s += __shfl_down(s, 16);
    sq += __shfl_down(sq, 32); sq += __shfl_down(sq, 16);
    snt[nt] = s; sqnt[nt] = sq;
  }
  if (lane < 16){
    #pragma unroll
    for (int nt=0; nt<4; nt++){
      red[wid][nt*16 + lane] = snt[nt];
      red[wid][128 + nt*16 + lane] = sqnt[nt];
    }
  }
  __syncthreads();
  if (threadIdx.x < 128){
    int c = threadIdx.x & 63;
    int off = (threadIdx.x < 64) ? threadIdx.x : (128 + c);
    float v = red[0][off]+red[1][off]+red[2][off]+red[3][off];
    int kind = (threadIdx.x < 64) ? 0 : 1;
    atomicAdd(ST_ADDR(stout, c, kind, blockIdx.x & 3), v);
  }
}

// ---------------- bn6+relu + 2x2 pool pad 1 (7 -> 4); COMPACT PRECOMPUTED COEF; y6 -> p6b bf16 ----------------
__global__ __launch_bounds__(256) void k_pool6(const float* __restrict__ y,
                                               const float* __restrict__ cf,   // [64] a | [64] b
                                               unsigned short* __restrict__ p6b){
  int idx = blockIdx.x*256 + threadIdx.x;       // NB*16*64 exact
  int oc = idx & 63; int t2 = idx >> 6;
  int xo = t2 & 3;  int yo = (t2>>2) & 3;  int b = t2 >> 4;
  float a = cf[oc];
  float bo = cf[64 + oc];
  const float* src = y + (size_t)b*3136;
  float mx = -1e30f;
  #pragma unroll
  for (int dy=0;dy<2;dy++){
    int iy = yo*2 - 1 + dy;
    if (iy < 0 || iy >= 7) continue;
    #pragma unroll
    for (int dx=0;dx<2;dx++){
      int ix = xo*2 - 1 + dx;
      if (ix < 0 || ix >= 7) continue;
      mx = fmaxf(mx, src[(iy*7+ix)*64 + oc]*a + bo);
    }
  }
  p6b[(size_t)b*1024 + (yo*4 + xo)*64 + oc] = f2bf(fmaxf(mx, 0.f));
}

// ---------------- conv7 as GEMM: M=2048 (batch), N=256 (pos25*10+o), K=1024; partial max per N-block ----------------
__global__ __launch_bounds__(256) void k_gemm7(const unsigned short* __restrict__ A,   // [2048][1024] bf16
                                               const unsigned short* __restrict__ Bl,  // [256][1024] bf16
                                               float* __restrict__ part){              // [2048][4][10]
  __shared__ float Lw[4][16*65];
  int wid = threadIdx.x>>6, lane = threadIdx.x&63;
  int quad = lane>>4, m = lane&15;
  int blkm = blockIdx.x >> 2, blkn = blockIdx.x & 3;   // grid 128
  int rowb = blkm*64 + wid*16 + m;
  const unsigned short* Arow = A + (size_t)rowb*1024;
  f32x4 acc[4];
  #pragma unroll
  for (int nt=0; nt<4; nt++) acc[nt] = (f32x4){0.f,0.f,0.f,0.f};
  for (int kc=0; kc<32; kc++){
    bf16x8 Af = *(const bf16x8*)(Arow + kc*32 + quad*8);
    #pragma unroll
    for (int nt=0; nt<4; nt++){
      bf16x8 Bf = *(const bf16x8*)(Bl + (size_t)(blkn*64 + nt*16 + m)*1024 + kc*32 + quad*8);
      acc[nt] = __builtin_amdgcn_mfma_f32_16x16x32_bf16(Af, Bf, acc[nt], 0, 0, 0);
    }
  }
  float* Lp = &Lw[wid][0];
  #pragma unroll
  for (int nt=0; nt<4; nt++)
    #pragma unroll
    for (int r=0; r<4; r++)
      Lp[(quad*4+r)*65 + nt*16 + m] = acc[nt][r];
  __syncthreads();
  for (int i=lane; i<160; i+=64){
    int br = i/10, o = i - 10*(i/10);
    int c0 = ((o - blkn*64) % 10 + 10) % 10;
    float mx = -1e30f;
    for (int c=c0; c<64; c+=10){
      if (blkn*64 + c < 250) mx = fmaxf(mx, Lp[br*65 + c]);
    }
    part[((size_t)(blkm*64 + wid*16 + br)*4 + blkn)*10 + o] = mx;
  }
}

// ---------------- logits: max over 4 N-block partials + bias; nms write ----------------
__global__ __launch_bounds__(256) void k_logits(const float* __restrict__ part,
                                                const float* __restrict__ bias,
                                                const float* __restrict__ nmsa,
                                                float* __restrict__ out){
  int idx = blockIdx.x*256 + threadIdx.x;       // 20480 exact (80 blocks)
  int b = idx/10, o = idx - 10*(idx/10);
  const float* p = part + (size_t)b*40 + o;
  float mx = fmaxf(fmaxf(p[0], p[10]), fmaxf(p[20], p[30]));
  out[idx] = mx + bias[o];
  if (blockIdx.x == 0 && threadIdx.x == 0){
    float nm = 0.f;
    #pragma unroll
    for (int cp=0; cp<8; cp++) nm += nmsa[cp*32];
    out[20480] = nm * (1.f/12845056.f);
  }
}

extern "C" void kernel_launch(void* const* d_in, const int* in_sizes, int n_in,
                              void* d_out, int out_size, void* d_ws, size_t ws_size,
                              hipStream_t stream){
  const float* x  = (const float*)d_in[0];
  const float* w1 = (const float*)d_in[1];
  const float* w2 = (const float*)d_in[2];
  const float* w3 = (const float*)d_in[3];
  const float* w4 = (const float*)d_in[4];
  const float* w5 = (const float*)d_in[5];
  const float* w6 = (const float*)d_in[6];
  const float* w7 = (const float*)d_in[7];
  const float* g1 = (const float*)d_in[8];
  const float* b1 = (const float*)d_in[9];
  const float* g2 = (const float*)d_in[10];
  const float* b2 = (const float*)d_in[11];
  const float* g3 = (const float*)d_in[12];
  const float* b3 = (const float*)d_in[13];
  const float* g4 = (const float*)d_in[14];
  const float* b4 = (const float*)d_in[15];
  const float* g5 = (const float*)d_in[16];
  const float* b5 = (const float*)d_in[17];
  const float* g6 = (const float*)d_in[18];
  const float* b6 = (const float*)d_in[19];
  const float* b7 = (const float*)d_in[20];
  float* out = (float*)d_out;
  float* W = (float*)d_ws;

  // arena (float units)
  unsigned short* p2b = (unsigned short*)(W + 15728640); // 2048*256*16 bf16 (16.8 MB, region holds 33.5 MB)
  unsigned short* y3b = (unsigned short*)(W + 24117248); // 2048*256*32 bf16 (33.6 MB, region holds 67 MB)
  float* p4   = W + 0;                 //  3,211,264  (2048*49*32) -> ends 3,211,264
  // line-padded stats arena lives in the verified-free gap [3211264, 3407872):
  //   6 layers x 8192 floats + 8-copy nms (256) + cf6 (128) = 49,536 floats -> ends 3,260,800 < 3,407,872.
  float* st   = W + 3211264;
  float* nmsa = st + 6*8192;
  float* cf6  = nmsa + 256;
  float* y5   = W + 3407872;           //  6,422,528  (2048*49*64)
  float* y6   = W + 10223616;          //  6,422,528
  unsigned short* p6b = (unsigned short*)(W + 16646144); // 2048*1024 bf16
  unsigned short* wb5 = (unsigned short*)(W + 40894464);  // 9*64*32 bf16
  unsigned short* wb6 = (unsigned short*)(W + 40912896);  // 9*64*64 bf16
  unsigned short* wb4 = (unsigned short*)(W + 40931328);  // 9*32*32 bf16
  unsigned short* Bl = (unsigned short*)(W + 40951808);   // 256*1024 bf16
  float* part = W + 41082880;          //  81,920 (2048*4*10)
  unsigned short* B2 = (unsigned short*)(W + 41164800);   // 5*16*32 bf16 (1280 floats)
  unsigned short* B3 = (unsigned short*)(W + 41166080);   // 5*32*32 bf16 (2560 floats)

  hipMemsetAsync(st, 0, 49536*sizeof(float), stream);

  k_pre<<<1819,256,0,stream>>>(x, w1, w2, w3, w4, w5, w6, w7,
                               B2, B3, wb4, wb5, wb6, Bl, st + 0*8192);

  k_conv2m<<<2048,256,0,stream>>>(x, w1, B2, st + 0*8192, g1, b1, p2b, st + 1*8192);

  k_conv3w<<<512,256,0,stream>>>(p2b, B3, st + 1*8192, g2, b2, y3b, st + 2*8192);

  k_conv4w<<<512,256,0,stream>>>(y3b, wb4, st + 2*8192, g3, b3, p4, st + 3*8192, nmsa);

  k_conv56m<32><<<512,256,0,stream>>>(p4, wb5, st + 3*8192, g4, b4, 1.f/401408.f, y5, st + 4*8192);

  k_conv56m<64><<<512,256,0,stream>>>(y5, wb6, st + 4*8192, g5, b5, 1.f/100352.f, y6, st + 5*8192);

  k_coef<64><<<1,64,0,stream>>>(st + 5*8192, g6, b6, 1.f/100352.f, 63, cf6);

  k_pool6<<<8192,256,0,stream>>>(y6, cf6, p6b);

  k_gemm7<<<128,256,0,stream>>>(p6b, Bl, part);
  k_logits<<<80,256,0,stream>>>(part, b7, nmsa, out);
}